// Round 2
// baseline (1778.601 us; speedup 1.0000x reference)
//
#include <hip/hip_runtime.h>
#include <math.h>

#define B_SZ 2
#define SEQ 4096
#define DMODEL 768
#define DSTATE 128
#define HEADDIM 64
#define DINNER 1536
#define NHEADS 24
#define DXBC 1792
#define DPROJ 3352
#define CHUNK 128
#define NCHUNK 32
#define ROWS (B_SZ*SEQ)

__device__ __forceinline__ float sigmoidf_(float x){ return 1.f/(1.f+expf(-x)); }
__device__ __forceinline__ float siluf_(float x){ return x/(1.f+expf(-x)); }
__device__ __forceinline__ float softplusf_(float x){ return (x>20.f)? x : log1pf(expf(x)); }

// -------- GEMM: C[M][N] = A[M][K] @ W[N][K]^T (fp32, 64x64x16 tile), strided A/C -----
template<bool EPI>
__global__ __launch_bounds__(256)
void gemm_nt(const float* __restrict__ A, const float* __restrict__ W,
             float* __restrict__ C, int M, int N, int K, int lda, int ldc,
             const float* __restrict__ gate, const float* __restrict__ resid)
{
    __shared__ float As[16][65];
    __shared__ float Ws[16][65];
    const int tid = threadIdx.x;
    const int bm = blockIdx.y*64, bn = blockIdx.x*64;
    const int tx = tid & 15, ty = tid >> 4;
    const int kk = tid & 15, rr = tid >> 4;
    float acc[4][4] = {};
    for (int k0 = 0; k0 < K; k0 += 16) {
#pragma unroll
        for (int r = 0; r < 4; ++r) {
            int m = rr + r*16;
            As[kk][m] = A[(size_t)(bm+m)*lda + k0 + kk];
            int n = bn + m;
            Ws[kk][m] = (n < N) ? W[(size_t)n*K + k0 + kk] : 0.f;
        }
        __syncthreads();
#pragma unroll
        for (int k = 0; k < 16; ++k) {
            float a[4], b[4];
#pragma unroll
            for (int i=0;i<4;++i){ a[i] = As[k][ty*4+i]; b[i] = Ws[k][tx*4+i]; }
#pragma unroll
            for (int i=0;i<4;++i)
#pragma unroll
                for (int j=0;j<4;++j) acc[i][j] += a[i]*b[j];
        }
        __syncthreads();
    }
    float gs = 0.f;
    if (EPI) gs = sigmoidf_(gate[0]);
#pragma unroll
    for (int i=0;i<4;++i){
        int m = bm + ty*4 + i;
#pragma unroll
        for (int j=0;j<4;++j){
            int n = bn + tx*4 + j;
            if (n < N) {
                size_t off = (size_t)m*ldc + n;
                C[off] = EPI ? (gs*acc[i][j] + resid[off]) : acc[i][j];
            }
        }
    }
}

// ---------------- dt = softplus(raw + dt_bias) ----------------
__global__ __launch_bounds__(256)
void dt_k(const float* __restrict__ zx, const float* __restrict__ dt_bias,
          float* __restrict__ dtb)
{
    int idx = blockIdx.x*256 + threadIdx.x;
    if (idx >= ROWS*NHEADS) return;
    int h = idx % NHEADS; int r = idx / NHEADS;
    float x = zx[(size_t)r*DPROJ + (DINNER+DXBC) + h] + dt_bias[h];
    dtb[idx] = softplusf_(x);
}

// ---------------- causal conv(4) + SiLU ----------------
__global__ __launch_bounds__(256)
void conv_silu_k(const float* __restrict__ zx, const float* __restrict__ cw,
                 const float* __restrict__ cb, float* __restrict__ xBC)
{
    int idx = blockIdx.x*256 + threadIdx.x;
    if (idx >= ROWS*DXBC) return;
    int ch = idx % DXBC;
    int r  = idx / DXBC;
    int l  = r & (SEQ-1);
    float4 w4 = *(const float4*)(cw + ch*4);
    float wv[4] = {w4.x, w4.y, w4.z, w4.w};
    float acc = cb[ch];
#pragma unroll
    for (int k=0;k<4;++k){
        int li = l - 3 + k;
        if (li >= 0) acc += wv[k] * zx[(size_t)(r-3+k)*DPROJ + DINNER + ch];
    }
    xBC[(size_t)idx] = siluf_(acc);
}

// ---------------- intra-chunk inclusive cumsum of dt*A ----------------
__global__ __launch_bounds__(128)
void scan_k(const float* __restrict__ dtb, const float* __restrict__ A_log,
            float* __restrict__ acum)
{
    int c = blockIdx.x & 31;
    int h = (blockIdx.x >> 5) % NHEADS;
    int b = blockIdx.x / (32*NHEADS);
    int l = threadIdx.x;
    float A = -expf(A_log[h]);
    int row = b*SEQ + c*CHUNK + l;
    float v = dtb[row*NHEADS + h] * A;
    __shared__ float sh[128];
    sh[l] = v; __syncthreads();
    for (int off=1; off<128; off<<=1){
        float t = (l>=off) ? sh[l-off] : 0.f;
        __syncthreads();
        sh[l] += t;
        __syncthreads();
    }
    acum[((b*NHEADS+h)*NCHUNK + c)*CHUNK + l] = sh[l];
}

// ---------------- CB[l][s] = sum_n C[l][n]*B[s][n], per chunk ----------------
__global__ __launch_bounds__(256)
void cb_k(const float* __restrict__ xBC, float* __restrict__ CB)
{
    int c = blockIdx.x & 31; int b = blockIdx.x >> 5;
    int base = b*SEQ + c*CHUNK;
    __shared__ float Cs[16][128], Bs[16][128];
    int tid = threadIdx.x;
    int tx = tid & 15, ty = tid >> 4;
    float acc[8][8] = {};
    for (int k0=0;k0<DSTATE;k0+=16){
#pragma unroll
        for (int rep=0;rep<8;++rep){
            int e = rep*256 + tid;
            int l = e >> 4, kk2 = e & 15;
            const float* src = xBC + (size_t)(base+l)*DXBC + DINNER + k0 + kk2;
            Bs[kk2][l] = src[0];
            Cs[kk2][l] = src[DSTATE];
        }
        __syncthreads();
#pragma unroll
        for (int k=0;k<16;++k){
            float cv[8], bv[8];
#pragma unroll
            for (int i=0;i<8;++i){ cv[i]=Cs[k][ty*8+i]; bv[i]=Bs[k][tx*8+i]; }
#pragma unroll
            for (int i=0;i<8;++i)
#pragma unroll
                for (int j=0;j<8;++j) acc[i][j] += cv[i]*bv[j];
        }
        __syncthreads();
    }
    size_t cbb = (size_t)(b*NCHUNK+c)*CHUNK*CHUNK;
#pragma unroll
    for (int i=0;i<8;++i)
#pragma unroll
        for (int j=0;j<8;++j)
            CB[cbb + (size_t)(ty*8+i)*CHUNK + tx*8+j] = acc[i][j];
}

// -------- chunk states[h][p][n] = sum_l B[l][n]*exp(Alast-Acum[l])*xd[l][p] --------
__global__ __launch_bounds__(256)
void states_k(const float* __restrict__ xBC, const float* __restrict__ dtb,
              const float* __restrict__ acum, float* __restrict__ states)
{
    int c = blockIdx.x & 31;
    int h = (blockIdx.x>>5) % NHEADS;
    int b = blockIdx.x/(32*NHEADS);
    int base = b*SEQ + c*CHUNK;
    int tid = threadIdx.x;
    __shared__ float xds[128][64];
    __shared__ float dec[128];
    int arow = ((b*NHEADS+h)*NCHUNK + c)*CHUNK;
#pragma unroll
    for (int rep=0;rep<32;++rep){
        int e = rep*256+tid; int s = e>>6, p = e&63;
        xds[s][p] = xBC[(size_t)(base+s)*DXBC + h*HEADDIM + p] * dtb[(base+s)*NHEADS + h];
    }
    if (tid < 128){
        float alast = acum[arow + 127];
        dec[tid] = expf(alast - acum[arow + tid]);
    }
    __syncthreads();
    int n = tid & 127, ph = tid >> 7;
    float acc[32] = {};
    for (int l=0;l<128;++l){
        float w = xBC[(size_t)(base+l)*DXBC + DINNER + n] * dec[l];
#pragma unroll
        for (int p=0;p<32;++p) acc[p] += w * xds[l][ph*32+p];
    }
    size_t sb = ((size_t)(b*NCHUNK+c)*NHEADS + h)*HEADDIM*DSTATE;
#pragma unroll
    for (int p=0;p<32;++p) states[sb + (size_t)(ph*32+p)*DSTATE + n] = acc[p];
}

// ---- sequential inter-chunk recurrence, in place: states[c] := prev[c] ----
__global__ __launch_bounds__(256)
void recur_k(float* __restrict__ states, const float* __restrict__ acum)
{
    int pb = blockIdx.x & 31;
    int h = (blockIdx.x>>5) % NHEADS;
    int b = blockIdx.x/(32*NHEADS);
    int pn = pb*256 + threadIdx.x;
    float S = 0.f;
    for (int c=0;c<NCHUNK;++c){
        size_t addr = ((size_t)(b*NCHUNK+c)*NHEADS + h)*(HEADDIM*DSTATE) + pn;
        float st = states[addr];
        states[addr] = S;
        float alast = acum[((b*NHEADS+h)*NCHUNK + c)*CHUNK + 127];
        S = S*expf(alast) + st;
    }
}

// ---------------- Y = Y_diag + Y_off + D*x, per (b,c,h); y has row stride ldy ------
__global__ __launch_bounds__(512)
void y_k(const float* __restrict__ xBC, const float* __restrict__ dtb,
         const float* __restrict__ acum, const float* __restrict__ CB,
         const float* __restrict__ states, const float* __restrict__ Dp,
         float* __restrict__ y, int ldy)
{
    int c = blockIdx.x & 31;
    int h = (blockIdx.x>>5) % NHEADS;
    int b = blockIdx.x/(32*NHEADS);
    int base = b*SEQ + c*CHUNK;
    int tid = threadIdx.x;
    __shared__ float xds[128][64];
    __shared__ float prevs[64][128];
    __shared__ float ac[128];
    int arow = ((b*NHEADS+h)*NCHUNK + c)*CHUNK;
    size_t sb = ((size_t)(b*NCHUNK+c)*NHEADS + h)*(HEADDIM*DSTATE);
#pragma unroll
    for (int rep=0;rep<16;++rep){
        int e = rep*512+tid;
        int s = e>>6, p = e&63;
        xds[s][p] = xBC[(size_t)(base+s)*DXBC + h*HEADDIM + p] * dtb[(base+s)*NHEADS + h];
        int pp = e>>7, nn = e&127;
        prevs[pp][nn] = states[sb + e];
    }
    if (tid<128) ac[tid] = acum[arow+tid];
    __syncthreads();
    int l = tid >> 2, pq = (tid&3)*16;
    size_t cbb = (size_t)(b*NCHUNK+c)*CHUNK*CHUNK + (size_t)l*CHUNK;
    const float* crow = xBC + (size_t)(base+l)*DXBC + DINNER + DSTATE;
    float acco[16] = {};
    for (int n=0;n<DSTATE;++n){
        float cl = crow[n];
#pragma unroll
        for (int p=0;p<16;++p) acco[p] += cl * prevs[pq+p][n];
    }
    float accd[16] = {};
    float al = ac[l];
    for (int s=0;s<=l;++s){
        float w = CB[cbb+s] * expf(al - ac[s]);
#pragma unroll
        for (int p=0;p<16;++p) accd[p] += w * xds[s][pq+p];
    }
    float eal = expf(al);
    float Dh = Dp[h];
    const float* xrow = xBC + (size_t)(base+l)*DXBC + h*HEADDIM;
    float* yrow = y + (size_t)(base+l)*ldy + h*HEADDIM;
#pragma unroll
    for (int p=0;p<16;++p)
        yrow[pq+p] = accd[p] + eal*acco[p] + Dh*xrow[pq+p];
}

// ---------------- y *= silu(z); RMSNorm * norm_w (in place, strided) ----------------
__global__ __launch_bounds__(256)
void norm_k(float* __restrict__ y, int ldy, const float* __restrict__ zx,
            const float* __restrict__ nw)
{
    int r = blockIdx.x;
    int tid = threadIdx.x;
    float v[6]; float ss = 0.f;
#pragma unroll
    for (int j=0;j<6;++j){
        int i = j*256 + tid;
        float zv = zx[(size_t)r*DPROJ + i];
        float yv = y[(size_t)r*ldy + i];
        float g = yv * siluf_(zv);
        v[j] = g; ss += g*g;
    }
    for (int off=32; off; off>>=1) ss += __shfl_down(ss, off);
    __shared__ float red[4];
    __shared__ float stot;
    int lane = tid & 63, wid = tid >> 6;
    if (lane==0) red[wid] = ss;
    __syncthreads();
    if (tid==0) stot = red[0]+red[1]+red[2]+red[3];
    __syncthreads();
    float scale = rsqrtf(stot * (1.f/DINNER) + 1e-5f);
#pragma unroll
    for (int j=0;j<6;++j){
        int i = j*256 + tid;
        y[(size_t)r*ldy + i] = v[j]*scale*nw[i];
    }
}

extern "C" void kernel_launch(void* const* d_in, const int* in_sizes, int n_in,
                              void* d_out, int out_size, void* d_ws, size_t ws_size,
                              hipStream_t stream)
{
    const float* feature = (const float*)d_in[0];
    const float* gate1   = (const float*)d_in[1];
    const float* in_w    = (const float*)d_in[2];
    const float* conv_w  = (const float*)d_in[3];
    const float* conv_b  = (const float*)d_in[4];
    const float* dt_bias = (const float*)d_in[5];
    const float* A_log   = (const float*)d_in[6];
    const float* Dp      = (const float*)d_in[7];
    const float* norm_w  = (const float*)d_in[8];
    const float* out_w   = (const float*)d_in[9];
    float* out = (float*)d_out;

    // workspace layout (floats) — total ~224.7 MB (< 256 MiB)
    float* ws = (float*)d_ws;
    float* zx     = ws;  ws += (size_t)ROWS*DPROJ;                              // 109.8 MB
    float* xBC    = ws;  ws += (size_t)ROWS*DXBC;                               // 58.7 MB
    float* dtb    = ws;  ws += (size_t)ROWS*NHEADS;                             // 0.8 MB
    float* acum   = ws;  ws += (size_t)B_SZ*NHEADS*NCHUNK*CHUNK;                // 0.8 MB
    float* CBbuf  = ws;  ws += (size_t)B_SZ*NCHUNK*CHUNK*CHUNK;                 // 4.2 MB
    float* states = ws;  ws += (size_t)B_SZ*NCHUNK*NHEADS*HEADDIM*DSTATE;       // 50.3 MB
    // ybuf overlays the dead xBC/dt columns of zx (cols [DINNER, DINNER+1536)),
    // valid after conv_silu_k + dt_k have consumed them. Row stride = DPROJ.
    float* ybuf = zx + DINNER;

    gemm_nt<false><<<dim3((DPROJ+63)/64, ROWS/64), 256, 0, stream>>>(
        feature, in_w, zx, ROWS, DPROJ, DMODEL, DMODEL, DPROJ, nullptr, nullptr);
    dt_k<<<(ROWS*NHEADS)/256, 256, 0, stream>>>(zx, dt_bias, dtb);
    conv_silu_k<<<(ROWS*DXBC)/256, 256, 0, stream>>>(zx, conv_w, conv_b, xBC);
    scan_k<<<B_SZ*NHEADS*NCHUNK, 128, 0, stream>>>(dtb, A_log, acum);
    cb_k<<<B_SZ*NCHUNK, 256, 0, stream>>>(xBC, CBbuf);
    states_k<<<B_SZ*NHEADS*NCHUNK, 256, 0, stream>>>(xBC, dtb, acum, states);
    recur_k<<<B_SZ*NHEADS*32, 256, 0, stream>>>(states, acum);
    y_k<<<B_SZ*NHEADS*NCHUNK, 512, 0, stream>>>(xBC, dtb, acum, CBbuf, states, Dp, ybuf, DPROJ);
    norm_k<<<ROWS, 256, 0, stream>>>(ybuf, DPROJ, zx, norm_w);
    gemm_nt<true><<<dim3(DMODEL/64, ROWS/64), 256, 0, stream>>>(
        ybuf, out_w, out, ROWS, DMODEL, DINNER, DPROJ, DMODEL, gate1, feature);
}

// Round 3
// 666.741 us; speedup vs baseline: 2.6676x; 2.6676x over previous
//
#include <hip/hip_runtime.h>
#include <hip/hip_bf16.h>
#include <math.h>

#define B_SZ 2
#define SEQ 4096
#define DMODEL 768
#define DSTATE 128
#define HEADDIM 64
#define DINNER 1536
#define NHEADS 24
#define DXBC 1792
#define DPROJ 3352
#define NPAD1 3456
#define CHUNK 128
#define NCHUNK 32
#define ROWS (B_SZ*SEQ)

typedef float floatx4 __attribute__((ext_vector_type(4)));
typedef __bf16 bf16x8 __attribute__((ext_vector_type(8)));

__device__ __forceinline__ float sigmoidf_(float x){ return 1.f/(1.f+expf(-x)); }
__device__ __forceinline__ float siluf_(float x){ return x/(1.f+expf(-x)); }
__device__ __forceinline__ float softplusf_(float x){ return (x>20.f)? x : log1pf(expf(x)); }

__device__ __forceinline__ void gload_lds16(const __hip_bfloat16* g, __hip_bfloat16* l){
    __builtin_amdgcn_global_load_lds(
        (const __attribute__((address_space(1))) void*)g,
        (__attribute__((address_space(3))) void*)l, 16, 0, 0);
}

// -------- bf16 MFMA GEMM: C[M][N] = A[M][K] @ W[N][K]^T ---------------------------
// A: bf16, row stride lda (elements). W: bf16 [Npad][K], K contiguous, rows n>=N zeroed.
// C: fp32, row stride ldc. 128x128 tile, 4 waves (2x2 of 64x64), BK=64.
template<bool EPI>
__global__ __launch_bounds__(256)
void gemm_mfma(const __hip_bfloat16* __restrict__ A, int lda,
               const __hip_bfloat16* __restrict__ W,
               float* __restrict__ C, int ldc, int N, int K,
               const float* __restrict__ gate, const float* __restrict__ resid, int ldr)
{
    __shared__ __align__(16) __hip_bfloat16 Asm[128*64];
    __shared__ __align__(16) __hip_bfloat16 Wsm[128*64];
    const int tid = threadIdx.x;
    const int lane = tid & 63, wave = tid >> 6;
    const int bm = blockIdx.y*128, bn = blockIdx.x*128;
    const int wm = (wave & 1)*64, wn = (wave >> 1)*64;
    floatx4 acc[4][4] = {};

    for (int k0 = 0; k0 < K; k0 += 64) {
        // stage A-tile and W-tile: 128 rows x 64 cols bf16 each (16 KB), 16B/lane
#pragma unroll
        for (int j = 0; j < 4; ++j) {
            int c = j*256 + tid;            // chunk id 0..1023
            int row = c >> 3, kc = (c & 7)*8;
            gload_lds16(A + (size_t)(bm+row)*lda + k0 + kc, Asm + c*8);
            gload_lds16(W + (size_t)(bn+row)*K  + k0 + kc, Wsm + c*8);
        }
        __syncthreads();     // compiler drains vmcnt before barrier
#pragma unroll
        for (int ks = 0; ks < 2; ++ks) {
            const int kq = (lane >> 4)*8 + ks*32;
            const int r16 = lane & 15;
            bf16x8 af[4], wf[4];
#pragma unroll
            for (int i = 0; i < 4; ++i) {
                af[i] = *(const bf16x8*)(Asm + (wm + i*16 + r16)*64 + kq);
                wf[i] = *(const bf16x8*)(Wsm + (wn + i*16 + r16)*64 + kq);
            }
#pragma unroll
            for (int mi = 0; mi < 4; ++mi)
#pragma unroll
                for (int ni = 0; ni < 4; ++ni)
                    acc[mi][ni] = __builtin_amdgcn_mfma_f32_16x16x32_bf16(
                        af[mi], wf[ni], acc[mi][ni], 0, 0, 0);
        }
        __syncthreads();
    }

    float gs = 0.f;
    if (EPI) gs = sigmoidf_(gate[0]);
    const int col = lane & 15, rowq = (lane >> 4)*4;
#pragma unroll
    for (int mi = 0; mi < 4; ++mi) {
#pragma unroll
        for (int ni = 0; ni < 4; ++ni) {
            int n = bn + wn + ni*16 + col;
            int m0 = bm + wm + mi*16 + rowq;
#pragma unroll
            for (int r = 0; r < 4; ++r) {
                float v = acc[mi][ni][r];
                size_t off = (size_t)(m0+r)*ldc + n;
                if (EPI)
                    C[off] = gs*v + resid[(size_t)(m0+r)*ldr + n];
                else if (n < N)
                    C[off] = v;
            }
        }
    }
}

// ---------------- fp32 -> bf16 casts ----------------
__global__ __launch_bounds__(256)
void cast_k(const float* __restrict__ src, __hip_bfloat16* __restrict__ dst, int n)
{
    int i = blockIdx.x*256 + threadIdx.x;
    if (i < n) dst[i] = __float2bfloat16(src[i]);
}
__global__ __launch_bounds__(256)
void cast_w1_k(const float* __restrict__ src, __hip_bfloat16* __restrict__ dst)
{
    int i = blockIdx.x*256 + threadIdx.x;
    if (i >= NPAD1*DMODEL) return;
    int n = i / DMODEL, k = i % DMODEL;
    dst[i] = __float2bfloat16(n < DPROJ ? src[(size_t)n*DMODEL + k] : 0.f);
}

// ---------------- dt = softplus(raw + dt_bias) ----------------
__global__ __launch_bounds__(256)
void dt_k(const float* __restrict__ zx, const float* __restrict__ dt_bias,
          float* __restrict__ dtb)
{
    int idx = blockIdx.x*256 + threadIdx.x;
    if (idx >= ROWS*NHEADS) return;
    int h = idx % NHEADS; int r = idx / NHEADS;
    float x = zx[(size_t)r*DPROJ + (DINNER+DXBC) + h] + dt_bias[h];
    dtb[idx] = softplusf_(x);
}

// ---------------- causal conv(4) + SiLU ----------------
__global__ __launch_bounds__(256)
void conv_silu_k(const float* __restrict__ zx, const float* __restrict__ cw,
                 const float* __restrict__ cb, float* __restrict__ xBC)
{
    int idx = blockIdx.x*256 + threadIdx.x;
    if (idx >= ROWS*DXBC) return;
    int ch = idx % DXBC;
    int r  = idx / DXBC;
    int l  = r & (SEQ-1);
    float4 w4 = *(const float4*)(cw + ch*4);
    float wv[4] = {w4.x, w4.y, w4.z, w4.w};
    float acc = cb[ch];
#pragma unroll
    for (int k=0;k<4;++k){
        int li = l - 3 + k;
        if (li >= 0) acc += wv[k] * zx[(size_t)(r-3+k)*DPROJ + DINNER + ch];
    }
    xBC[(size_t)idx] = siluf_(acc);
}

// ---------------- intra-chunk inclusive cumsum of dt*A ----------------
__global__ __launch_bounds__(128)
void scan_k(const float* __restrict__ dtb, const float* __restrict__ A_log,
            float* __restrict__ acum)
{
    int c = blockIdx.x & 31;
    int h = (blockIdx.x >> 5) % NHEADS;
    int b = blockIdx.x / (32*NHEADS);
    int l = threadIdx.x;
    float A = -expf(A_log[h]);
    int row = b*SEQ + c*CHUNK + l;
    float v = dtb[row*NHEADS + h] * A;
    __shared__ float sh[128];
    sh[l] = v; __syncthreads();
    for (int off=1; off<128; off<<=1){
        float t = (l>=off) ? sh[l-off] : 0.f;
        __syncthreads();
        sh[l] += t;
        __syncthreads();
    }
    acum[((b*NHEADS+h)*NCHUNK + c)*CHUNK + l] = sh[l];
}

// ---------------- CB[l][s] = sum_n C[l][n]*B[s][n], per chunk ----------------
__global__ __launch_bounds__(256)
void cb_k(const float* __restrict__ xBC, float* __restrict__ CB)
{
    int c = blockIdx.x & 31; int b = blockIdx.x >> 5;
    int base = b*SEQ + c*CHUNK;
    __shared__ float Cs[16][128], Bs[16][128];
    int tid = threadIdx.x;
    int tx = tid & 15, ty = tid >> 4;
    float acc[8][8] = {};
    for (int k0=0;k0<DSTATE;k0+=16){
#pragma unroll
        for (int rep=0;rep<8;++rep){
            int e = rep*256 + tid;
            int l = e >> 4, kk2 = e & 15;
            const float* src = xBC + (size_t)(base+l)*DXBC + DINNER + k0 + kk2;
            Bs[kk2][l] = src[0];
            Cs[kk2][l] = src[DSTATE];
        }
        __syncthreads();
#pragma unroll
        for (int k=0;k<16;++k){
            float cv[8], bv[8];
#pragma unroll
            for (int i=0;i<8;++i){ cv[i]=Cs[k][ty*8+i]; bv[i]=Bs[k][tx*8+i]; }
#pragma unroll
            for (int i=0;i<8;++i)
#pragma unroll
                for (int j=0;j<8;++j) acc[i][j] += cv[i]*bv[j];
        }
        __syncthreads();
    }
    size_t cbb = (size_t)(b*NCHUNK+c)*CHUNK*CHUNK;
#pragma unroll
    for (int i=0;i<8;++i)
#pragma unroll
        for (int j=0;j<8;++j)
            CB[cbb + (size_t)(ty*8+i)*CHUNK + tx*8+j] = acc[i][j];
}

// -------- chunk states[h][p][n] = sum_l B[l][n]*exp(Alast-Acum[l])*xd[l][p] --------
__global__ __launch_bounds__(256)
void states_k(const float* __restrict__ xBC, const float* __restrict__ dtb,
              const float* __restrict__ acum, float* __restrict__ states)
{
    int c = blockIdx.x & 31;
    int h = (blockIdx.x>>5) % NHEADS;
    int b = blockIdx.x/(32*NHEADS);
    int base = b*SEQ + c*CHUNK;
    int tid = threadIdx.x;
    __shared__ float xds[128][64];
    __shared__ float dec[128];
    int arow = ((b*NHEADS+h)*NCHUNK + c)*CHUNK;
#pragma unroll
    for (int rep=0;rep<32;++rep){
        int e = rep*256+tid; int s = e>>6, p = e&63;
        xds[s][p] = xBC[(size_t)(base+s)*DXBC + h*HEADDIM + p] * dtb[(base+s)*NHEADS + h];
    }
    if (tid < 128){
        float alast = acum[arow + 127];
        dec[tid] = expf(alast - acum[arow + tid]);
    }
    __syncthreads();
    int n = tid & 127, ph = tid >> 7;
    float acc[32] = {};
    for (int l=0;l<128;++l){
        float w = xBC[(size_t)(base+l)*DXBC + DINNER + n] * dec[l];
#pragma unroll
        for (int p=0;p<32;++p) acc[p] += w * xds[l][ph*32+p];
    }
    size_t sb = ((size_t)(b*NCHUNK+c)*NHEADS + h)*HEADDIM*DSTATE;
#pragma unroll
    for (int p=0;p<32;++p) states[sb + (size_t)(ph*32+p)*DSTATE + n] = acc[p];
}

// ---- sequential inter-chunk recurrence, in place: states[c] := prev[c] ----
__global__ __launch_bounds__(256)
void recur_k(float* __restrict__ states, const float* __restrict__ acum)
{
    int pb = blockIdx.x & 31;
    int h = (blockIdx.x>>5) % NHEADS;
    int b = blockIdx.x/(32*NHEADS);
    int pn = pb*256 + threadIdx.x;
    float S = 0.f;
    for (int c=0;c<NCHUNK;++c){
        size_t addr = ((size_t)(b*NCHUNK+c)*NHEADS + h)*(HEADDIM*DSTATE) + pn;
        float st = states[addr];
        states[addr] = S;
        float alast = acum[((b*NHEADS+h)*NCHUNK + c)*CHUNK + 127];
        S = S*expf(alast) + st;
    }
}

// ---------------- Y = Y_diag + Y_off + D*x, per (b,c,h); y fp32, stride ldy ------
__global__ __launch_bounds__(512)
void y_k(const float* __restrict__ xBC, const float* __restrict__ dtb,
         const float* __restrict__ acum, const float* __restrict__ CB,
         const float* __restrict__ states, const float* __restrict__ Dp,
         float* __restrict__ y, int ldy)
{
    int c = blockIdx.x & 31;
    int h = (blockIdx.x>>5) % NHEADS;
    int b = blockIdx.x/(32*NHEADS);
    int base = b*SEQ + c*CHUNK;
    int tid = threadIdx.x;
    __shared__ float xds[128][64];
    __shared__ float prevs[64][128];
    __shared__ float ac[128];
    int arow = ((b*NHEADS+h)*NCHUNK + c)*CHUNK;
    size_t sb = ((size_t)(b*NCHUNK+c)*NHEADS + h)*(HEADDIM*DSTATE);
#pragma unroll
    for (int rep=0;rep<16;++rep){
        int e = rep*512+tid;
        int s = e>>6, p = e&63;
        xds[s][p] = xBC[(size_t)(base+s)*DXBC + h*HEADDIM + p] * dtb[(base+s)*NHEADS + h];
        int pp = e>>7, nn = e&127;
        prevs[pp][nn] = states[sb + e];
    }
    if (tid<128) ac[tid] = acum[arow+tid];
    __syncthreads();
    int l = tid >> 2, pq = (tid&3)*16;
    size_t cbb = (size_t)(b*NCHUNK+c)*CHUNK*CHUNK + (size_t)l*CHUNK;
    const float* crow = xBC + (size_t)(base+l)*DXBC + DINNER + DSTATE;
    float acco[16] = {};
    for (int n=0;n<DSTATE;++n){
        float cl = crow[n];
#pragma unroll
        for (int p=0;p<16;++p) acco[p] += cl * prevs[pq+p][n];
    }
    float accd[16] = {};
    float al = ac[l];
    for (int s=0;s<=l;++s){
        float w = CB[cbb+s] * expf(al - ac[s]);
#pragma unroll
        for (int p=0;p<16;++p) accd[p] += w * xds[s][pq+p];
    }
    float eal = expf(al);
    float Dh = Dp[h];
    const float* xrow = xBC + (size_t)(base+l)*DXBC + h*HEADDIM;
    float* yrow = y + (size_t)(base+l)*ldy + h*HEADDIM;
#pragma unroll
    for (int p=0;p<16;++p)
        yrow[pq+p] = accd[p] + eal*acco[p] + Dh*xrow[pq+p];
}

// ------- y *= silu(z); RMSNorm * norm_w; emit bf16 (strided overlay) -------------
__global__ __launch_bounds__(256)
void norm_k(const float* __restrict__ y, int ldy, const float* __restrict__ zx,
            const float* __restrict__ nw, __hip_bfloat16* __restrict__ yb, int ldyb)
{
    int r = blockIdx.x;
    int tid = threadIdx.x;
    float v[6]; float ss = 0.f;
#pragma unroll
    for (int j=0;j<6;++j){
        int i = j*256 + tid;
        float zv = zx[(size_t)r*DPROJ + i];
        float yv = y[(size_t)r*ldy + i];
        float g = yv * siluf_(zv);
        v[j] = g; ss += g*g;
    }
    for (int off=32; off; off>>=1) ss += __shfl_down(ss, off);
    __shared__ float red[4];
    __shared__ float stot;
    int lane = tid & 63, wid = tid >> 6;
    if (lane==0) red[wid] = ss;
    __syncthreads();      // also guarantees all fp32 y reads precede bf16 overlay writes
    if (tid==0) stot = red[0]+red[1]+red[2]+red[3];
    __syncthreads();
    float scale = rsqrtf(stot * (1.f/DINNER) + 1e-5f);
#pragma unroll
    for (int j=0;j<6;++j){
        int i = j*256 + tid;
        yb[(size_t)r*ldyb + i] = __float2bfloat16(v[j]*scale*nw[i]);
    }
}

extern "C" void kernel_launch(void* const* d_in, const int* in_sizes, int n_in,
                              void* d_out, int out_size, void* d_ws, size_t ws_size,
                              hipStream_t stream)
{
    const float* feature = (const float*)d_in[0];
    const float* gate1   = (const float*)d_in[1];
    const float* in_w    = (const float*)d_in[2];
    const float* conv_w  = (const float*)d_in[3];
    const float* conv_b  = (const float*)d_in[4];
    const float* dt_bias = (const float*)d_in[5];
    const float* A_log   = (const float*)d_in[6];
    const float* Dp      = (const float*)d_in[7];
    const float* norm_w  = (const float*)d_in[8];
    const float* out_w   = (const float*)d_in[9];
    float* out = (float*)d_out;

    // workspace layout — total ~245 MB (< 256 MiB)
    float* ws = (float*)d_ws;
    float* zx     = ws;  ws += (size_t)ROWS*DPROJ;                              // 109.8 MB
    float* xBC    = ws;  ws += (size_t)ROWS*DXBC;                               // 58.7 MB
    float* dtb    = ws;  ws += (size_t)ROWS*NHEADS;                             // 0.8 MB
    float* acum   = ws;  ws += (size_t)B_SZ*NHEADS*NCHUNK*CHUNK;                // 0.8 MB
    float* CBbuf  = ws;  ws += (size_t)B_SZ*NCHUNK*CHUNK*CHUNK;                 // 4.2 MB
    float* states = ws;  ws += (size_t)B_SZ*NCHUNK*NHEADS*HEADDIM*DSTATE;       // 50.3 MB
    __hip_bfloat16* fbf  = (__hip_bfloat16*)ws;  ws += (size_t)ROWS*DMODEL/2;   // 12.6 MB
    __hip_bfloat16* wbf  = (__hip_bfloat16*)ws;  ws += (size_t)NPAD1*DMODEL/2;  //  5.3 MB
    __hip_bfloat16* owbf = (__hip_bfloat16*)ws;  ws += (size_t)DMODEL*DINNER/2; //  2.4 MB
    // ybuf (fp32 SSD out) and ybf (bf16 normed) overlay zx's dead xBC/dt columns.
    float* ybuf = zx + DINNER;                       // fp32, row stride DPROJ
    __hip_bfloat16* ybf = (__hip_bfloat16*)(zx + DINNER); // bf16, row stride DPROJ*2

    cast_k<<<(ROWS*DMODEL+255)/256, 256, 0, stream>>>(feature, fbf, ROWS*DMODEL);
    cast_w1_k<<<(NPAD1*DMODEL+255)/256, 256, 0, stream>>>(in_w, wbf);
    cast_k<<<(DMODEL*DINNER+255)/256, 256, 0, stream>>>(out_w, owbf, DMODEL*DINNER);

    gemm_mfma<false><<<dim3(NPAD1/128, ROWS/128), 256, 0, stream>>>(
        fbf, DMODEL, wbf, zx, DPROJ, DPROJ, DMODEL, nullptr, nullptr, 0);
    dt_k<<<(ROWS*NHEADS)/256, 256, 0, stream>>>(zx, dt_bias, dtb);
    conv_silu_k<<<(ROWS*DXBC)/256, 256, 0, stream>>>(zx, conv_w, conv_b, xBC);
    scan_k<<<B_SZ*NHEADS*NCHUNK, 128, 0, stream>>>(dtb, A_log, acum);
    cb_k<<<B_SZ*NCHUNK, 256, 0, stream>>>(xBC, CBbuf);
    states_k<<<B_SZ*NHEADS*NCHUNK, 256, 0, stream>>>(xBC, dtb, acum, states);
    recur_k<<<B_SZ*NHEADS*32, 256, 0, stream>>>(states, acum);
    y_k<<<B_SZ*NHEADS*NCHUNK, 512, 0, stream>>>(xBC, dtb, acum, CBbuf, states, Dp, ybuf, DPROJ);
    norm_k<<<ROWS, 256, 0, stream>>>(ybuf, DPROJ, zx, norm_w, ybf, DPROJ*2);
    gemm_mfma<true><<<dim3(DMODEL/128, ROWS/128), 256, 0, stream>>>(
        ybf, DPROJ*2, owbf, out, DMODEL, DMODEL, DINNER, gate1, feature, DMODEL);
}

// Round 4
// 482.098 us; speedup vs baseline: 3.6893x; 1.3830x over previous
//
#include <hip/hip_runtime.h>
#include <hip/hip_bf16.h>
#include <math.h>

#define B_SZ 2
#define SEQ 4096
#define DMODEL 768
#define DSTATE 128
#define HEADDIM 64
#define DINNER 1536
#define NHEADS 24
#define DXBC 1792
#define DPROJ 3352
#define NPAD1 3456
#define CHUNK 128
#define NCHUNK 32
#define ROWS (B_SZ*SEQ)
#define LDT 136   // padded row stride (bf16 elems) for 128-wide LDS tiles
#define LDC 72    // padded row stride for 64-wide LDS tiles (cb kernel)

typedef float floatx4 __attribute__((ext_vector_type(4)));
typedef __bf16 bf16x8 __attribute__((ext_vector_type(8)));

__device__ __forceinline__ float sigmoidf_(float x){ return 1.f/(1.f+expf(-x)); }
__device__ __forceinline__ float siluf_(float x){ return x/(1.f+expf(-x)); }
__device__ __forceinline__ float softplusf_(float x){ return (x>20.f)? x : log1pf(expf(x)); }

__device__ __forceinline__ void gload_lds16(const __hip_bfloat16* g, __hip_bfloat16* l){
    __builtin_amdgcn_global_load_lds(
        (const __attribute__((address_space(1))) void*)g,
        (__attribute__((address_space(3))) void*)l, 16, 0, 0);
}

// -------- bf16 MFMA GEMM: C[M][N] = A[M][K] @ W[N][K]^T ---------------------------
template<bool EPI>
__global__ __launch_bounds__(256)
void gemm_mfma(const __hip_bfloat16* __restrict__ A, int lda,
               const __hip_bfloat16* __restrict__ W,
               float* __restrict__ C, int ldc, int N, int K,
               const float* __restrict__ gate, const float* __restrict__ resid, int ldr)
{
    __shared__ __align__(16) __hip_bfloat16 Asm[128*64];
    __shared__ __align__(16) __hip_bfloat16 Wsm[128*64];
    const int tid = threadIdx.x;
    const int lane = tid & 63, wave = tid >> 6;
    const int bm = blockIdx.y*128, bn = blockIdx.x*128;
    const int wm = (wave & 1)*64, wn = (wave >> 1)*64;
    floatx4 acc[4][4] = {};

    for (int k0 = 0; k0 < K; k0 += 64) {
#pragma unroll
        for (int j = 0; j < 4; ++j) {
            int c = j*256 + tid;
            int row = c >> 3, kc = (c & 7)*8;
            gload_lds16(A + (size_t)(bm+row)*lda + k0 + kc, Asm + c*8);
            gload_lds16(W + (size_t)(bn+row)*K  + k0 + kc, Wsm + c*8);
        }
        __syncthreads();
#pragma unroll
        for (int ks = 0; ks < 2; ++ks) {
            const int kq = (lane >> 4)*8 + ks*32;
            const int r16 = lane & 15;
            bf16x8 af[4], wf[4];
#pragma unroll
            for (int i = 0; i < 4; ++i) {
                af[i] = *(const bf16x8*)(Asm + (wm + i*16 + r16)*64 + kq);
                wf[i] = *(const bf16x8*)(Wsm + (wn + i*16 + r16)*64 + kq);
            }
#pragma unroll
            for (int mi = 0; mi < 4; ++mi)
#pragma unroll
                for (int ni = 0; ni < 4; ++ni)
                    acc[mi][ni] = __builtin_amdgcn_mfma_f32_16x16x32_bf16(
                        af[mi], wf[ni], acc[mi][ni], 0, 0, 0);
        }
        __syncthreads();
    }

    float gs = 0.f;
    if (EPI) gs = sigmoidf_(gate[0]);
    const int col = lane & 15, rowq = (lane >> 4)*4;
#pragma unroll
    for (int mi = 0; mi < 4; ++mi) {
#pragma unroll
        for (int ni = 0; ni < 4; ++ni) {
            int n = bn + wn + ni*16 + col;
            int m0 = bm + wm + mi*16 + rowq;
#pragma unroll
            for (int r = 0; r < 4; ++r) {
                float v = acc[mi][ni][r];
                size_t off = (size_t)(m0+r)*ldc + n;
                if (EPI)
                    C[off] = gs*v + resid[(size_t)(m0+r)*ldr + n];
                else if (n < N)
                    C[off] = v;
            }
        }
    }
}

// ---------------- fp32 -> bf16 casts ----------------
__global__ __launch_bounds__(256)
void cast_k(const float* __restrict__ src, __hip_bfloat16* __restrict__ dst, int n)
{
    int i = blockIdx.x*256 + threadIdx.x;
    if (i < n) dst[i] = __float2bfloat16(src[i]);
}
__global__ __launch_bounds__(256)
void cast_w1_k(const float* __restrict__ src, __hip_bfloat16* __restrict__ dst)
{
    int i = blockIdx.x*256 + threadIdx.x;
    if (i >= NPAD1*DMODEL) return;
    int n = i / DMODEL, k = i % DMODEL;
    dst[i] = __float2bfloat16(n < DPROJ ? src[(size_t)n*DMODEL + k] : 0.f);
}

// ---------------- dt = softplus(raw + dt_bias) ----------------
__global__ __launch_bounds__(256)
void dt_k(const float* __restrict__ zx, const float* __restrict__ dt_bias,
          float* __restrict__ dtb)
{
    int idx = blockIdx.x*256 + threadIdx.x;
    if (idx >= ROWS*NHEADS) return;
    int h = idx % NHEADS; int r = idx / NHEADS;
    float x = zx[(size_t)r*DPROJ + (DINNER+DXBC) + h] + dt_bias[h];
    dtb[idx] = softplusf_(x);
}

// ---------------- causal conv(4) + SiLU ----------------
__global__ __launch_bounds__(256)
void conv_silu_k(const float* __restrict__ zx, const float* __restrict__ cw,
                 const float* __restrict__ cb, float* __restrict__ xBC)
{
    int idx = blockIdx.x*256 + threadIdx.x;
    if (idx >= ROWS*DXBC) return;
    int ch = idx % DXBC;
    int r  = idx / DXBC;
    int l  = r & (SEQ-1);
    float4 w4 = *(const float4*)(cw + ch*4);
    float wv[4] = {w4.x, w4.y, w4.z, w4.w};
    float acc = cb[ch];
#pragma unroll
    for (int k=0;k<4;++k){
        int li = l - 3 + k;
        if (li >= 0) acc += wv[k] * zx[(size_t)(r-3+k)*DPROJ + DINNER + ch];
    }
    xBC[(size_t)idx] = siluf_(acc);
}

// ---------------- intra-chunk inclusive cumsum of dt*A ----------------
__global__ __launch_bounds__(128)
void scan_k(const float* __restrict__ dtb, const float* __restrict__ A_log,
            float* __restrict__ acum)
{
    int c = blockIdx.x & 31;
    int h = (blockIdx.x >> 5) % NHEADS;
    int b = blockIdx.x / (32*NHEADS);
    int l = threadIdx.x;
    float A = -expf(A_log[h]);
    int row = b*SEQ + c*CHUNK + l;
    float v = dtb[row*NHEADS + h] * A;
    __shared__ float sh[128];
    sh[l] = v; __syncthreads();
    for (int off=1; off<128; off<<=1){
        float t = (l>=off) ? sh[l-off] : 0.f;
        __syncthreads();
        sh[l] += t;
        __syncthreads();
    }
    acum[((b*NHEADS+h)*NCHUNK + c)*CHUNK + l] = sh[l];
}

// ------------- MFMA CB[l][s] = sum_n C[l][n]*B[s][n], per (b,c), bf16 out -------------
__global__ __launch_bounds__(256)
void cb_mfma(const float* __restrict__ xBC, __hip_bfloat16* __restrict__ CB16)
{
    __shared__ __align__(16) __hip_bfloat16 Cs[128*LDC];
    __shared__ __align__(16) __hip_bfloat16 Bs[128*LDC];
    int c = blockIdx.x & 31, b = blockIdx.x >> 5;
    int base = b*SEQ + c*CHUNK;
    int tid = threadIdx.x;
    int lane = tid & 63, wave = tid >> 6;
    const int r16 = lane & 15, kq = (lane>>4)*8;
    floatx4 acc[2][8] = {};
    for (int k0 = 0; k0 < DSTATE; k0 += 64) {
        for (int rep=0; rep<32; ++rep){
            int e = rep*256 + tid;
            int kk = e & 63, l = e >> 6;
            const float* src = xBC + (size_t)(base+l)*DXBC + DINNER + k0 + kk;
            Bs[l*LDC + kk] = __float2bfloat16(src[0]);
            Cs[l*LDC + kk] = __float2bfloat16(src[DSTATE]);
        }
        __syncthreads();
#pragma unroll
        for (int ks=0; ks<2; ++ks){
#pragma unroll
            for (int mt=0; mt<2; ++mt){
                bf16x8 af = *(const bf16x8*)(Cs + ((wave*2+mt)*16 + r16)*LDC + ks*32 + kq);
#pragma unroll
                for (int st=0; st<8; ++st){
                    bf16x8 bf = *(const bf16x8*)(Bs + (st*16 + r16)*LDC + ks*32 + kq);
                    acc[mt][st] = __builtin_amdgcn_mfma_f32_16x16x32_bf16(af, bf, acc[mt][st], 0,0,0);
                }
            }
        }
        __syncthreads();
    }
    size_t cbb = (size_t)(b*NCHUNK+c)*CHUNK*CHUNK;
    const int scol = lane & 15, rowq = (lane>>4)*4;
#pragma unroll
    for (int mt=0; mt<2; ++mt)
#pragma unroll
        for (int st=0; st<8; ++st)
#pragma unroll
            for (int r=0; r<4; ++r){
                int l = (wave*2+mt)*16 + rowq + r;
                int s = st*16 + scol;
                CB16[cbb + (size_t)l*128 + s] = __float2bfloat16(acc[mt][st][r]);
            }
}

// ---- MFMA chunk states[p][n] = sum_l xd[l][p] * dec[l]*B[l][n], per (b,c,h) ----
__global__ __launch_bounds__(256)
void states_mfma(const float* __restrict__ xBC, const float* __restrict__ dtb,
                 const float* __restrict__ acum, float* __restrict__ states)
{
    __shared__ __align__(16) char smem[52736];
    __hip_bfloat16* BT = (__hip_bfloat16*)smem;            // [128 n][LDT] k=l
    __hip_bfloat16* xT = (__hip_bfloat16*)(smem + 34816);  // [64 p][LDT]  k=l
    float* dec = (float*)(smem + 52224);
    int c = blockIdx.x & 31;
    int h = (blockIdx.x>>5) % NHEADS;
    int b = blockIdx.x/(32*NHEADS);
    int base = b*SEQ + c*CHUNK;
    int tid = threadIdx.x;
    int lane = tid & 63, wave = tid >> 6;
    int arow = ((b*NHEADS+h)*NCHUNK + c)*CHUNK;
    if (tid < 128){
        float alast = acum[arow + 127];
        dec[tid] = expf(alast - acum[arow + tid]);
    }
    __syncthreads();
    for (int rep=0; rep<32; ++rep){
        int e = rep*256 + tid;
        int p = e & 63, s = e >> 6;
        float v = xBC[(size_t)(base+s)*DXBC + h*HEADDIM + p] * dtb[(base+s)*NHEADS + h];
        xT[p*LDT + s] = __float2bfloat16(v);
    }
    for (int rep=0; rep<64; ++rep){
        int e = rep*256 + tid;
        int n = e & 127, l = e >> 7;
        float v = xBC[(size_t)(base+l)*DXBC + DINNER + n] * dec[l];
        BT[n*LDT + l] = __float2bfloat16(v);
    }
    __syncthreads();
    const int r16 = lane & 15, kq = (lane>>4)*8;
    floatx4 acc[8] = {};
#pragma unroll
    for (int ks=0; ks<4; ++ks){
        bf16x8 af = *(const bf16x8*)(xT + (wave*16 + r16)*LDT + ks*32 + kq);
#pragma unroll
        for (int nt=0; nt<8; ++nt){
            bf16x8 bf = *(const bf16x8*)(BT + (nt*16 + r16)*LDT + ks*32 + kq);
            acc[nt] = __builtin_amdgcn_mfma_f32_16x16x32_bf16(af, bf, acc[nt], 0,0,0);
        }
    }
    size_t sb = ((size_t)(b*NCHUNK+c)*NHEADS + h)*(HEADDIM*DSTATE);
    const int ncol = lane & 15, rowq = (lane>>4)*4;
#pragma unroll
    for (int nt=0; nt<8; ++nt)
#pragma unroll
        for (int r=0; r<4; ++r){
            int p = wave*16 + rowq + r;
            int n = nt*16 + ncol;
            states[sb + (size_t)p*DSTATE + n] = acc[nt][r];
        }
}

// ---- sequential inter-chunk recurrence, in place: states[c] := prev[c] ----
__global__ __launch_bounds__(256)
void recur_k(float* __restrict__ states, const float* __restrict__ acum)
{
    int pb = blockIdx.x & 31;
    int h = (blockIdx.x>>5) % NHEADS;
    int b = blockIdx.x/(32*NHEADS);
    int pn = pb*256 + threadIdx.x;
    float S = 0.f;
    for (int c=0;c<NCHUNK;++c){
        size_t addr = ((size_t)(b*NCHUNK+c)*NHEADS + h)*(HEADDIM*DSTATE) + pn;
        float st = states[addr];
        states[addr] = S;
        float alast = acum[((b*NHEADS+h)*NCHUNK + c)*CHUNK + 127];
        S = S*expf(alast) + st;
    }
}

// ---- MFMA Y = tril(CB*exp(dAc)) @ xd  +  (C*exp(ac)) @ prev^T  +  D*x ----
__global__ __launch_bounds__(512)
void y_mfma(const float* __restrict__ xBC, const float* __restrict__ dtb,
            const float* __restrict__ acum, const __hip_bfloat16* __restrict__ CB16,
            const float* __restrict__ states, const float* __restrict__ Dp,
            float* __restrict__ y, int ldy)
{
    __shared__ __align__(16) char smem[52736];
    __hip_bfloat16* Wd = (__hip_bfloat16*)smem;            // phase1: Wd[128 l][LDT] k=s; phase2: Cexp[128 l][LDT] k=n
    __hip_bfloat16* xT = (__hip_bfloat16*)(smem + 34816);  // phase1: xdT[64 p][LDT] k=s; phase2: prev[64 p][LDT] k=n
    float* ac = (float*)(smem + 52224);
    int c = blockIdx.x & 31;
    int h = (blockIdx.x>>5) % NHEADS;
    int b = blockIdx.x/(32*NHEADS);
    int base = b*SEQ + c*CHUNK;
    int tid = threadIdx.x;
    int lane = tid & 63, wave = tid >> 6;
    int arow = ((b*NHEADS+h)*NCHUNK + c)*CHUNK;
    size_t sb  = ((size_t)(b*NCHUNK+c)*NHEADS + h)*(HEADDIM*DSTATE);
    size_t cbb = (size_t)(b*NCHUNK+c)*CHUNK*CHUNK;
    if (tid < 128) ac[tid] = acum[arow + tid];
    __syncthreads();
    // xdT[p][s]
    for (int rep=0; rep<16; ++rep){
        int e = rep*512 + tid;
        int p = e & 63, s = e >> 6;
        float v = xBC[(size_t)(base+s)*DXBC + h*HEADDIM + p] * dtb[(base+s)*NHEADS + h];
        xT[p*LDT + s] = __float2bfloat16(v);
    }
    // Wd[l][s] = tril(CB * exp(ac[l]-ac[s]))
    for (int rep=0; rep<32; ++rep){
        int e = rep*512 + tid;
        int s = e & 127, l = e >> 7;
        float w = 0.f;
        if (s <= l)
            w = __bfloat162float(CB16[cbb + (size_t)l*128 + s]) * expf(ac[l]-ac[s]);
        Wd[l*LDT + s] = __float2bfloat16(w);
    }
    __syncthreads();
    const int r16 = lane & 15, kq = (lane>>4)*8;
    floatx4 acc[4] = {};
    // Y_diag: wave w owns rows l in [16w,16w+16); only k-steps covering s <= l_max
    int nks = (16*(wave+1) + 31) >> 5;
    for (int ks=0; ks<nks; ++ks){
        bf16x8 af = *(const bf16x8*)(Wd + (wave*16 + r16)*LDT + ks*32 + kq);
#pragma unroll
        for (int pt=0; pt<4; ++pt){
            bf16x8 bf = *(const bf16x8*)(xT + (pt*16 + r16)*LDT + ks*32 + kq);
            acc[pt] = __builtin_amdgcn_mfma_f32_16x16x32_bf16(af, bf, acc[pt], 0,0,0);
        }
    }
    __syncthreads();
    // phase 2: Cexp[l][n], prev[p][n]
    for (int rep=0; rep<32; ++rep){
        int e = rep*512 + tid;
        int n = e & 127, l = e >> 7;
        float v = xBC[(size_t)(base+l)*DXBC + DINNER + DSTATE + n] * expf(ac[l]);
        Wd[l*LDT + n] = __float2bfloat16(v);
    }
    for (int rep=0; rep<16; ++rep){
        int e = rep*512 + tid;
        int n = e & 127, p = e >> 7;
        xT[p*LDT + n] = __float2bfloat16(states[sb + (size_t)p*DSTATE + n]);
    }
    __syncthreads();
#pragma unroll
    for (int ks=0; ks<4; ++ks){
        bf16x8 af = *(const bf16x8*)(Wd + (wave*16 + r16)*LDT + ks*32 + kq);
#pragma unroll
        for (int pt=0; pt<4; ++pt){
            bf16x8 bf = *(const bf16x8*)(xT + (pt*16 + r16)*LDT + ks*32 + kq);
            acc[pt] = __builtin_amdgcn_mfma_f32_16x16x32_bf16(af, bf, acc[pt], 0,0,0);
        }
    }
    // epilogue: y = acc + D*x
    float Dh = Dp[h];
    const int pcol = lane & 15, rowq = (lane>>4)*4;
#pragma unroll
    for (int pt=0; pt<4; ++pt)
#pragma unroll
        for (int r=0; r<4; ++r){
            int l = wave*16 + rowq + r;
            int p = pt*16 + pcol;
            float x = xBC[(size_t)(base+l)*DXBC + h*HEADDIM + p];
            y[(size_t)(base+l)*ldy + h*HEADDIM + p] = acc[pt][r] + Dh*x;
        }
}

// ------- y *= silu(z); RMSNorm * norm_w; emit bf16 (strided overlay) -------------
__global__ __launch_bounds__(256)
void norm_k(const float* __restrict__ y, int ldy, const float* __restrict__ zx,
            const float* __restrict__ nw, __hip_bfloat16* __restrict__ yb, int ldyb)
{
    int r = blockIdx.x;
    int tid = threadIdx.x;
    float v[6]; float ss = 0.f;
#pragma unroll
    for (int j=0;j<6;++j){
        int i = j*256 + tid;
        float zv = zx[(size_t)r*DPROJ + i];
        float yv = y[(size_t)r*ldy + i];
        float g = yv * siluf_(zv);
        v[j] = g; ss += g*g;
    }
    for (int off=32; off; off>>=1) ss += __shfl_down(ss, off);
    __shared__ float red[4];
    __shared__ float stot;
    int lane = tid & 63, wid = tid >> 6;
    if (lane==0) red[wid] = ss;
    __syncthreads();
    if (tid==0) stot = red[0]+red[1]+red[2]+red[3];
    __syncthreads();
    float scale = rsqrtf(stot * (1.f/DINNER) + 1e-5f);
#pragma unroll
    for (int j=0;j<6;++j){
        int i = j*256 + tid;
        yb[(size_t)r*ldyb + i] = __float2bfloat16(v[j]*scale*nw[i]);
    }
}

extern "C" void kernel_launch(void* const* d_in, const int* in_sizes, int n_in,
                              void* d_out, int out_size, void* d_ws, size_t ws_size,
                              hipStream_t stream)
{
    const float* feature = (const float*)d_in[0];
    const float* gate1   = (const float*)d_in[1];
    const float* in_w    = (const float*)d_in[2];
    const float* conv_w  = (const float*)d_in[3];
    const float* conv_b  = (const float*)d_in[4];
    const float* dt_bias = (const float*)d_in[5];
    const float* A_log   = (const float*)d_in[6];
    const float* Dp      = (const float*)d_in[7];
    const float* norm_w  = (const float*)d_in[8];
    const float* out_w   = (const float*)d_in[9];
    float* out = (float*)d_out;

    // workspace layout — total ~243 MB (< 256 MiB)
    float* ws = (float*)d_ws;
    float* zx     = ws;  ws += (size_t)ROWS*DPROJ;                              // 109.8 MB
    float* xBC    = ws;  ws += (size_t)ROWS*DXBC;                               // 58.7 MB
    float* dtb    = ws;  ws += (size_t)ROWS*NHEADS;                             // 0.8 MB
    float* acum   = ws;  ws += (size_t)B_SZ*NHEADS*NCHUNK*CHUNK;                // 0.8 MB
    __hip_bfloat16* CB16 = (__hip_bfloat16*)ws; ws += (size_t)B_SZ*NCHUNK*CHUNK*CHUNK/2; // 2.1 MB
    float* states = ws;  ws += (size_t)B_SZ*NCHUNK*NHEADS*HEADDIM*DSTATE;       // 50.3 MB
    __hip_bfloat16* fbf  = (__hip_bfloat16*)ws;  ws += (size_t)ROWS*DMODEL/2;   // 12.6 MB
    __hip_bfloat16* wbf  = (__hip_bfloat16*)ws;  ws += (size_t)NPAD1*DMODEL/2;  //  5.3 MB
    __hip_bfloat16* owbf = (__hip_bfloat16*)ws;  ws += (size_t)DMODEL*DINNER/2; //  2.4 MB
    // ybuf (fp32 SSD out) and ybf (bf16 normed) overlay zx's dead xBC/dt columns.
    float* ybuf = zx + DINNER;                       // fp32, row stride DPROJ
    __hip_bfloat16* ybf = (__hip_bfloat16*)(zx + DINNER); // bf16, row stride DPROJ*2

    cast_k<<<(ROWS*DMODEL+255)/256, 256, 0, stream>>>(feature, fbf, ROWS*DMODEL);
    cast_w1_k<<<(NPAD1*DMODEL+255)/256, 256, 0, stream>>>(in_w, wbf);
    cast_k<<<(DMODEL*DINNER+255)/256, 256, 0, stream>>>(out_w, owbf, DMODEL*DINNER);

    gemm_mfma<false><<<dim3(NPAD1/128, ROWS/128), 256, 0, stream>>>(
        fbf, DMODEL, wbf, zx, DPROJ, DPROJ, DMODEL, nullptr, nullptr, 0);
    dt_k<<<(ROWS*NHEADS)/256, 256, 0, stream>>>(zx, dt_bias, dtb);
    conv_silu_k<<<(ROWS*DXBC)/256, 256, 0, stream>>>(zx, conv_w, conv_b, xBC);
    scan_k<<<B_SZ*NHEADS*NCHUNK, 128, 0, stream>>>(dtb, A_log, acum);
    cb_mfma<<<B_SZ*NCHUNK, 256, 0, stream>>>(xBC, CB16);
    states_mfma<<<B_SZ*NHEADS*NCHUNK, 256, 0, stream>>>(xBC, dtb, acum, states);
    recur_k<<<B_SZ*NHEADS*32, 256, 0, stream>>>(states, acum);
    y_mfma<<<B_SZ*NHEADS*NCHUNK, 512, 0, stream>>>(xBC, dtb, acum, CB16, states, Dp, ybuf, DPROJ);
    norm_k<<<ROWS, 256, 0, stream>>>(ybuf, DPROJ, zx, norm_w, ybf, DPROJ*2);
    gemm_mfma<true><<<dim3(DMODEL/128, ROWS/128), 256, 0, stream>>>(
        ybf, DPROJ*2, owbf, out, DMODEL, DMODEL, DINNER, gate1, feature, DMODEL);
}

// Round 5
// 400.147 us; speedup vs baseline: 4.4449x; 1.2048x over previous
//
#include <hip/hip_runtime.h>
#include <hip/hip_bf16.h>
#include <math.h>

#define B_SZ 2
#define SEQ 4096
#define DMODEL 768
#define DSTATE 128
#define HEADDIM 64
#define DINNER 1536
#define NHEADS 24
#define DXBC 1792
#define DPROJ 3352
#define NPAD1 3456
#define CHUNK 128
#define NCHUNK 32
#define ROWS (B_SZ*SEQ)
#define LDTC 136   // padded LDS stride for conv input tile

typedef float floatx4 __attribute__((ext_vector_type(4)));
typedef __bf16 bf16x8 __attribute__((ext_vector_type(8)));

__device__ __forceinline__ float sigmoidf_(float x){ return 1.f/(1.f+expf(-x)); }
__device__ __forceinline__ float siluf_(float x){ return x/(1.f+expf(-x)); }
__device__ __forceinline__ float softplusf_(float x){ return (x>20.f)? x : log1pf(expf(x)); }

__device__ __forceinline__ void gload_lds16(const __hip_bfloat16* g, __hip_bfloat16* l){
    __builtin_amdgcn_global_load_lds(
        (const __attribute__((address_space(1))) void*)g,
        (__attribute__((address_space(3))) void*)l, 16, 0, 0);
}

// ======== GEMM1: zxbcdt = feature @ in_proj^T, epilogue splits into z / xbc16 / dtraw ====
__global__ __launch_bounds__(256)
void gemm1_mfma(const __hip_bfloat16* __restrict__ A,   // fbf [ROWS][768]
                const __hip_bfloat16* __restrict__ W,   // wbf [3456][768] (rows>=3352 zero)
                float* __restrict__ z, __hip_bfloat16* __restrict__ xbc16,
                float* __restrict__ dtraw)
{
    __shared__ __align__(16) __hip_bfloat16 Asm[128*64];
    __shared__ __align__(16) __hip_bfloat16 Wsm[128*64];
    const int tid = threadIdx.x;
    const int lane = tid & 63, wave = tid >> 6;
    const int bm = blockIdx.y*128, bn = blockIdx.x*128;
    const int wm = (wave & 1)*64, wn = (wave >> 1)*64;
    floatx4 acc[4][4] = {};
    for (int k0 = 0; k0 < DMODEL; k0 += 64) {
#pragma unroll
        for (int j = 0; j < 4; ++j) {
            int cc = j*256 + tid;
            int row = cc >> 3, kc = (cc & 7)*8;
            gload_lds16(A + (size_t)(bm+row)*DMODEL + k0 + kc, Asm + cc*8);
            gload_lds16(W + (size_t)(bn+row)*DMODEL + k0 + kc, Wsm + cc*8);
        }
        __syncthreads();
#pragma unroll
        for (int ks = 0; ks < 2; ++ks) {
            const int kq = (lane >> 4)*8 + ks*32;
            const int r16 = lane & 15;
            bf16x8 af[4], wf[4];
#pragma unroll
            for (int i = 0; i < 4; ++i) {
                af[i] = *(const bf16x8*)(Asm + (wm + i*16 + r16)*64 + kq);
                wf[i] = *(const bf16x8*)(Wsm + (wn + i*16 + r16)*64 + kq);
            }
#pragma unroll
            for (int mi = 0; mi < 4; ++mi)
#pragma unroll
                for (int ni = 0; ni < 4; ++ni)
                    acc[mi][ni] = __builtin_amdgcn_mfma_f32_16x16x32_bf16(
                        af[mi], wf[ni], acc[mi][ni], 0, 0, 0);
        }
        __syncthreads();
    }
    const int col = lane & 15, rowq = (lane >> 4)*4;
#pragma unroll
    for (int mi = 0; mi < 4; ++mi)
#pragma unroll
        for (int ni = 0; ni < 4; ++ni) {
            int n = bn + wn + ni*16 + col;
            int m0 = bm + wm + mi*16 + rowq;
#pragma unroll
            for (int r = 0; r < 4; ++r) {
                float v = acc[mi][ni][r];
                size_t m = m0 + r;
                if (n < DINNER)            z[m*DINNER + n] = v;
                else if (n < DINNER+DXBC)  xbc16[m*DXBC + n - DINNER] = __float2bfloat16(v);
                else if (n < DPROJ)        dtraw[m*NHEADS + n - (DINNER+DXBC)] = v;
            }
        }
}

// ======== GEMM2: out = sigmoid(gate)*(y16 @ out_w^T) + feature ========
__global__ __launch_bounds__(256)
void gemm2_mfma(const __hip_bfloat16* __restrict__ A,   // y16 [ROWS][1536]
                const __hip_bfloat16* __restrict__ W,   // owbf [768][1536]
                float* __restrict__ C,
                const float* __restrict__ gate, const float* __restrict__ resid)
{
    __shared__ __align__(16) __hip_bfloat16 Asm[128*64];
    __shared__ __align__(16) __hip_bfloat16 Wsm[128*64];
    const int tid = threadIdx.x;
    const int lane = tid & 63, wave = tid >> 6;
    const int bm = blockIdx.y*128, bn = blockIdx.x*128;
    const int wm = (wave & 1)*64, wn = (wave >> 1)*64;
    floatx4 acc[4][4] = {};
    for (int k0 = 0; k0 < DINNER; k0 += 64) {
#pragma unroll
        for (int j = 0; j < 4; ++j) {
            int cc = j*256 + tid;
            int row = cc >> 3, kc = (cc & 7)*8;
            gload_lds16(A + (size_t)(bm+row)*DINNER + k0 + kc, Asm + cc*8);
            gload_lds16(W + (size_t)(bn+row)*DINNER + k0 + kc, Wsm + cc*8);
        }
        __syncthreads();
#pragma unroll
        for (int ks = 0; ks < 2; ++ks) {
            const int kq = (lane >> 4)*8 + ks*32;
            const int r16 = lane & 15;
            bf16x8 af[4], wf[4];
#pragma unroll
            for (int i = 0; i < 4; ++i) {
                af[i] = *(const bf16x8*)(Asm + (wm + i*16 + r16)*64 + kq);
                wf[i] = *(const bf16x8*)(Wsm + (wn + i*16 + r16)*64 + kq);
            }
#pragma unroll
            for (int mi = 0; mi < 4; ++mi)
#pragma unroll
                for (int ni = 0; ni < 4; ++ni)
                    acc[mi][ni] = __builtin_amdgcn_mfma_f32_16x16x32_bf16(
                        af[mi], wf[ni], acc[mi][ni], 0, 0, 0);
        }
        __syncthreads();
    }
    float gs = sigmoidf_(gate[0]);
    const int col = lane & 15, rowq = (lane >> 4)*4;
#pragma unroll
    for (int mi = 0; mi < 4; ++mi)
#pragma unroll
        for (int ni = 0; ni < 4; ++ni) {
            int n = bn + wn + ni*16 + col;
            int m0 = bm + wm + mi*16 + rowq;
#pragma unroll
            for (int r = 0; r < 4; ++r) {
                size_t off = (size_t)(m0+r)*DMODEL + n;
                C[off] = gs*acc[mi][ni][r] + resid[off];
            }
        }
}

// ---------------- fp32 -> bf16 casts ----------------
__global__ __launch_bounds__(256)
void cast_k(const float* __restrict__ src, __hip_bfloat16* __restrict__ dst, int n)
{
    int i = blockIdx.x*256 + threadIdx.x;
    if (i < n) dst[i] = __float2bfloat16(src[i]);
}
__global__ __launch_bounds__(256)
void cast_w1_k(const float* __restrict__ src, __hip_bfloat16* __restrict__ dst)
{
    int i = blockIdx.x*256 + threadIdx.x;
    if (i >= NPAD1*DMODEL) return;
    int n = i / DMODEL, k = i % DMODEL;
    dst[i] = __float2bfloat16(n < DPROJ ? src[(size_t)n*DMODEL + k] : 0.f);
}

// ---------------- dt = softplus(raw + dt_bias) ----------------
__global__ __launch_bounds__(256)
void dt_k(const float* __restrict__ dtraw, const float* __restrict__ dt_bias,
          float* __restrict__ dtb)
{
    int idx = blockIdx.x*256 + threadIdx.x;
    if (idx >= ROWS*NHEADS) return;
    int h = idx % NHEADS;
    dtb[idx] = softplusf_(dtraw[idx] + dt_bias[h]);
}

// ======== conv4+SiLU, emits x_bf/x_t/B_n/B_t/C_n in MFMA-ready layouts ========
// grid (14 ch-tiles, 32 l-tiles, B), 256 thr. ch-tiles 0..11 = x, 12 = B, 13 = C.
__global__ __launch_bounds__(256)
void conv_k(const __hip_bfloat16* __restrict__ xbc16, const float* __restrict__ cw,
            const float* __restrict__ cbias,
            __hip_bfloat16* __restrict__ x_bf, __hip_bfloat16* __restrict__ x_t,
            __hip_bfloat16* __restrict__ B_n, __hip_bfloat16* __restrict__ B_t,
            __hip_bfloat16* __restrict__ C_n)
{
    __shared__ __align__(16) __hip_bfloat16 in[131*LDTC];
    int ct = blockIdx.x, lt = blockIdx.y, b = blockIdx.z;
    int tid = threadIdx.x;
    int base = lt*128;
    // stage rows base-3 .. base+127, 128 channels, bf16x8 vectors
    for (int it = 0; it < 2096; it += 256) {
        int e = it + tid; if (e >= 2096) break;
        int row = e >> 4, c0 = (e & 15)*8;
        int l = base - 3 + row;
        bf16x8 v;
        if (l < 0) { for (int j = 0; j < 8; ++j) v[j] = (__bf16)0.f; }
        else v = *(const bf16x8*)(xbc16 + ((size_t)b*SEQ + l)*DXBC + ct*128 + c0);
        *(bf16x8*)(in + row*LDTC + c0) = v;
    }
    __syncthreads();
    int ch = tid & 127, lh = tid >> 7, l0 = lh*64;
    int g = ct*128 + ch;
    float w0 = cw[g*4+0], w1 = cw[g*4+1], w2 = cw[g*4+2], w3 = cw[g*4+3];
    float bias = cbias[g];
    float a0 = __bfloat162float(in[(l0+0)*LDTC + ch]);
    float a1 = __bfloat162float(in[(l0+1)*LDTC + ch]);
    float a2 = __bfloat162float(in[(l0+2)*LDTC + ch]);
    // transposed-destination row
    size_t trow = 0;
    if (ct < 12)      trow = ((size_t)b*NHEADS + (g>>6))*HEADDIM + (g & 63);
    else if (ct == 12) trow = (size_t)b*DSTATE + ch;
    bf16x8 obuf;
#pragma unroll
    for (int li = 0; li < 64; ++li) {
        float a3 = __bfloat162float(in[(l0+li+3)*LDTC + ch]);
        float o = siluf_(bias + w0*a0 + w1*a1 + w2*a2 + w3*a3);
        a0 = a1; a1 = a2; a2 = a3;
        __hip_bfloat16 ob = __float2bfloat16(o);
        size_t rr = (size_t)b*SEQ + base + l0 + li;
        if (ct < 12)       x_bf[rr*DINNER + g] = ob;
        else if (ct == 12) B_n[rr*DSTATE + ch] = ob;
        else               C_n[rr*DSTATE + ch] = ob;
        obuf[li & 7] = *(const __bf16*)&ob;
        if ((li & 7) == 7 && ct <= 12) {
            __hip_bfloat16* dst = (ct < 12) ? x_t : B_t;
            *(bf16x8*)(dst + trow*SEQ + base + l0 + (li - 7)) = obuf;
        }
    }
}

// ---------------- intra-chunk inclusive cumsum of dt*A ----------------
__global__ __launch_bounds__(128)
void scan_k(const float* __restrict__ dtb, const float* __restrict__ A_log,
            float* __restrict__ acum)
{
    int c = blockIdx.x & 31;
    int h = (blockIdx.x >> 5) % NHEADS;
    int b = blockIdx.x / (32*NHEADS);
    int l = threadIdx.x;
    float A = -expf(A_log[h]);
    size_t row = (size_t)b*SEQ + c*CHUNK + l;
    float v = dtb[row*NHEADS + h] * A;
    __shared__ float sh[128];
    sh[l] = v; __syncthreads();
    for (int off=1; off<128; off<<=1){
        float t = (l>=off) ? sh[l-off] : 0.f;
        __syncthreads();
        sh[l] += t;
        __syncthreads();
    }
    acum[((b*NHEADS+h)*NCHUNK + c)*CHUNK + l] = sh[l];
}

// ======== CB[l][s] = sum_n C[l][n]*B[s][n], per (b,c), LDS-free, tril tiles only ========
__global__ __launch_bounds__(256)
void cb_mfma(const __hip_bfloat16* __restrict__ B_n, const __hip_bfloat16* __restrict__ C_n,
             __hip_bfloat16* __restrict__ CB16)
{
    int c = blockIdx.x & 31, b = blockIdx.x >> 5;
    size_t base = (size_t)b*SEQ + c*CHUNK;
    int tid = threadIdx.x, lane = tid & 63, wave = tid >> 6;
    int r16 = lane & 15, kq = (lane>>4)*8;
    floatx4 acc[2][8] = {};
#pragma unroll
    for (int ks = 0; ks < 4; ++ks) {
        int k0 = ks*32 + kq;
        bf16x8 af[2], bfv[8];
#pragma unroll
        for (int mt = 0; mt < 2; ++mt)
            af[mt] = *(const bf16x8*)(C_n + (base + (wave*2+mt)*16 + r16)*DSTATE + k0);
#pragma unroll
        for (int st = 0; st < 8; ++st)
            bfv[st] = *(const bf16x8*)(B_n + (base + st*16 + r16)*DSTATE + k0);
#pragma unroll
        for (int mt = 0; mt < 2; ++mt)
#pragma unroll
            for (int st = 0; st < 8; ++st)
                if (st <= wave*2+mt)
                    acc[mt][st] = __builtin_amdgcn_mfma_f32_16x16x32_bf16(
                        af[mt], bfv[st], acc[mt][st], 0,0,0);
    }
    size_t cbb = (size_t)(b*NCHUNK+c)*CHUNK*CHUNK;
    int scol = lane & 15, rowq = (lane>>4)*4;
#pragma unroll
    for (int mt = 0; mt < 2; ++mt)
#pragma unroll
        for (int st = 0; st < 8; ++st)
            if (st <= wave*2+mt)
#pragma unroll
                for (int r = 0; r < 4; ++r)
                    CB16[cbb + (size_t)((wave*2+mt)*16 + rowq + r)*CHUNK + st*16 + scol] =
                        __float2bfloat16(acc[mt][st][r]);
}

// ======== states[p][n] = sum_l (x[l,p]*f[l]) * B[l,n], f = dt*dec, LDS-free frags ========
__global__ __launch_bounds__(256)
void states_mfma(const __hip_bfloat16* __restrict__ x_t, const __hip_bfloat16* __restrict__ B_t,
                 const float* __restrict__ dtb, const float* __restrict__ acum,
                 __hip_bfloat16* __restrict__ states)
{
    __shared__ float f[128];
    int c = blockIdx.x & 31;
    int h = (blockIdx.x>>5) % NHEADS;
    int b = blockIdx.x/(32*NHEADS);
    int tid = threadIdx.x, lane = tid & 63, wave = tid >> 6;
    int arow = ((b*NHEADS+h)*NCHUNK + c)*CHUNK;
    size_t rbase = (size_t)b*SEQ + c*CHUNK;
    if (tid < 128) {
        float alast = acum[arow + 127];
        f[tid] = dtb[(rbase + tid)*NHEADS + h] * expf(alast - acum[arow + tid]);
    }
    __syncthreads();
    int r16 = lane & 15, kq = (lane>>4)*8;
    size_t xtb = ((size_t)b*NHEADS + h)*HEADDIM;
    int cl = c*CHUNK;
    floatx4 acc[8] = {};
#pragma unroll
    for (int ks = 0; ks < 4; ++ks) {
        int k0 = ks*32 + kq;
        bf16x8 xa = *(const bf16x8*)(x_t + (xtb + wave*16 + r16)*SEQ + cl + k0);
        bf16x8 af;
#pragma unroll
        for (int j = 0; j < 8; ++j)
            af[j] = (__bf16)((float)xa[j] * f[k0 + j]);
        bf16x8 bfv[8];
#pragma unroll
        for (int nt = 0; nt < 8; ++nt)
            bfv[nt] = *(const bf16x8*)(B_t + ((size_t)b*DSTATE + nt*16 + r16)*SEQ + cl + k0);
#pragma unroll
        for (int nt = 0; nt < 8; ++nt)
            acc[nt] = __builtin_amdgcn_mfma_f32_16x16x32_bf16(af, bfv[nt], acc[nt], 0,0,0);
    }
    size_t sb = ((size_t)(b*NCHUNK+c)*NHEADS + h)*(HEADDIM*DSTATE);
    int ncol = lane & 15, rowq = (lane>>4)*4;
#pragma unroll
    for (int nt = 0; nt < 8; ++nt)
#pragma unroll
        for (int r = 0; r < 4; ++r)
            states[sb + (size_t)(wave*16 + rowq + r)*DSTATE + nt*16 + ncol] =
                __float2bfloat16(acc[nt][r]);
}

// ---- sequential inter-chunk recurrence, in place (bf16): states[c] := prev[c] ----
__global__ __launch_bounds__(256)
void recur_k(__hip_bfloat16* __restrict__ states, const float* __restrict__ acum)
{
    int pb = blockIdx.x & 3;
    int bh = blockIdx.x >> 2;
    int h = bh % NHEADS, b = bh / NHEADS;
    int voff = (pb*256 + threadIdx.x)*8;
    float S[8] = {};
    for (int c = 0; c < NCHUNK; ++c) {
        size_t addr = ((size_t)(b*NCHUNK+c)*NHEADS + h)*(HEADDIM*DSTATE) + voff;
        bf16x8 st = *(bf16x8*)(states + addr);
        float e = expf(acum[((b*NHEADS+h)*NCHUNK + c)*CHUNK + 127]);
        bf16x8 pv;
#pragma unroll
        for (int j = 0; j < 8; ++j) {
            pv[j] = (__bf16)S[j];
            S[j] = S[j]*e + (float)st[j];
        }
        *(bf16x8*)(states + addr) = pv;
    }
}

// ======== Y = tril(CB*exp(dAc)*dt) @ x  +  (C*exp(ac)) @ prev^T  +  D*x ========
// 512 thr / 8 waves; wave w owns l-tile w; LDS-free fragment loads.
__global__ __launch_bounds__(512)
void y_mfma(const __hip_bfloat16* __restrict__ x_t, const __hip_bfloat16* __restrict__ x_bf,
            const __hip_bfloat16* __restrict__ C_n, const __hip_bfloat16* __restrict__ CB16,
            const __hip_bfloat16* __restrict__ states, const float* __restrict__ dtb,
            const float* __restrict__ acum, const float* __restrict__ Dp,
            __hip_bfloat16* __restrict__ y16)
{
    __shared__ float ac[128], dts[128];
    int c = blockIdx.x & 31;
    int h = (blockIdx.x>>5) % NHEADS;
    int b = blockIdx.x/(32*NHEADS);
    int tid = threadIdx.x, lane = tid & 63, wave = tid >> 6;
    int arow = ((b*NHEADS+h)*NCHUNK + c)*CHUNK;
    size_t rbase = (size_t)b*SEQ + c*CHUNK;
    if (tid < 128) {
        ac[tid]  = acum[arow + tid];
        dts[tid] = dtb[(rbase + tid)*NHEADS + h];
    }
    __syncthreads();
    int r16 = lane & 15, kq = (lane>>4)*8;
    int l = wave*16 + r16;
    float acl = ac[l];
    size_t cbb = (size_t)(b*NCHUNK+c)*CHUNK*CHUNK;
    size_t xtb = ((size_t)b*NHEADS + h)*HEADDIM;
    int cl = c*CHUNK;
    floatx4 acc[4] = {};
    // phase 1: Y_diag
    int nks = ((wave+1)*16 + 31) >> 5;
    for (int ks = 0; ks < nks; ++ks) {
        int k0 = ks*32 + kq;
        bf16x8 cbv = *(const bf16x8*)(CB16 + cbb + (size_t)l*CHUNK + k0);
        bf16x8 af;
#pragma unroll
        for (int j = 0; j < 8; ++j) {
            int s = k0 + j;
            float w = (s <= l) ? (float)cbv[j] * expf(acl - ac[s]) * dts[s] : 0.f;
            af[j] = (__bf16)w;
        }
        bf16x8 bfv[4];
#pragma unroll
        for (int pt = 0; pt < 4; ++pt)
            bfv[pt] = *(const bf16x8*)(x_t + (xtb + pt*16 + r16)*SEQ + cl + k0);
#pragma unroll
        for (int pt = 0; pt < 4; ++pt)
            acc[pt] = __builtin_amdgcn_mfma_f32_16x16x32_bf16(af, bfv[pt], acc[pt], 0,0,0);
    }
    // phase 2: Y_off
    float eal = expf(acl);
    size_t sb = ((size_t)(b*NCHUNK+c)*NHEADS + h)*(HEADDIM*DSTATE);
#pragma unroll
    for (int ks = 0; ks < 4; ++ks) {
        int k0 = ks*32 + kq;
        bf16x8 cv = *(const bf16x8*)(C_n + (rbase + l)*DSTATE + k0);
        bf16x8 af;
#pragma unroll
        for (int j = 0; j < 8; ++j)
            af[j] = (__bf16)((float)cv[j] * eal);
        bf16x8 bfv[4];
#pragma unroll
        for (int pt = 0; pt < 4; ++pt)
            bfv[pt] = *(const bf16x8*)(states + sb + (size_t)(pt*16 + r16)*DSTATE + k0);
#pragma unroll
        for (int pt = 0; pt < 4; ++pt)
            acc[pt] = __builtin_amdgcn_mfma_f32_16x16x32_bf16(af, bfv[pt], acc[pt], 0,0,0);
    }
    // epilogue: y = acc + D*x
    float Dh = Dp[h];
    int pcol = lane & 15, rowq = (lane>>4)*4;
#pragma unroll
    for (int pt = 0; pt < 4; ++pt)
#pragma unroll
        for (int r = 0; r < 4; ++r) {
            int ll = wave*16 + rowq + r;
            int p = pt*16 + pcol;
            size_t rr = rbase + ll;
            float x = __bfloat162float(x_bf[rr*DINNER + h*HEADDIM + p]);
            y16[rr*DINNER + h*HEADDIM + p] = __float2bfloat16(acc[pt][r] + Dh*x);
        }
}

// ------- y16 *= silu(z); RMSNorm * norm_w (in place, bf16) -------------
__global__ __launch_bounds__(256)
void norm_k(__hip_bfloat16* __restrict__ y16, const float* __restrict__ z,
            const float* __restrict__ nw)
{
    int r = blockIdx.x, tid = threadIdx.x;
    float v[6]; float ss = 0.f;
#pragma unroll
    for (int j = 0; j < 6; ++j) {
        int i = j*256 + tid;
        float zv = z[(size_t)r*DINNER + i];
        float yv = __bfloat162float(y16[(size_t)r*DINNER + i]);
        float g = yv * siluf_(zv);
        v[j] = g; ss += g*g;
    }
    for (int off=32; off; off>>=1) ss += __shfl_down(ss, off);
    __shared__ float red[4];
    __shared__ float stot;
    int lane = tid & 63, wid = tid >> 6;
    if (lane==0) red[wid] = ss;
    __syncthreads();
    if (tid==0) stot = red[0]+red[1]+red[2]+red[3];
    __syncthreads();
    float scale = rsqrtf(stot * (1.f/DINNER) + 1e-5f);
#pragma unroll
    for (int j = 0; j < 6; ++j) {
        int i = j*256 + tid;
        y16[(size_t)r*DINNER + i] = __float2bfloat16(v[j]*scale*nw[i]);
    }
}

extern "C" void kernel_launch(void* const* d_in, const int* in_sizes, int n_in,
                              void* d_out, int out_size, void* d_ws, size_t ws_size,
                              hipStream_t stream)
{
    const float* feature = (const float*)d_in[0];
    const float* gate1   = (const float*)d_in[1];
    const float* in_w    = (const float*)d_in[2];
    const float* conv_w  = (const float*)d_in[3];
    const float* conv_b  = (const float*)d_in[4];
    const float* dt_bias = (const float*)d_in[5];
    const float* A_log   = (const float*)d_in[6];
    const float* Dp      = (const float*)d_in[7];
    const float* norm_w  = (const float*)d_in[8];
    const float* out_w   = (const float*)d_in[9];
    float* out = (float*)d_out;

    // workspace layout — ~211 MB (< 256 MiB)
    char* p = (char*)d_ws;
    float* z      = (float*)p;            p += (size_t)ROWS*DINNER*4;      // 50.3 MB
    __hip_bfloat16* xbc16 = (__hip_bfloat16*)p; p += (size_t)ROWS*DXBC*2;  // 29.4 MB
    float* dtraw  = (float*)p;            p += (size_t)ROWS*NHEADS*4;      // 0.8 MB
    __hip_bfloat16* x_bf = (__hip_bfloat16*)p; p += (size_t)ROWS*DINNER*2; // 25.2 MB
    __hip_bfloat16* x_t  = (__hip_bfloat16*)p; p += (size_t)ROWS*DINNER*2; // 25.2 MB
    __hip_bfloat16* B_n  = (__hip_bfloat16*)p; p += (size_t)ROWS*DSTATE*2; // 2.1 MB
    __hip_bfloat16* B_t  = (__hip_bfloat16*)p; p += (size_t)ROWS*DSTATE*2; // 2.1 MB
    __hip_bfloat16* C_n  = (__hip_bfloat16*)p; p += (size_t)ROWS*DSTATE*2; // 2.1 MB
    float* dtb    = (float*)p;            p += (size_t)ROWS*NHEADS*4;      // 0.8 MB
    float* acum   = (float*)p;            p += (size_t)B_SZ*NHEADS*NCHUNK*CHUNK*4; // 0.8 MB
    __hip_bfloat16* CB16 = (__hip_bfloat16*)p; p += (size_t)B_SZ*NCHUNK*CHUNK*CHUNK*2; // 2.1 MB
    __hip_bfloat16* states = (__hip_bfloat16*)p; p += (size_t)B_SZ*NCHUNK*NHEADS*HEADDIM*DSTATE*2; // 25.2 MB
    __hip_bfloat16* y16  = (__hip_bfloat16*)p; p += (size_t)ROWS*DINNER*2; // 25.2 MB
    __hip_bfloat16* fbf  = (__hip_bfloat16*)p; p += (size_t)ROWS*DMODEL*2; // 12.6 MB
    __hip_bfloat16* wbf  = (__hip_bfloat16*)p; p += (size_t)NPAD1*DMODEL*2;//  5.3 MB
    __hip_bfloat16* owbf = (__hip_bfloat16*)p; p += (size_t)DMODEL*DINNER*2;// 2.4 MB

    cast_k<<<(ROWS*DMODEL+255)/256, 256, 0, stream>>>(feature, fbf, ROWS*DMODEL);
    cast_w1_k<<<(NPAD1*DMODEL+255)/256, 256, 0, stream>>>(in_w, wbf);
    cast_k<<<(DMODEL*DINNER+255)/256, 256, 0, stream>>>(out_w, owbf, DMODEL*DINNER);

    gemm1_mfma<<<dim3(NPAD1/128, ROWS/128), 256, 0, stream>>>(fbf, wbf, z, xbc16, dtraw);
    dt_k<<<(ROWS*NHEADS)/256, 256, 0, stream>>>(dtraw, dt_bias, dtb);
    conv_k<<<dim3(14, 32, B_SZ), 256, 0, stream>>>(xbc16, conv_w, conv_b,
                                                   x_bf, x_t, B_n, B_t, C_n);
    scan_k<<<B_SZ*NHEADS*NCHUNK, 128, 0, stream>>>(dtb, A_log, acum);
    cb_mfma<<<B_SZ*NCHUNK, 256, 0, stream>>>(B_n, C_n, CB16);
    states_mfma<<<B_SZ*NHEADS*NCHUNK, 256, 0, stream>>>(x_t, B_t, dtb, acum, states);
    recur_k<<<B_SZ*NHEADS*4, 256, 0, stream>>>(states, acum);
    y_mfma<<<B_SZ*NHEADS*NCHUNK, 512, 0, stream>>>(x_t, x_bf, C_n, CB16, states,
                                                   dtb, acum, Dp, y16);
    norm_k<<<ROWS, 256, 0, stream>>>(y16, z, norm_w);
    gemm2_mfma<<<dim3(DMODEL/128, ROWS/128), 256, 0, stream>>>(y16, owbf, out, gate1, feature);
}

// Round 6
// 395.703 us; speedup vs baseline: 4.4948x; 1.0112x over previous
//
#include <hip/hip_runtime.h>
#include <hip/hip_bf16.h>
#include <math.h>

#define B_SZ 2
#define SEQ 4096
#define DMODEL 768
#define DSTATE 128
#define HEADDIM 64
#define DINNER 1536
#define NHEADS 24
#define DXBC 1792
#define DPROJ 3352
#define NPAD1 3456
#define CHUNK 128
#define NCHUNK 32
#define ROWS (B_SZ*SEQ)
#define LDTC 136   // padded LDS stride for conv input tile
#define LDE 136    // padded LDS stride (bf16) for gemm1 epilogue tile
#define LDE2 132   // padded LDS stride (fp32) for gemm2 epilogue tile

typedef float floatx4 __attribute__((ext_vector_type(4)));
typedef __bf16 bf16x8 __attribute__((ext_vector_type(8)));

__device__ __forceinline__ float sigmoidf_(float x){ return 1.f/(1.f+expf(-x)); }
__device__ __forceinline__ float siluf_(float x){ return x/(1.f+expf(-x)); }
__device__ __forceinline__ float softplusf_(float x){ return (x>20.f)? x : log1pf(expf(x)); }

__device__ __forceinline__ void gload_lds16(const __hip_bfloat16* g, __hip_bfloat16* l){
    __builtin_amdgcn_global_load_lds(
        (const __attribute__((address_space(1))) void*)g,
        (__attribute__((address_space(3))) void*)l, 16, 0, 0);
}

// ======== GEMM1: zxbcdt = feature @ in_proj^T; epilogue -> z16 / xbc16 / dtb ========
// N-tile -> dest: blocks 0..11 = z (bf16), 12..25 = xbc16, 26 = dt (softplus fused).
__global__ __launch_bounds__(256)
void gemm1_mfma(const __hip_bfloat16* __restrict__ A,   // fbf [ROWS][768]
                const __hip_bfloat16* __restrict__ W,   // wbf [3456][768]
                __hip_bfloat16* __restrict__ z16, __hip_bfloat16* __restrict__ xbc16,
                float* __restrict__ dtb, const float* __restrict__ dt_bias)
{
    __shared__ __align__(16) char smem[128*LDE*2];      // 34816 B
    __hip_bfloat16* Asm = (__hip_bfloat16*)smem;
    __hip_bfloat16* Wsm = Asm + 128*64;
    const int tid = threadIdx.x;
    const int lane = tid & 63, wave = tid >> 6;
    const int bx = blockIdx.x;
    const int bm = blockIdx.y*128, bn = bx*128;
    const int wm = (wave & 1)*64, wn = (wave >> 1)*64;
    floatx4 acc[4][4] = {};
    for (int k0 = 0; k0 < DMODEL; k0 += 64) {
#pragma unroll
        for (int j = 0; j < 4; ++j) {
            int cc = j*256 + tid;
            int row = cc >> 3, kc = (cc & 7)*8;
            gload_lds16(A + (size_t)(bm+row)*DMODEL + k0 + kc, Asm + cc*8);
            gload_lds16(W + (size_t)(bn+row)*DMODEL + k0 + kc, Wsm + cc*8);
        }
        __syncthreads();
#pragma unroll
        for (int ks = 0; ks < 2; ++ks) {
            const int kq = (lane >> 4)*8 + ks*32;
            const int r16 = lane & 15;
            bf16x8 af[4], wf[4];
#pragma unroll
            for (int i = 0; i < 4; ++i) {
                af[i] = *(const bf16x8*)(Asm + (wm + i*16 + r16)*64 + kq);
                wf[i] = *(const bf16x8*)(Wsm + (wn + i*16 + r16)*64 + kq);
            }
#pragma unroll
            for (int mi = 0; mi < 4; ++mi)
#pragma unroll
                for (int ni = 0; ni < 4; ++ni)
                    acc[mi][ni] = __builtin_amdgcn_mfma_f32_16x16x32_bf16(
                        af[mi], wf[ni], acc[mi][ni], 0, 0, 0);
        }
        __syncthreads();
    }
    const int col = lane & 15, rowq = (lane >> 4)*4;
    if (bx == 26) {
        // dt block: only local cols 0..23 live (h index); softplus fused
        if (wn == 0) {
#pragma unroll
            for (int mi = 0; mi < 4; ++mi)
#pragma unroll
                for (int ni = 0; ni < 2; ++ni) {
                    int h = ni*16 + col;
                    if (h < NHEADS)
#pragma unroll
                        for (int r = 0; r < 4; ++r) {
                            int m = bm + wm + mi*16 + rowq + r;
                            dtb[(size_t)m*NHEADS + h] =
                                softplusf_(acc[mi][ni][r] + dt_bias[h]);
                        }
                }
        }
        return;
    }
    // LDS-transpose epilogue: bf16 tile, then full-line vector stores
    __hip_bfloat16* Tsm = (__hip_bfloat16*)smem;
#pragma unroll
    for (int mi = 0; mi < 4; ++mi)
#pragma unroll
        for (int ni = 0; ni < 4; ++ni)
#pragma unroll
            for (int r = 0; r < 4; ++r)
                Tsm[(wm + mi*16 + rowq + r)*LDE + wn + ni*16 + col] =
                    __float2bfloat16(acc[mi][ni][r]);
    __syncthreads();
    __hip_bfloat16* dst; int ldd;
    if (bx < 12) { dst = z16 + bn;            ldd = DINNER; }
    else         { dst = xbc16 + bn - DINNER; ldd = DXBC;  }
#pragma unroll
    for (int it = 0; it < 8; ++it) {
        int e = it*256 + tid;
        int row = e >> 4, c0 = (e & 15)*8;
        bf16x8 v = *(const bf16x8*)(Tsm + row*LDE + c0);
        *(bf16x8*)(dst + (size_t)(bm+row)*ldd + c0) = v;
    }
}

// ======== GEMM2: out = sigmoid(gate)*(y16 @ out_w^T) + feature, LDS fp32 epilogue ====
__global__ __launch_bounds__(256)
void gemm2_mfma(const __hip_bfloat16* __restrict__ A,   // y16 [ROWS][1536]
                const __hip_bfloat16* __restrict__ W,   // owbf [768][1536]
                float* __restrict__ C,
                const float* __restrict__ gate, const float* __restrict__ resid)
{
    __shared__ __align__(16) char smem[128*LDE*2];
    __hip_bfloat16* Asm = (__hip_bfloat16*)smem;
    __hip_bfloat16* Wsm = Asm + 128*64;
    const int tid = threadIdx.x;
    const int lane = tid & 63, wave = tid >> 6;
    const int bm = blockIdx.y*128, bn = blockIdx.x*128;
    const int wm = (wave & 1)*64, wn = (wave >> 1)*64;
    floatx4 acc[4][4] = {};
    for (int k0 = 0; k0 < DINNER; k0 += 64) {
#pragma unroll
        for (int j = 0; j < 4; ++j) {
            int cc = j*256 + tid;
            int row = cc >> 3, kc = (cc & 7)*8;
            gload_lds16(A + (size_t)(bm+row)*DINNER + k0 + kc, Asm + cc*8);
            gload_lds16(W + (size_t)(bn+row)*DINNER + k0 + kc, Wsm + cc*8);
        }
        __syncthreads();
#pragma unroll
        for (int ks = 0; ks < 2; ++ks) {
            const int kq = (lane >> 4)*8 + ks*32;
            const int r16 = lane & 15;
            bf16x8 af[4], wf[4];
#pragma unroll
            for (int i = 0; i < 4; ++i) {
                af[i] = *(const bf16x8*)(Asm + (wm + i*16 + r16)*64 + kq);
                wf[i] = *(const bf16x8*)(Wsm + (wn + i*16 + r16)*64 + kq);
            }
#pragma unroll
            for (int mi = 0; mi < 4; ++mi)
#pragma unroll
                for (int ni = 0; ni < 4; ++ni)
                    acc[mi][ni] = __builtin_amdgcn_mfma_f32_16x16x32_bf16(
                        af[mi], wf[ni], acc[mi][ni], 0, 0, 0);
        }
        __syncthreads();
    }
    float gs = sigmoidf_(gate[0]);
    const int col = lane & 15, rowq = (lane >> 4)*4;
    float* Tsm = (float*)smem;   // 64 x LDE2 fp32
    for (int half = 0; half < 2; ++half) {
        if ((wave & 1) == half) {
#pragma unroll
            for (int mi = 0; mi < 4; ++mi)
#pragma unroll
                for (int ni = 0; ni < 4; ++ni)
#pragma unroll
                    for (int r = 0; r < 4; ++r)
                        Tsm[(mi*16 + rowq + r)*LDE2 + wn + ni*16 + col] = acc[mi][ni][r];
        }
        __syncthreads();
#pragma unroll
        for (int it = 0; it < 8; ++it) {
            int e = it*256 + tid;
            int row = e >> 5, c0 = (e & 31)*4;
            float4 v = *(const float4*)(Tsm + row*LDE2 + c0);
            size_t off = (size_t)(bm + half*64 + row)*DMODEL + bn + c0;
            float4 rv = *(const float4*)(resid + off);
            v.x = gs*v.x + rv.x; v.y = gs*v.y + rv.y;
            v.z = gs*v.z + rv.z; v.w = gs*v.w + rv.w;
            *(float4*)(C + off) = v;
        }
        __syncthreads();
    }
}

// ---------------- fp32 -> bf16 casts ----------------
__global__ __launch_bounds__(256)
void cast_k(const float* __restrict__ src, __hip_bfloat16* __restrict__ dst, int n)
{
    int i = blockIdx.x*256 + threadIdx.x;
    if (i < n) dst[i] = __float2bfloat16(src[i]);
}
__global__ __launch_bounds__(256)
void cast_w1_k(const float* __restrict__ src, __hip_bfloat16* __restrict__ dst)
{
    int i = blockIdx.x*256 + threadIdx.x;
    if (i >= NPAD1*DMODEL) return;
    int n = i / DMODEL, k = i % DMODEL;
    dst[i] = __float2bfloat16(n < DPROJ ? src[(size_t)n*DMODEL + k] : 0.f);
}

// ======== conv4+SiLU, emits x_bf/x_t/B_n/B_t/C_n in MFMA-ready layouts ========
__global__ __launch_bounds__(256)
void conv_k(const __hip_bfloat16* __restrict__ xbc16, const float* __restrict__ cw,
            const float* __restrict__ cbias,
            __hip_bfloat16* __restrict__ x_bf, __hip_bfloat16* __restrict__ x_t,
            __hip_bfloat16* __restrict__ B_n, __hip_bfloat16* __restrict__ B_t,
            __hip_bfloat16* __restrict__ C_n)
{
    __shared__ __align__(16) __hip_bfloat16 in[131*LDTC];
    int ct = blockIdx.x, lt = blockIdx.y, b = blockIdx.z;
    int tid = threadIdx.x;
    int base = lt*128;
    for (int it = 0; it < 2096; it += 256) {
        int e = it + tid; if (e >= 2096) break;
        int row = e >> 4, c0 = (e & 15)*8;
        int l = base - 3 + row;
        bf16x8 v;
        if (l < 0) { for (int j = 0; j < 8; ++j) v[j] = (__bf16)0.f; }
        else v = *(const bf16x8*)(xbc16 + ((size_t)b*SEQ + l)*DXBC + ct*128 + c0);
        *(bf16x8*)(in + row*LDTC + c0) = v;
    }
    __syncthreads();
    int ch = tid & 127, lh = tid >> 7, l0 = lh*64;
    int g = ct*128 + ch;
    float w0 = cw[g*4+0], w1 = cw[g*4+1], w2 = cw[g*4+2], w3 = cw[g*4+3];
    float bias = cbias[g];
    float a0 = __bfloat162float(in[(l0+0)*LDTC + ch]);
    float a1 = __bfloat162float(in[(l0+1)*LDTC + ch]);
    float a2 = __bfloat162float(in[(l0+2)*LDTC + ch]);
    size_t trow = 0;
    if (ct < 12)      trow = ((size_t)b*NHEADS + (g>>6))*HEADDIM + (g & 63);
    else if (ct == 12) trow = (size_t)b*DSTATE + ch;
    bf16x8 obuf;
#pragma unroll
    for (int li = 0; li < 64; ++li) {
        float a3 = __bfloat162float(in[(l0+li+3)*LDTC + ch]);
        float o = siluf_(bias + w0*a0 + w1*a1 + w2*a2 + w3*a3);
        a0 = a1; a1 = a2; a2 = a3;
        __hip_bfloat16 ob = __float2bfloat16(o);
        size_t rr = (size_t)b*SEQ + base + l0 + li;
        if (ct < 12)       x_bf[rr*DINNER + g] = ob;
        else if (ct == 12) B_n[rr*DSTATE + ch] = ob;
        else               C_n[rr*DSTATE + ch] = ob;
        obuf[li & 7] = *(const __bf16*)&ob;
        if ((li & 7) == 7 && ct <= 12) {
            __hip_bfloat16* dst = (ct < 12) ? x_t : B_t;
            *(bf16x8*)(dst + trow*SEQ + base + l0 + (li - 7)) = obuf;
        }
    }
}

// ---------------- intra-chunk inclusive cumsum of dt*A ----------------
__global__ __launch_bounds__(128)
void scan_k(const float* __restrict__ dtb, const float* __restrict__ A_log,
            float* __restrict__ acum)
{
    int c = blockIdx.x & 31;
    int h = (blockIdx.x >> 5) % NHEADS;
    int b = blockIdx.x / (32*NHEADS);
    int l = threadIdx.x;
    float A = -expf(A_log[h]);
    size_t row = (size_t)b*SEQ + c*CHUNK + l;
    float v = dtb[row*NHEADS + h] * A;
    __shared__ float sh[128];
    sh[l] = v; __syncthreads();
    for (int off=1; off<128; off<<=1){
        float t = (l>=off) ? sh[l-off] : 0.f;
        __syncthreads();
        sh[l] += t;
        __syncthreads();
    }
    acum[((b*NHEADS+h)*NCHUNK + c)*CHUNK + l] = sh[l];
}

// ======== CB[l][s] = sum_n C[l][n]*B[s][n], per (b,c), LDS-free, tril tiles only ========
__global__ __launch_bounds__(256)
void cb_mfma(const __hip_bfloat16* __restrict__ B_n, const __hip_bfloat16* __restrict__ C_n,
             __hip_bfloat16* __restrict__ CB16)
{
    int c = blockIdx.x & 31, b = blockIdx.x >> 5;
    size_t base = (size_t)b*SEQ + c*CHUNK;
    int tid = threadIdx.x, lane = tid & 63, wave = tid >> 6;
    int r16 = lane & 15, kq = (lane>>4)*8;
    floatx4 acc[2][8] = {};
#pragma unroll
    for (int ks = 0; ks < 4; ++ks) {
        int k0 = ks*32 + kq;
        bf16x8 af[2], bfv[8];
#pragma unroll
        for (int mt = 0; mt < 2; ++mt)
            af[mt] = *(const bf16x8*)(C_n + (base + (wave*2+mt)*16 + r16)*DSTATE + k0);
#pragma unroll
        for (int st = 0; st < 8; ++st)
            bfv[st] = *(const bf16x8*)(B_n + (base + st*16 + r16)*DSTATE + k0);
#pragma unroll
        for (int mt = 0; mt < 2; ++mt)
#pragma unroll
            for (int st = 0; st < 8; ++st)
                if (st <= wave*2+mt)
                    acc[mt][st] = __builtin_amdgcn_mfma_f32_16x16x32_bf16(
                        af[mt], bfv[st], acc[mt][st], 0,0,0);
    }
    size_t cbb = (size_t)(b*NCHUNK+c)*CHUNK*CHUNK;
    int scol = lane & 15, rowq = (lane>>4)*4;
#pragma unroll
    for (int mt = 0; mt < 2; ++mt)
#pragma unroll
        for (int st = 0; st < 8; ++st)
            if (st <= wave*2+mt)
#pragma unroll
                for (int r = 0; r < 4; ++r)
                    CB16[cbb + (size_t)((wave*2+mt)*16 + rowq + r)*CHUNK + st*16 + scol] =
                        __float2bfloat16(acc[mt][st][r]);
}

// ======== states[p][n] = sum_l (x[l,p]*f[l]) * B[l,n], f = dt*dec ========
__global__ __launch_bounds__(256)
void states_mfma(const __hip_bfloat16* __restrict__ x_t, const __hip_bfloat16* __restrict__ B_t,
                 const float* __restrict__ dtb, const float* __restrict__ acum,
                 __hip_bfloat16* __restrict__ states)
{
    __shared__ float f[128];
    int c = blockIdx.x & 31;
    int h = (blockIdx.x>>5) % NHEADS;
    int b = blockIdx.x/(32*NHEADS);
    int tid = threadIdx.x, lane = tid & 63, wave = tid >> 6;
    int arow = ((b*NHEADS+h)*NCHUNK + c)*CHUNK;
    size_t rbase = (size_t)b*SEQ + c*CHUNK;
    if (tid < 128) {
        float alast = acum[arow + 127];
        f[tid] = dtb[(rbase + tid)*NHEADS + h] * expf(alast - acum[arow + tid]);
    }
    __syncthreads();
    int r16 = lane & 15, kq = (lane>>4)*8;
    size_t xtb = ((size_t)b*NHEADS + h)*HEADDIM;
    int cl = c*CHUNK;
    floatx4 acc[8] = {};
#pragma unroll
    for (int ks = 0; ks < 4; ++ks) {
        int k0 = ks*32 + kq;
        bf16x8 xa = *(const bf16x8*)(x_t + (xtb + wave*16 + r16)*SEQ + cl + k0);
        bf16x8 af;
#pragma unroll
        for (int j = 0; j < 8; ++j)
            af[j] = (__bf16)((float)xa[j] * f[k0 + j]);
        bf16x8 bfv[8];
#pragma unroll
        for (int nt = 0; nt < 8; ++nt)
            bfv[nt] = *(const bf16x8*)(B_t + ((size_t)b*DSTATE + nt*16 + r16)*SEQ + cl + k0);
#pragma unroll
        for (int nt = 0; nt < 8; ++nt)
            acc[nt] = __builtin_amdgcn_mfma_f32_16x16x32_bf16(af, bfv[nt], acc[nt], 0,0,0);
    }
    size_t sb = ((size_t)(b*NCHUNK+c)*NHEADS + h)*(HEADDIM*DSTATE);
    int ncol = lane & 15, rowq = (lane>>4)*4;
#pragma unroll
    for (int nt = 0; nt < 8; ++nt)
#pragma unroll
        for (int r = 0; r < 4; ++r)
            states[sb + (size_t)(wave*16 + rowq + r)*DSTATE + nt*16 + ncol] =
                __float2bfloat16(acc[nt][r]);
}

// ---- sequential inter-chunk recurrence, in place (bf16): states[c] := prev[c] ----
__global__ __launch_bounds__(256)
void recur_k(__hip_bfloat16* __restrict__ states, const float* __restrict__ acum)
{
    int pb = blockIdx.x & 3;
    int bh = blockIdx.x >> 2;
    int h = bh % NHEADS, b = bh / NHEADS;
    int voff = (pb*256 + threadIdx.x)*8;
    float S[8] = {};
    for (int c = 0; c < NCHUNK; ++c) {
        size_t addr = ((size_t)(b*NCHUNK+c)*NHEADS + h)*(HEADDIM*DSTATE) + voff;
        bf16x8 st = *(bf16x8*)(states + addr);
        float e = expf(acum[((b*NHEADS+h)*NCHUNK + c)*CHUNK + 127]);
        bf16x8 pv;
#pragma unroll
        for (int j = 0; j < 8; ++j) {
            pv[j] = (__bf16)S[j];
            S[j] = S[j]*e + (float)st[j];
        }
        *(bf16x8*)(states + addr) = pv;
    }
}

// ======== Y = tril(CB*exp(dAc)*dt) @ x  +  (C*exp(ac)) @ prev^T  +  D*x ========
__global__ __launch_bounds__(512)
void y_mfma(const __hip_bfloat16* __restrict__ x_t, const __hip_bfloat16* __restrict__ x_bf,
            const __hip_bfloat16* __restrict__ C_n, const __hip_bfloat16* __restrict__ CB16,
            const __hip_bfloat16* __restrict__ states, const float* __restrict__ dtb,
            const float* __restrict__ acum, const float* __restrict__ Dp,
            __hip_bfloat16* __restrict__ y16)
{
    __shared__ float ac[128], dts[128];
    int c = blockIdx.x & 31;
    int h = (blockIdx.x>>5) % NHEADS;
    int b = blockIdx.x/(32*NHEADS);
    int tid = threadIdx.x, lane = tid & 63, wave = tid >> 6;
    int arow = ((b*NHEADS+h)*NCHUNK + c)*CHUNK;
    size_t rbase = (size_t)b*SEQ + c*CHUNK;
    if (tid < 128) {
        ac[tid]  = acum[arow + tid];
        dts[tid] = dtb[(rbase + tid)*NHEADS + h];
    }
    __syncthreads();
    int r16 = lane & 15, kq = (lane>>4)*8;
    int l = wave*16 + r16;
    float acl = ac[l];
    size_t cbb = (size_t)(b*NCHUNK+c)*CHUNK*CHUNK;
    size_t xtb = ((size_t)b*NHEADS + h)*HEADDIM;
    int cl = c*CHUNK;
    floatx4 acc[4] = {};
    int nks = ((wave+1)*16 + 31) >> 5;
    for (int ks = 0; ks < nks; ++ks) {
        int k0 = ks*32 + kq;
        bf16x8 cbv = *(const bf16x8*)(CB16 + cbb + (size_t)l*CHUNK + k0);
        bf16x8 af;
#pragma unroll
        for (int j = 0; j < 8; ++j) {
            int s = k0 + j;
            float w = (s <= l) ? (float)cbv[j] * expf(acl - ac[s]) * dts[s] : 0.f;
            af[j] = (__bf16)w;
        }
        bf16x8 bfv[4];
#pragma unroll
        for (int pt = 0; pt < 4; ++pt)
            bfv[pt] = *(const bf16x8*)(x_t + (xtb + pt*16 + r16)*SEQ + cl + k0);
#pragma unroll
        for (int pt = 0; pt < 4; ++pt)
            acc[pt] = __builtin_amdgcn_mfma_f32_16x16x32_bf16(af, bfv[pt], acc[pt], 0,0,0);
    }
    float eal = expf(acl);
    size_t sb = ((size_t)(b*NCHUNK+c)*NHEADS + h)*(HEADDIM*DSTATE);
#pragma unroll
    for (int ks = 0; ks < 4; ++ks) {
        int k0 = ks*32 + kq;
        bf16x8 cv = *(const bf16x8*)(C_n + (rbase + l)*DSTATE + k0);
        bf16x8 af;
#pragma unroll
        for (int j = 0; j < 8; ++j)
            af[j] = (__bf16)((float)cv[j] * eal);
        bf16x8 bfv[4];
#pragma unroll
        for (int pt = 0; pt < 4; ++pt)
            bfv[pt] = *(const bf16x8*)(states + sb + (size_t)(pt*16 + r16)*DSTATE + k0);
#pragma unroll
        for (int pt = 0; pt < 4; ++pt)
            acc[pt] = __builtin_amdgcn_mfma_f32_16x16x32_bf16(af, bfv[pt], acc[pt], 0,0,0);
    }
    float Dh = Dp[h];
    int pcol = lane & 15, rowq = (lane>>4)*4;
#pragma unroll
    for (int pt = 0; pt < 4; ++pt)
#pragma unroll
        for (int r = 0; r < 4; ++r) {
            int ll = wave*16 + rowq + r;
            int p = pt*16 + pcol;
            size_t rr = rbase + ll;
            float x = __bfloat162float(x_bf[rr*DINNER + h*HEADDIM + p]);
            y16[rr*DINNER + h*HEADDIM + p] = __float2bfloat16(acc[pt][r] + Dh*x);
        }
}

// ------- y16 *= silu(z16); RMSNorm * norm_w (in place, bf16, vectorized) -------------
__global__ __launch_bounds__(256)
void norm_k(__hip_bfloat16* __restrict__ y16, const __hip_bfloat16* __restrict__ z16,
            const float* __restrict__ nw)
{
    int r = blockIdx.x, tid = threadIdx.x;
    float v[8]; float ss = 0.f;
    int c0 = tid*8;
    if (tid < 192) {
        bf16x8 zv = *(const bf16x8*)(z16 + (size_t)r*DINNER + c0);
        bf16x8 yv = *(const bf16x8*)(y16 + (size_t)r*DINNER + c0);
#pragma unroll
        for (int j = 0; j < 8; ++j) {
            float g = (float)yv[j] * siluf_((float)zv[j]);
            v[j] = g; ss += g*g;
        }
    }
    for (int off=32; off; off>>=1) ss += __shfl_down(ss, off);
    __shared__ float red[4];
    __shared__ float stot;
    int lane = tid & 63, wid = tid >> 6;
    if (lane==0) red[wid] = ss;
    __syncthreads();
    if (tid==0) stot = red[0]+red[1]+red[2]+red[3];
    __syncthreads();
    float scale = rsqrtf(stot * (1.f/DINNER) + 1e-5f);
    if (tid < 192) {
        bf16x8 ov;
#pragma unroll
        for (int j = 0; j < 8; ++j)
            ov[j] = (__bf16)(v[j]*scale*nw[c0+j]);
        *(bf16x8*)(y16 + (size_t)r*DINNER + c0) = ov;
    }
}

extern "C" void kernel_launch(void* const* d_in, const int* in_sizes, int n_in,
                              void* d_out, int out_size, void* d_ws, size_t ws_size,
                              hipStream_t stream)
{
    const float* feature = (const float*)d_in[0];
    const float* gate1   = (const float*)d_in[1];
    const float* in_w    = (const float*)d_in[2];
    const float* conv_w  = (const float*)d_in[3];
    const float* conv_b  = (const float*)d_in[4];
    const float* dt_bias = (const float*)d_in[5];
    const float* A_log   = (const float*)d_in[6];
    const float* Dp      = (const float*)d_in[7];
    const float* norm_w  = (const float*)d_in[8];
    const float* out_w   = (const float*)d_in[9];
    float* out = (float*)d_out;

    // workspace layout — ~186 MB (< 256 MiB)
    char* p = (char*)d_ws;
    __hip_bfloat16* z16   = (__hip_bfloat16*)p; p += (size_t)ROWS*DINNER*2;  // 25.2 MB
    __hip_bfloat16* xbc16 = (__hip_bfloat16*)p; p += (size_t)ROWS*DXBC*2;    // 29.4 MB
    __hip_bfloat16* x_bf  = (__hip_bfloat16*)p; p += (size_t)ROWS*DINNER*2;  // 25.2 MB
    __hip_bfloat16* x_t   = (__hip_bfloat16*)p; p += (size_t)ROWS*DINNER*2;  // 25.2 MB
    __hip_bfloat16* B_n   = (__hip_bfloat16*)p; p += (size_t)ROWS*DSTATE*2;  // 2.1 MB
    __hip_bfloat16* B_t   = (__hip_bfloat16*)p; p += (size_t)ROWS*DSTATE*2;  // 2.1 MB
    __hip_bfloat16* C_n   = (__hip_bfloat16*)p; p += (size_t)ROWS*DSTATE*2;  // 2.1 MB
    float* dtb    = (float*)p;            p += (size_t)ROWS*NHEADS*4;        // 0.8 MB
    float* acum   = (float*)p;            p += (size_t)B_SZ*NHEADS*NCHUNK*CHUNK*4; // 0.8 MB
    __hip_bfloat16* CB16 = (__hip_bfloat16*)p; p += (size_t)B_SZ*NCHUNK*CHUNK*CHUNK*2; // 2.1 MB
    __hip_bfloat16* states = (__hip_bfloat16*)p; p += (size_t)B_SZ*NCHUNK*NHEADS*HEADDIM*DSTATE*2; // 25.2 MB
    __hip_bfloat16* y16  = (__hip_bfloat16*)p; p += (size_t)ROWS*DINNER*2;   // 25.2 MB
    __hip_bfloat16* fbf  = (__hip_bfloat16*)p; p += (size_t)ROWS*DMODEL*2;   // 12.6 MB
    __hip_bfloat16* wbf  = (__hip_bfloat16*)p; p += (size_t)NPAD1*DMODEL*2;  //  5.3 MB
    __hip_bfloat16* owbf = (__hip_bfloat16*)p; p += (size_t)DMODEL*DINNER*2; //  2.4 MB

    cast_k<<<(ROWS*DMODEL+255)/256, 256, 0, stream>>>(feature, fbf, ROWS*DMODEL);
    cast_w1_k<<<(NPAD1*DMODEL+255)/256, 256, 0, stream>>>(in_w, wbf);
    cast_k<<<(DMODEL*DINNER+255)/256, 256, 0, stream>>>(out_w, owbf, DMODEL*DINNER);

    gemm1_mfma<<<dim3(NPAD1/128, ROWS/128), 256, 0, stream>>>(fbf, wbf, z16, xbc16,
                                                              dtb, dt_bias);
    conv_k<<<dim3(14, 32, B_SZ), 256, 0, stream>>>(xbc16, conv_w, conv_b,
                                                   x_bf, x_t, B_n, B_t, C_n);
    scan_k<<<B_SZ*NHEADS*NCHUNK, 128, 0, stream>>>(dtb, A_log, acum);
    cb_mfma<<<B_SZ*NCHUNK, 256, 0, stream>>>(B_n, C_n, CB16);
    states_mfma<<<B_SZ*NHEADS*NCHUNK, 256, 0, stream>>>(x_t, B_t, dtb, acum, states);
    recur_k<<<B_SZ*NHEADS*4, 256, 0, stream>>>(states, acum);
    y_mfma<<<B_SZ*NHEADS*NCHUNK, 512, 0, stream>>>(x_t, x_bf, C_n, CB16, states,
                                                   dtb, acum, Dp, y16);
    norm_k<<<ROWS, 256, 0, stream>>>(y16, z16, norm_w);
    gemm2_mfma<<<dim3(DMODEL/128, ROWS/128), 256, 0, stream>>>(y16, owbf, out, gate1, feature);
}

// Round 7
// 387.658 us; speedup vs baseline: 4.5881x; 1.0208x over previous
//
#include <hip/hip_runtime.h>
#include <hip/hip_bf16.h>
#include <math.h>

#define B_SZ 2
#define SEQ 4096
#define DMODEL 768
#define DSTATE 128
#define HEADDIM 64
#define DINNER 1536
#define NHEADS 24
#define DXBC 1792
#define DPROJ 3352
#define NPAD1 3456
#define CHUNK 128
#define NCHUNK 32
#define ROWS (B_SZ*SEQ)
#define LDTC 136   // padded LDS stride for conv input tile
#define LDE 136    // padded LDS stride (bf16) for gemm1 epilogue tile
#define LDE2 132   // padded LDS stride (fp32) for gemm2 epilogue tile

typedef float floatx4 __attribute__((ext_vector_type(4)));
typedef __bf16 bf16x8 __attribute__((ext_vector_type(8)));

__device__ __forceinline__ float sigmoidf_(float x){ return 1.f/(1.f+expf(-x)); }
__device__ __forceinline__ float siluf_(float x){ return x/(1.f+expf(-x)); }
__device__ __forceinline__ float softplusf_(float x){ return (x>20.f)? x : log1pf(expf(x)); }

__device__ __forceinline__ void gload_lds16(const __hip_bfloat16* g, __hip_bfloat16* l){
    __builtin_amdgcn_global_load_lds(
        (const __attribute__((address_space(1))) void*)g,
        (__attribute__((address_space(3))) void*)l, 16, 0, 0);
}

// ======== GEMM1: zxbcdt = feature @ in_proj^T; epilogue -> z16 / xbc16 / dtb ========
// 1-D grid, XCD-band swizzle: each XCD (blk%8) owns an 8-M-tile band; W-tiles are
// reused by 8 consecutive same-XCD blocks (L2-hot). N-tile -> dest: 0..11 = z,
// 12..25 = xbc16, 26 = dt (softplus fused).
__global__ __launch_bounds__(256)
void gemm1_mfma(const __hip_bfloat16* __restrict__ A,   // fbf [ROWS][768]
                const __hip_bfloat16* __restrict__ W,   // wbf [3456][768]
                __hip_bfloat16* __restrict__ z16, __hip_bfloat16* __restrict__ xbc16,
                float* __restrict__ dtb, const float* __restrict__ dt_bias)
{
    __shared__ __align__(16) char smem[128*LDE*2];      // 34816 B
    __hip_bfloat16* Asm = (__hip_bfloat16*)smem;
    __hip_bfloat16* Wsm = Asm + 128*64;
    const int tid = threadIdx.x;
    const int lane = tid & 63, wave = tid >> 6;
    const int blk = blockIdx.x;
    const int m_tile = ((blk & 7) << 3) | ((blk >> 3) & 7);   // XCD M-band
    const int bx = blk >> 6;                                   // N-tile 0..26
    const int bm = m_tile*128, bn = bx*128;
    const int wm = (wave & 1)*64, wn = (wave >> 1)*64;
    floatx4 acc[4][4] = {};
    for (int k0 = 0; k0 < DMODEL; k0 += 64) {
#pragma unroll
        for (int j = 0; j < 4; ++j) {
            int cc = j*256 + tid;
            int row = cc >> 3, kc = (cc & 7)*8;
            gload_lds16(A + (size_t)(bm+row)*DMODEL + k0 + kc, Asm + cc*8);
            gload_lds16(W + (size_t)(bn+row)*DMODEL + k0 + kc, Wsm + cc*8);
        }
        __syncthreads();
#pragma unroll
        for (int ks = 0; ks < 2; ++ks) {
            const int kq = (lane >> 4)*8 + ks*32;
            const int r16 = lane & 15;
            bf16x8 af[4], wf[4];
#pragma unroll
            for (int i = 0; i < 4; ++i) {
                af[i] = *(const bf16x8*)(Asm + (wm + i*16 + r16)*64 + kq);
                wf[i] = *(const bf16x8*)(Wsm + (wn + i*16 + r16)*64 + kq);
            }
#pragma unroll
            for (int mi = 0; mi < 4; ++mi)
#pragma unroll
                for (int ni = 0; ni < 4; ++ni)
                    acc[mi][ni] = __builtin_amdgcn_mfma_f32_16x16x32_bf16(
                        af[mi], wf[ni], acc[mi][ni], 0, 0, 0);
        }
        __syncthreads();
    }
    const int col = lane & 15, rowq = (lane >> 4)*4;
    if (bx == 26) {
        if (wn == 0) {
#pragma unroll
            for (int mi = 0; mi < 4; ++mi)
#pragma unroll
                for (int ni = 0; ni < 2; ++ni) {
                    int h = ni*16 + col;
                    if (h < NHEADS)
#pragma unroll
                        for (int r = 0; r < 4; ++r) {
                            int m = bm + wm + mi*16 + rowq + r;
                            dtb[(size_t)m*NHEADS + h] =
                                softplusf_(acc[mi][ni][r] + dt_bias[h]);
                        }
                }
        }
        return;
    }
    __hip_bfloat16* Tsm = (__hip_bfloat16*)smem;
#pragma unroll
    for (int mi = 0; mi < 4; ++mi)
#pragma unroll
        for (int ni = 0; ni < 4; ++ni)
#pragma unroll
            for (int r = 0; r < 4; ++r)
                Tsm[(wm + mi*16 + rowq + r)*LDE + wn + ni*16 + col] =
                    __float2bfloat16(acc[mi][ni][r]);
    __syncthreads();
    __hip_bfloat16* dst; int ldd;
    if (bx < 12) { dst = z16 + bn;            ldd = DINNER; }
    else         { dst = xbc16 + bn - DINNER; ldd = DXBC;  }
#pragma unroll
    for (int it = 0; it < 8; ++it) {
        int e = it*256 + tid;
        int row = e >> 4, c0 = (e & 15)*8;
        bf16x8 v = *(const bf16x8*)(Tsm + row*LDE + c0);
        *(bf16x8*)(dst + (size_t)(bm+row)*ldd + c0) = v;
    }
}

// ======== GEMM2: out = sigmoid(gate)*(y16 @ out_w^T) + feature, XCD-band swizzle ====
__global__ __launch_bounds__(256)
void gemm2_mfma(const __hip_bfloat16* __restrict__ A,   // y16 [ROWS][1536]
                const __hip_bfloat16* __restrict__ W,   // owbf [768][1536]
                float* __restrict__ C,
                const float* __restrict__ gate, const float* __restrict__ resid)
{
    __shared__ __align__(16) char smem[128*LDE*2];
    __hip_bfloat16* Asm = (__hip_bfloat16*)smem;
    __hip_bfloat16* Wsm = Asm + 128*64;
    const int tid = threadIdx.x;
    const int lane = tid & 63, wave = tid >> 6;
    const int blk = blockIdx.x;
    const int m_tile = ((blk & 7) << 3) | ((blk >> 3) & 7);
    const int bm = m_tile*128, bn = (blk >> 6)*128;             // n-tile 0..5
    const int wm = (wave & 1)*64, wn = (wave >> 1)*64;
    floatx4 acc[4][4] = {};
    for (int k0 = 0; k0 < DINNER; k0 += 64) {
#pragma unroll
        for (int j = 0; j < 4; ++j) {
            int cc = j*256 + tid;
            int row = cc >> 3, kc = (cc & 7)*8;
            gload_lds16(A + (size_t)(bm+row)*DINNER + k0 + kc, Asm + cc*8);
            gload_lds16(W + (size_t)(bn+row)*DINNER + k0 + kc, Wsm + cc*8);
        }
        __syncthreads();
#pragma unroll
        for (int ks = 0; ks < 2; ++ks) {
            const int kq = (lane >> 4)*8 + ks*32;
            const int r16 = lane & 15;
            bf16x8 af[4], wf[4];
#pragma unroll
            for (int i = 0; i < 4; ++i) {
                af[i] = *(const bf16x8*)(Asm + (wm + i*16 + r16)*64 + kq);
                wf[i] = *(const bf16x8*)(Wsm + (wn + i*16 + r16)*64 + kq);
            }
#pragma unroll
            for (int mi = 0; mi < 4; ++mi)
#pragma unroll
                for (int ni = 0; ni < 4; ++ni)
                    acc[mi][ni] = __builtin_amdgcn_mfma_f32_16x16x32_bf16(
                        af[mi], wf[ni], acc[mi][ni], 0, 0, 0);
        }
        __syncthreads();
    }
    float gs = sigmoidf_(gate[0]);
    const int col = lane & 15, rowq = (lane >> 4)*4;
    float* Tsm = (float*)smem;   // 64 x LDE2 fp32
    for (int half = 0; half < 2; ++half) {
        if ((wave & 1) == half) {
#pragma unroll
            for (int mi = 0; mi < 4; ++mi)
#pragma unroll
                for (int ni = 0; ni < 4; ++ni)
#pragma unroll
                    for (int r = 0; r < 4; ++r)
                        Tsm[(mi*16 + rowq + r)*LDE2 + wn + ni*16 + col] = acc[mi][ni][r];
        }
        __syncthreads();
#pragma unroll
        for (int it = 0; it < 8; ++it) {
            int e = it*256 + tid;
            int row = e >> 5, c0 = (e & 31)*4;
            float4 v = *(const float4*)(Tsm + row*LDE2 + c0);
            size_t off = (size_t)(bm + half*64 + row)*DMODEL + bn + c0;
            float4 rv = *(const float4*)(resid + off);
            v.x = gs*v.x + rv.x; v.y = gs*v.y + rv.y;
            v.z = gs*v.z + rv.z; v.w = gs*v.w + rv.w;
            *(float4*)(C + off) = v;
        }
        __syncthreads();
    }
}

// ---------------- fp32 -> bf16 casts ----------------
__global__ __launch_bounds__(256)
void cast_k(const float* __restrict__ src, __hip_bfloat16* __restrict__ dst, int n)
{
    int i = blockIdx.x*256 + threadIdx.x;
    if (i < n) dst[i] = __float2bfloat16(src[i]);
}
__global__ __launch_bounds__(256)
void cast_w1_k(const float* __restrict__ src, __hip_bfloat16* __restrict__ dst)
{
    int i = blockIdx.x*256 + threadIdx.x;
    if (i >= NPAD1*DMODEL) return;
    int n = i / DMODEL, k = i % DMODEL;
    dst[i] = __float2bfloat16(n < DPROJ ? src[(size_t)n*DMODEL + k] : 0.f);
}

// ======== conv4+SiLU, emits x_bf/x_t/B_n/B_t/C_n in MFMA-ready layouts ========
__global__ __launch_bounds__(256)
void conv_k(const __hip_bfloat16* __restrict__ xbc16, const float* __restrict__ cw,
            const float* __restrict__ cbias,
            __hip_bfloat16* __restrict__ x_bf, __hip_bfloat16* __restrict__ x_t,
            __hip_bfloat16* __restrict__ B_n, __hip_bfloat16* __restrict__ B_t,
            __hip_bfloat16* __restrict__ C_n)
{
    __shared__ __align__(16) __hip_bfloat16 in[131*LDTC];
    int ct = blockIdx.x, lt = blockIdx.y, b = blockIdx.z;
    int tid = threadIdx.x;
    int base = lt*128;
    for (int it = 0; it < 2096; it += 256) {
        int e = it + tid; if (e >= 2096) break;
        int row = e >> 4, c0 = (e & 15)*8;
        int l = base - 3 + row;
        bf16x8 v;
        if (l < 0) { for (int j = 0; j < 8; ++j) v[j] = (__bf16)0.f; }
        else v = *(const bf16x8*)(xbc16 + ((size_t)b*SEQ + l)*DXBC + ct*128 + c0);
        *(bf16x8*)(in + row*LDTC + c0) = v;
    }
    __syncthreads();
    int ch = tid & 127, lh = tid >> 7, l0 = lh*64;
    int g = ct*128 + ch;
    float w0 = cw[g*4+0], w1 = cw[g*4+1], w2 = cw[g*4+2], w3 = cw[g*4+3];
    float bias = cbias[g];
    float a0 = __bfloat162float(in[(l0+0)*LDTC + ch]);
    float a1 = __bfloat162float(in[(l0+1)*LDTC + ch]);
    float a2 = __bfloat162float(in[(l0+2)*LDTC + ch]);
    size_t trow = 0;
    if (ct < 12)      trow = ((size_t)b*NHEADS + (g>>6))*HEADDIM + (g & 63);
    else if (ct == 12) trow = (size_t)b*DSTATE + ch;
    bf16x8 obuf;
#pragma unroll
    for (int li = 0; li < 64; ++li) {
        float a3 = __bfloat162float(in[(l0+li+3)*LDTC + ch]);
        float o = siluf_(bias + w0*a0 + w1*a1 + w2*a2 + w3*a3);
        a0 = a1; a1 = a2; a2 = a3;
        __hip_bfloat16 ob = __float2bfloat16(o);
        size_t rr = (size_t)b*SEQ + base + l0 + li;
        if (ct < 12)       x_bf[rr*DINNER + g] = ob;
        else if (ct == 12) B_n[rr*DSTATE + ch] = ob;
        else               C_n[rr*DSTATE + ch] = ob;
        obuf[li & 7] = *(const __bf16*)&ob;
        if ((li & 7) == 7 && ct <= 12) {
            __hip_bfloat16* dst = (ct < 12) ? x_t : B_t;
            *(bf16x8*)(dst + trow*SEQ + base + l0 + (li - 7)) = obuf;
        }
    }
}

// ---------------- intra-chunk inclusive cumsum of dt*A ----------------
__global__ __launch_bounds__(128)
void scan_k(const float* __restrict__ dtb, const float* __restrict__ A_log,
            float* __restrict__ acum)
{
    int c = blockIdx.x & 31;
    int h = (blockIdx.x >> 5) % NHEADS;
    int b = blockIdx.x / (32*NHEADS);
    int l = threadIdx.x;
    float A = -expf(A_log[h]);
    size_t row = (size_t)b*SEQ + c*CHUNK + l;
    float v = dtb[row*NHEADS + h] * A;
    __shared__ float sh[128];
    sh[l] = v; __syncthreads();
    for (int off=1; off<128; off<<=1){
        float t = (l>=off) ? sh[l-off] : 0.f;
        __syncthreads();
        sh[l] += t;
        __syncthreads();
    }
    acum[((b*NHEADS+h)*NCHUNK + c)*CHUNK + l] = sh[l];
}

// ======== CB[l][s] = sum_n C[l][n]*B[s][n], per (b,c), LDS-free, tril tiles only ========
__global__ __launch_bounds__(256)
void cb_mfma(const __hip_bfloat16* __restrict__ B_n, const __hip_bfloat16* __restrict__ C_n,
             __hip_bfloat16* __restrict__ CB16)
{
    int c = blockIdx.x & 31, b = blockIdx.x >> 5;
    size_t base = (size_t)b*SEQ + c*CHUNK;
    int tid = threadIdx.x, lane = tid & 63, wave = tid >> 6;
    int r16 = lane & 15, kq = (lane>>4)*8;
    floatx4 acc[2][8] = {};
#pragma unroll
    for (int ks = 0; ks < 4; ++ks) {
        int k0 = ks*32 + kq;
        bf16x8 af[2], bfv[8];
#pragma unroll
        for (int mt = 0; mt < 2; ++mt)
            af[mt] = *(const bf16x8*)(C_n + (base + (wave*2+mt)*16 + r16)*DSTATE + k0);
#pragma unroll
        for (int st = 0; st < 8; ++st)
            bfv[st] = *(const bf16x8*)(B_n + (base + st*16 + r16)*DSTATE + k0);
#pragma unroll
        for (int mt = 0; mt < 2; ++mt)
#pragma unroll
            for (int st = 0; st < 8; ++st)
                if (st <= wave*2+mt)
                    acc[mt][st] = __builtin_amdgcn_mfma_f32_16x16x32_bf16(
                        af[mt], bfv[st], acc[mt][st], 0,0,0);
    }
    size_t cbb = (size_t)(b*NCHUNK+c)*CHUNK*CHUNK;
    int scol = lane & 15, rowq = (lane>>4)*4;
#pragma unroll
    for (int mt = 0; mt < 2; ++mt)
#pragma unroll
        for (int st = 0; st < 8; ++st)
            if (st <= wave*2+mt)
#pragma unroll
                for (int r = 0; r < 4; ++r)
                    CB16[cbb + (size_t)((wave*2+mt)*16 + rowq + r)*CHUNK + st*16 + scol] =
                        __float2bfloat16(acc[mt][st][r]);
}

// ======== states[p][n] = sum_l (x[l,p]*f[l]) * B[l,n], f = dt*dec ========
__global__ __launch_bounds__(256)
void states_mfma(const __hip_bfloat16* __restrict__ x_t, const __hip_bfloat16* __restrict__ B_t,
                 const float* __restrict__ dtb, const float* __restrict__ acum,
                 __hip_bfloat16* __restrict__ states)
{
    __shared__ float f[128];
    int c = blockIdx.x & 31;
    int h = (blockIdx.x>>5) % NHEADS;
    int b = blockIdx.x/(32*NHEADS);
    int tid = threadIdx.x, lane = tid & 63, wave = tid >> 6;
    int arow = ((b*NHEADS+h)*NCHUNK + c)*CHUNK;
    size_t rbase = (size_t)b*SEQ + c*CHUNK;
    if (tid < 128) {
        float alast = acum[arow + 127];
        f[tid] = dtb[(rbase + tid)*NHEADS + h] * expf(alast - acum[arow + tid]);
    }
    __syncthreads();
    int r16 = lane & 15, kq = (lane>>4)*8;
    size_t xtb = ((size_t)b*NHEADS + h)*HEADDIM;
    int cl = c*CHUNK;
    floatx4 acc[8] = {};
#pragma unroll
    for (int ks = 0; ks < 4; ++ks) {
        int k0 = ks*32 + kq;
        bf16x8 xa = *(const bf16x8*)(x_t + (xtb + wave*16 + r16)*SEQ + cl + k0);
        bf16x8 af;
#pragma unroll
        for (int j = 0; j < 8; ++j)
            af[j] = (__bf16)((float)xa[j] * f[k0 + j]);
        bf16x8 bfv[8];
#pragma unroll
        for (int nt = 0; nt < 8; ++nt)
            bfv[nt] = *(const bf16x8*)(B_t + ((size_t)b*DSTATE + nt*16 + r16)*SEQ + cl + k0);
#pragma unroll
        for (int nt = 0; nt < 8; ++nt)
            acc[nt] = __builtin_amdgcn_mfma_f32_16x16x32_bf16(af, bfv[nt], acc[nt], 0,0,0);
    }
    size_t sb = ((size_t)(b*NCHUNK+c)*NHEADS + h)*(HEADDIM*DSTATE);
    int ncol = lane & 15, rowq = (lane>>4)*4;
#pragma unroll
    for (int nt = 0; nt < 8; ++nt)
#pragma unroll
        for (int r = 0; r < 4; ++r)
            states[sb + (size_t)(wave*16 + rowq + r)*DSTATE + nt*16 + ncol] =
                __float2bfloat16(acc[nt][r]);
}

// ---- sequential inter-chunk recurrence, in place (bf16): states[c] := prev[c] ----
__global__ __launch_bounds__(256)
void recur_k(__hip_bfloat16* __restrict__ states, const float* __restrict__ acum)
{
    int pb = blockIdx.x & 3;
    int bh = blockIdx.x >> 2;
    int h = bh % NHEADS, b = bh / NHEADS;
    int voff = (pb*256 + threadIdx.x)*8;
    float S[8] = {};
    for (int c = 0; c < NCHUNK; ++c) {
        size_t addr = ((size_t)(b*NCHUNK+c)*NHEADS + h)*(HEADDIM*DSTATE) + voff;
        bf16x8 st = *(bf16x8*)(states + addr);
        float e = expf(acum[((b*NHEADS+h)*NCHUNK + c)*CHUNK + 127]);
        bf16x8 pv;
#pragma unroll
        for (int j = 0; j < 8; ++j) {
            pv[j] = (__bf16)S[j];
            S[j] = S[j]*e + (float)st[j];
        }
        *(bf16x8*)(states + addr) = pv;
    }
}

// ======== Y = tril(CB*exp(dAc)*dt) @ x  +  (C*exp(ac)) @ prev^T  +  D*x ========
__global__ __launch_bounds__(512)
void y_mfma(const __hip_bfloat16* __restrict__ x_t, const __hip_bfloat16* __restrict__ x_bf,
            const __hip_bfloat16* __restrict__ C_n, const __hip_bfloat16* __restrict__ CB16,
            const __hip_bfloat16* __restrict__ states, const float* __restrict__ dtb,
            const float* __restrict__ acum, const float* __restrict__ Dp,
            __hip_bfloat16* __restrict__ y16)
{
    __shared__ float ac[128], dts[128];
    int c = blockIdx.x & 31;
    int h = (blockIdx.x>>5) % NHEADS;
    int b = blockIdx.x/(32*NHEADS);
    int tid = threadIdx.x, lane = tid & 63, wave = tid >> 6;
    int arow = ((b*NHEADS+h)*NCHUNK + c)*CHUNK;
    size_t rbase = (size_t)b*SEQ + c*CHUNK;
    if (tid < 128) {
        ac[tid]  = acum[arow + tid];
        dts[tid] = dtb[(rbase + tid)*NHEADS + h];
    }
    __syncthreads();
    int r16 = lane & 15, kq = (lane>>4)*8;
    int l = wave*16 + r16;
    float acl = ac[l];
    size_t cbb = (size_t)(b*NCHUNK+c)*CHUNK*CHUNK;
    size_t xtb = ((size_t)b*NHEADS + h)*HEADDIM;
    int cl = c*CHUNK;
    floatx4 acc[4] = {};
    int nks = ((wave+1)*16 + 31) >> 5;
    for (int ks = 0; ks < nks; ++ks) {
        int k0 = ks*32 + kq;
        bf16x8 cbv = *(const bf16x8*)(CB16 + cbb + (size_t)l*CHUNK + k0);
        bf16x8 af;
#pragma unroll
        for (int j = 0; j < 8; ++j) {
            int s = k0 + j;
            float w = (s <= l) ? (float)cbv[j] * expf(acl - ac[s]) * dts[s] : 0.f;
            af[j] = (__bf16)w;
        }
        bf16x8 bfv[4];
#pragma unroll
        for (int pt = 0; pt < 4; ++pt)
            bfv[pt] = *(const bf16x8*)(x_t + (xtb + pt*16 + r16)*SEQ + cl + k0);
#pragma unroll
        for (int pt = 0; pt < 4; ++pt)
            acc[pt] = __builtin_amdgcn_mfma_f32_16x16x32_bf16(af, bfv[pt], acc[pt], 0,0,0);
    }
    float eal = expf(acl);
    size_t sb = ((size_t)(b*NCHUNK+c)*NHEADS + h)*(HEADDIM*DSTATE);
#pragma unroll
    for (int ks = 0; ks < 4; ++ks) {
        int k0 = ks*32 + kq;
        bf16x8 cv = *(const bf16x8*)(C_n + (rbase + l)*DSTATE + k0);
        bf16x8 af;
#pragma unroll
        for (int j = 0; j < 8; ++j)
            af[j] = (__bf16)((float)cv[j] * eal);
        bf16x8 bfv[4];
#pragma unroll
        for (int pt = 0; pt < 4; ++pt)
            bfv[pt] = *(const bf16x8*)(states + sb + (size_t)(pt*16 + r16)*DSTATE + k0);
#pragma unroll
        for (int pt = 0; pt < 4; ++pt)
            acc[pt] = __builtin_amdgcn_mfma_f32_16x16x32_bf16(af, bfv[pt], acc[pt], 0,0,0);
    }
    float Dh = Dp[h];
    int pcol = lane & 15, rowq = (lane>>4)*4;
#pragma unroll
    for (int pt = 0; pt < 4; ++pt)
#pragma unroll
        for (int r = 0; r < 4; ++r) {
            int ll = wave*16 + rowq + r;
            int p = pt*16 + pcol;
            size_t rr = rbase + ll;
            float x = __bfloat162float(x_bf[rr*DINNER + h*HEADDIM + p]);
            y16[rr*DINNER + h*HEADDIM + p] = __float2bfloat16(acc[pt][r] + Dh*x);
        }
}

// ------- y16 *= silu(z16); RMSNorm * norm_w (in place, bf16, vectorized) -------------
__global__ __launch_bounds__(256)
void norm_k(__hip_bfloat16* __restrict__ y16, const __hip_bfloat16* __restrict__ z16,
            const float* __restrict__ nw)
{
    int r = blockIdx.x, tid = threadIdx.x;
    float v[8]; float ss = 0.f;
    int c0 = tid*8;
    if (tid < 192) {
        bf16x8 zv = *(const bf16x8*)(z16 + (size_t)r*DINNER + c0);
        bf16x8 yv = *(const bf16x8*)(y16 + (size_t)r*DINNER + c0);
#pragma unroll
        for (int j = 0; j < 8; ++j) {
            float g = (float)yv[j] * siluf_((float)zv[j]);
            v[j] = g; ss += g*g;
        }
    }
    for (int off=32; off; off>>=1) ss += __shfl_down(ss, off);
    __shared__ float red[4];
    __shared__ float stot;
    int lane = tid & 63, wid = tid >> 6;
    if (lane==0) red[wid] = ss;
    __syncthreads();
    if (tid==0) stot = red[0]+red[1]+red[2]+red[3];
    __syncthreads();
    float scale = rsqrtf(stot * (1.f/DINNER) + 1e-5f);
    if (tid < 192) {
        bf16x8 ov;
#pragma unroll
        for (int j = 0; j < 8; ++j)
            ov[j] = (__bf16)(v[j]*scale*nw[c0+j]);
        *(bf16x8*)(y16 + (size_t)r*DINNER + c0) = ov;
    }
}

extern "C" void kernel_launch(void* const* d_in, const int* in_sizes, int n_in,
                              void* d_out, int out_size, void* d_ws, size_t ws_size,
                              hipStream_t stream)
{
    const float* feature = (const float*)d_in[0];
    const float* gate1   = (const float*)d_in[1];
    const float* in_w    = (const float*)d_in[2];
    const float* conv_w  = (const float*)d_in[3];
    const float* conv_b  = (const float*)d_in[4];
    const float* dt_bias = (const float*)d_in[5];
    const float* A_log   = (const float*)d_in[6];
    const float* Dp      = (const float*)d_in[7];
    const float* norm_w  = (const float*)d_in[8];
    const float* out_w   = (const float*)d_in[9];
    float* out = (float*)d_out;

    // workspace layout — ~186 MB (< 256 MiB)
    char* p = (char*)d_ws;
    __hip_bfloat16* z16   = (__hip_bfloat16*)p; p += (size_t)ROWS*DINNER*2;  // 25.2 MB
    __hip_bfloat16* xbc16 = (__hip_bfloat16*)p; p += (size_t)ROWS*DXBC*2;    // 29.4 MB
    __hip_bfloat16* x_bf  = (__hip_bfloat16*)p; p += (size_t)ROWS*DINNER*2;  // 25.2 MB
    __hip_bfloat16* x_t   = (__hip_bfloat16*)p; p += (size_t)ROWS*DINNER*2;  // 25.2 MB
    __hip_bfloat16* B_n   = (__hip_bfloat16*)p; p += (size_t)ROWS*DSTATE*2;  // 2.1 MB
    __hip_bfloat16* B_t   = (__hip_bfloat16*)p; p += (size_t)ROWS*DSTATE*2;  // 2.1 MB
    __hip_bfloat16* C_n   = (__hip_bfloat16*)p; p += (size_t)ROWS*DSTATE*2;  // 2.1 MB
    float* dtb    = (float*)p;            p += (size_t)ROWS*NHEADS*4;        // 0.8 MB
    float* acum   = (float*)p;            p += (size_t)B_SZ*NHEADS*NCHUNK*CHUNK*4; // 0.8 MB
    __hip_bfloat16* CB16 = (__hip_bfloat16*)p; p += (size_t)B_SZ*NCHUNK*CHUNK*CHUNK*2; // 2.1 MB
    __hip_bfloat16* states = (__hip_bfloat16*)p; p += (size_t)B_SZ*NCHUNK*NHEADS*HEADDIM*DSTATE*2; // 25.2 MB
    __hip_bfloat16* y16  = (__hip_bfloat16*)p; p += (size_t)ROWS*DINNER*2;   // 25.2 MB
    __hip_bfloat16* fbf  = (__hip_bfloat16*)p; p += (size_t)ROWS*DMODEL*2;   // 12.6 MB
    __hip_bfloat16* wbf  = (__hip_bfloat16*)p; p += (size_t)NPAD1*DMODEL*2;  //  5.3 MB
    __hip_bfloat16* owbf = (__hip_bfloat16*)p; p += (size_t)DMODEL*DINNER*2; //  2.4 MB

    cast_k<<<(ROWS*DMODEL+255)/256, 256, 0, stream>>>(feature, fbf, ROWS*DMODEL);
    cast_w1_k<<<(NPAD1*DMODEL+255)/256, 256, 0, stream>>>(in_w, wbf);
    cast_k<<<(DMODEL*DINNER+255)/256, 256, 0, stream>>>(out_w, owbf, DMODEL*DINNER);

    gemm1_mfma<<<27*64, 256, 0, stream>>>(fbf, wbf, z16, xbc16, dtb, dt_bias);
    conv_k<<<dim3(14, 32, B_SZ), 256, 0, stream>>>(xbc16, conv_w, conv_b,
                                                   x_bf, x_t, B_n, B_t, C_n);
    scan_k<<<B_SZ*NHEADS*NCHUNK, 128, 0, stream>>>(dtb, A_log, acum);
    cb_mfma<<<B_SZ*NCHUNK, 256, 0, stream>>>(B_n, C_n, CB16);
    states_mfma<<<B_SZ*NHEADS*NCHUNK, 256, 0, stream>>>(x_t, B_t, dtb, acum, states);
    recur_k<<<B_SZ*NHEADS*4, 256, 0, stream>>>(states, acum);
    y_mfma<<<B_SZ*NHEADS*NCHUNK, 512, 0, stream>>>(x_t, x_bf, C_n, CB16, states,
                                                   dtb, acum, Dp, y16);
    norm_k<<<ROWS, 256, 0, stream>>>(y16, z16, norm_w);
    gemm2_mfma<<<6*64, 256, 0, stream>>>(y16, owbf, out, gate1, feature);
}

// Round 8
// 375.515 us; speedup vs baseline: 4.7364x; 1.0323x over previous
//
#include <hip/hip_runtime.h>
#include <hip/hip_bf16.h>
#include <math.h>

#define B_SZ 2
#define SEQ 4096
#define DMODEL 768
#define DSTATE 128
#define HEADDIM 64
#define DINNER 1536
#define NHEADS 24
#define DXBC 1792
#define DPROJ 3352
#define NPAD1 3456
#define CHUNK 128
#define NCHUNK 32
#define ROWS (B_SZ*SEQ)
#define LDTC 136   // padded LDS stride for conv input tile
#define LDE 136    // padded LDS stride (bf16) for gemm1 epilogue tile
#define LDE2 132   // padded LDS stride (fp32) for gemm2 epilogue tile

typedef float floatx4 __attribute__((ext_vector_type(4)));
typedef __bf16 bf16x8 __attribute__((ext_vector_type(8)));

__device__ __forceinline__ float sigmoidf_(float x){ return 1.f/(1.f+expf(-x)); }
__device__ __forceinline__ float siluf_(float x){ return x/(1.f+expf(-x)); }
__device__ __forceinline__ float softplusf_(float x){ return (x>20.f)? x : log1pf(expf(x)); }

__device__ __forceinline__ void gload_lds16(const __hip_bfloat16* g, __hip_bfloat16* l){
    __builtin_amdgcn_global_load_lds(
        (const __attribute__((address_space(1))) void*)g,
        (__attribute__((address_space(3))) void*)l, 16, 0, 0);
}

// ======== GEMM1: zxbcdt = feature @ in_proj^T; epilogue -> z16 / xbc16 / dtb ========
// XCD-band swizzle for L2; XOR bank-swizzle in LDS: slot (row, j) holds global
// chunk j^(row&7); fragment reads use chunk q^(r16&7) -> 2-way max (free).
__global__ __launch_bounds__(256)
void gemm1_mfma(const __hip_bfloat16* __restrict__ A,   // fbf [ROWS][768]
                const __hip_bfloat16* __restrict__ W,   // wbf [3456][768]
                __hip_bfloat16* __restrict__ z16, __hip_bfloat16* __restrict__ xbc16,
                float* __restrict__ dtb, const float* __restrict__ dt_bias)
{
    __shared__ __align__(16) char smem[128*LDE*2];      // 34816 B
    __hip_bfloat16* Asm = (__hip_bfloat16*)smem;
    __hip_bfloat16* Wsm = Asm + 128*64;
    const int tid = threadIdx.x;
    const int lane = tid & 63, wave = tid >> 6;
    const int blk = blockIdx.x;
    const int m_tile = ((blk & 7) << 3) | ((blk >> 3) & 7);   // XCD M-band
    const int bx = blk >> 6;                                   // N-tile 0..26
    const int bm = m_tile*128, bn = bx*128;
    const int wm = (wave & 1)*64, wn = (wave >> 1)*64;
    const int r16 = lane & 15, qbase = lane >> 4, sw = r16 & 7;
    floatx4 acc[4][4] = {};
    for (int k0 = 0; k0 < DMODEL; k0 += 64) {
#pragma unroll
        for (int j = 0; j < 4; ++j) {
            int cc = j*256 + tid;
            int row = cc >> 3, jc = cc & 7;
            int sj = jc ^ (row & 7);               // bank swizzle source chunk
            gload_lds16(A + (size_t)(bm+row)*DMODEL + k0 + sj*8, Asm + cc*8);
            gload_lds16(W + (size_t)(bn+row)*DMODEL + k0 + sj*8, Wsm + cc*8);
        }
        __syncthreads();
#pragma unroll
        for (int ks = 0; ks < 2; ++ks) {
            const int kq = ((qbase + ks*4) ^ sw)*8;   // swizzled chunk offset
            bf16x8 af[4], wf[4];
#pragma unroll
            for (int i = 0; i < 4; ++i) {
                af[i] = *(const bf16x8*)(Asm + (wm + i*16 + r16)*64 + kq);
                wf[i] = *(const bf16x8*)(Wsm + (wn + i*16 + r16)*64 + kq);
            }
#pragma unroll
            for (int mi = 0; mi < 4; ++mi)
#pragma unroll
                for (int ni = 0; ni < 4; ++ni)
                    acc[mi][ni] = __builtin_amdgcn_mfma_f32_16x16x32_bf16(
                        af[mi], wf[ni], acc[mi][ni], 0, 0, 0);
        }
        __syncthreads();
    }
    const int col = lane & 15, rowq = (lane >> 4)*4;
    if (bx == 26) {
        if (wn == 0) {
#pragma unroll
            for (int mi = 0; mi < 4; ++mi)
#pragma unroll
                for (int ni = 0; ni < 2; ++ni) {
                    int h = ni*16 + col;
                    if (h < NHEADS)
#pragma unroll
                        for (int r = 0; r < 4; ++r) {
                            int m = bm + wm + mi*16 + rowq + r;
                            dtb[(size_t)m*NHEADS + h] =
                                softplusf_(acc[mi][ni][r] + dt_bias[h]);
                        }
                }
        }
        return;
    }
    __hip_bfloat16* Tsm = (__hip_bfloat16*)smem;
#pragma unroll
    for (int mi = 0; mi < 4; ++mi)
#pragma unroll
        for (int ni = 0; ni < 4; ++ni)
#pragma unroll
            for (int r = 0; r < 4; ++r)
                Tsm[(wm + mi*16 + rowq + r)*LDE + wn + ni*16 + col] =
                    __float2bfloat16(acc[mi][ni][r]);
    __syncthreads();
    __hip_bfloat16* dst; int ldd;
    if (bx < 12) { dst = z16 + bn;            ldd = DINNER; }
    else         { dst = xbc16 + bn - DINNER; ldd = DXBC;  }
#pragma unroll
    for (int it = 0; it < 8; ++it) {
        int e = it*256 + tid;
        int row = e >> 4, c0 = (e & 15)*8;
        bf16x8 v = *(const bf16x8*)(Tsm + row*LDE + c0);
        *(bf16x8*)(dst + (size_t)(bm+row)*ldd + c0) = v;
    }
}

// ======== GEMM2: out = sigmoid(gate)*(y16 @ out_w^T) + feature ========
__global__ __launch_bounds__(256)
void gemm2_mfma(const __hip_bfloat16* __restrict__ A,   // y16 [ROWS][1536]
                const __hip_bfloat16* __restrict__ W,   // owbf [768][1536]
                float* __restrict__ C,
                const float* __restrict__ gate, const float* __restrict__ resid)
{
    __shared__ __align__(16) char smem[128*LDE*2];
    __hip_bfloat16* Asm = (__hip_bfloat16*)smem;
    __hip_bfloat16* Wsm = Asm + 128*64;
    const int tid = threadIdx.x;
    const int lane = tid & 63, wave = tid >> 6;
    const int blk = blockIdx.x;
    const int m_tile = ((blk & 7) << 3) | ((blk >> 3) & 7);
    const int bm = m_tile*128, bn = (blk >> 6)*128;             // n-tile 0..5
    const int wm = (wave & 1)*64, wn = (wave >> 1)*64;
    const int r16 = lane & 15, qbase = lane >> 4, sw = r16 & 7;
    floatx4 acc[4][4] = {};
    for (int k0 = 0; k0 < DINNER; k0 += 64) {
#pragma unroll
        for (int j = 0; j < 4; ++j) {
            int cc = j*256 + tid;
            int row = cc >> 3, jc = cc & 7;
            int sj = jc ^ (row & 7);
            gload_lds16(A + (size_t)(bm+row)*DINNER + k0 + sj*8, Asm + cc*8);
            gload_lds16(W + (size_t)(bn+row)*DINNER + k0 + sj*8, Wsm + cc*8);
        }
        __syncthreads();
#pragma unroll
        for (int ks = 0; ks < 2; ++ks) {
            const int kq = ((qbase + ks*4) ^ sw)*8;
            bf16x8 af[4], wf[4];
#pragma unroll
            for (int i = 0; i < 4; ++i) {
                af[i] = *(const bf16x8*)(Asm + (wm + i*16 + r16)*64 + kq);
                wf[i] = *(const bf16x8*)(Wsm + (wn + i*16 + r16)*64 + kq);
            }
#pragma unroll
            for (int mi = 0; mi < 4; ++mi)
#pragma unroll
                for (int ni = 0; ni < 4; ++ni)
                    acc[mi][ni] = __builtin_amdgcn_mfma_f32_16x16x32_bf16(
                        af[mi], wf[ni], acc[mi][ni], 0, 0, 0);
        }
        __syncthreads();
    }
    float gs = sigmoidf_(gate[0]);
    const int col = lane & 15, rowq = (lane >> 4)*4;
    float* Tsm = (float*)smem;   // 64 x LDE2 fp32
    for (int half = 0; half < 2; ++half) {
        if ((wave & 1) == half) {
#pragma unroll
            for (int mi = 0; mi < 4; ++mi)
#pragma unroll
                for (int ni = 0; ni < 4; ++ni)
#pragma unroll
                    for (int r = 0; r < 4; ++r)
                        Tsm[(mi*16 + rowq + r)*LDE2 + wn + ni*16 + col] = acc[mi][ni][r];
        }
        __syncthreads();
#pragma unroll
        for (int it = 0; it < 8; ++it) {
            int e = it*256 + tid;
            int row = e >> 5, c0 = (e & 31)*4;
            float4 v = *(const float4*)(Tsm + row*LDE2 + c0);
            size_t off = (size_t)(bm + half*64 + row)*DMODEL + bn + c0;
            float4 rv = *(const float4*)(resid + off);
            v.x = gs*v.x + rv.x; v.y = gs*v.y + rv.y;
            v.z = gs*v.z + rv.z; v.w = gs*v.w + rv.w;
            *(float4*)(C + off) = v;
        }
        __syncthreads();
    }
}

// ---------------- fp32 -> bf16 casts ----------------
__global__ __launch_bounds__(256)
void cast_k(const float* __restrict__ src, __hip_bfloat16* __restrict__ dst, int n)
{
    int i = blockIdx.x*256 + threadIdx.x;
    if (i < n) dst[i] = __float2bfloat16(src[i]);
}
__global__ __launch_bounds__(256)
void cast_w1_k(const float* __restrict__ src, __hip_bfloat16* __restrict__ dst)
{
    int i = blockIdx.x*256 + threadIdx.x;
    if (i >= NPAD1*DMODEL) return;
    int n = i / DMODEL, k = i % DMODEL;
    dst[i] = __float2bfloat16(n < DPROJ ? src[(size_t)n*DMODEL + k] : 0.f);
}

// ======== conv4+SiLU, emits x_bf/x_t/B_n/B_t/C_n in MFMA-ready layouts ========
__global__ __launch_bounds__(256)
void conv_k(const __hip_bfloat16* __restrict__ xbc16, const float* __restrict__ cw,
            const float* __restrict__ cbias,
            __hip_bfloat16* __restrict__ x_bf, __hip_bfloat16* __restrict__ x_t,
            __hip_bfloat16* __restrict__ B_n, __hip_bfloat16* __restrict__ B_t,
            __hip_bfloat16* __restrict__ C_n)
{
    __shared__ __align__(16) __hip_bfloat16 in[131*LDTC];
    int ct = blockIdx.x, lt = blockIdx.y, b = blockIdx.z;
    int tid = threadIdx.x;
    int base = lt*128;
    for (int it = 0; it < 2096; it += 256) {
        int e = it + tid; if (e >= 2096) break;
        int row = e >> 4, c0 = (e & 15)*8;
        int l = base - 3 + row;
        bf16x8 v;
        if (l < 0) { for (int j = 0; j < 8; ++j) v[j] = (__bf16)0.f; }
        else v = *(const bf16x8*)(xbc16 + ((size_t)b*SEQ + l)*DXBC + ct*128 + c0);
        *(bf16x8*)(in + row*LDTC + c0) = v;
    }
    __syncthreads();
    int ch = tid & 127, lh = tid >> 7, l0 = lh*64;
    int g = ct*128 + ch;
    float w0 = cw[g*4+0], w1 = cw[g*4+1], w2 = cw[g*4+2], w3 = cw[g*4+3];
    float bias = cbias[g];
    float a0 = __bfloat162float(in[(l0+0)*LDTC + ch]);
    float a1 = __bfloat162float(in[(l0+1)*LDTC + ch]);
    float a2 = __bfloat162float(in[(l0+2)*LDTC + ch]);
    size_t trow = 0;
    if (ct < 12)      trow = ((size_t)b*NHEADS + (g>>6))*HEADDIM + (g & 63);
    else if (ct == 12) trow = (size_t)b*DSTATE + ch;
    bf16x8 obuf;
#pragma unroll
    for (int li = 0; li < 64; ++li) {
        float a3 = __bfloat162float(in[(l0+li+3)*LDTC + ch]);
        float o = siluf_(bias + w0*a0 + w1*a1 + w2*a2 + w3*a3);
        a0 = a1; a1 = a2; a2 = a3;
        __hip_bfloat16 ob = __float2bfloat16(o);
        size_t rr = (size_t)b*SEQ + base + l0 + li;
        if (ct < 12)       x_bf[rr*DINNER + g] = ob;
        else if (ct == 12) B_n[rr*DSTATE + ch] = ob;
        else               C_n[rr*DSTATE + ch] = ob;
        obuf[li & 7] = *(const __bf16*)&ob;
        if ((li & 7) == 7 && ct <= 12) {
            __hip_bfloat16* dst = (ct < 12) ? x_t : B_t;
            *(bf16x8*)(dst + trow*SEQ + base + l0 + (li - 7)) = obuf;
        }
    }
}

// ---------------- intra-chunk inclusive cumsum of dt*A ----------------
__global__ __launch_bounds__(128)
void scan_k(const float* __restrict__ dtb, const float* __restrict__ A_log,
            float* __restrict__ acum)
{
    int c = blockIdx.x & 31;
    int h = (blockIdx.x >> 5) % NHEADS;
    int b = blockIdx.x / (32*NHEADS);
    int l = threadIdx.x;
    float A = -expf(A_log[h]);
    size_t row = (size_t)b*SEQ + c*CHUNK + l;
    float v = dtb[row*NHEADS + h] * A;
    __shared__ float sh[128];
    sh[l] = v; __syncthreads();
    for (int off=1; off<128; off<<=1){
        float t = (l>=off) ? sh[l-off] : 0.f;
        __syncthreads();
        sh[l] += t;
        __syncthreads();
    }
    acum[((b*NHEADS+h)*NCHUNK + c)*CHUNK + l] = sh[l];
}

// ======== CB[l][s] = sum_n C[l][n]*B[s][n], per (b,c), LDS-free, tril tiles only ========
__global__ __launch_bounds__(256)
void cb_mfma(const __hip_bfloat16* __restrict__ B_n, const __hip_bfloat16* __restrict__ C_n,
             __hip_bfloat16* __restrict__ CB16)
{
    int c = blockIdx.x & 31, b = blockIdx.x >> 5;
    size_t base = (size_t)b*SEQ + c*CHUNK;
    int tid = threadIdx.x, lane = tid & 63, wave = tid >> 6;
    int r16 = lane & 15, kq = (lane>>4)*8;
    floatx4 acc[2][8] = {};
#pragma unroll
    for (int ks = 0; ks < 4; ++ks) {
        int k0 = ks*32 + kq;
        bf16x8 af[2], bfv[8];
#pragma unroll
        for (int mt = 0; mt < 2; ++mt)
            af[mt] = *(const bf16x8*)(C_n + (base + (wave*2+mt)*16 + r16)*DSTATE + k0);
#pragma unroll
        for (int st = 0; st < 8; ++st)
            bfv[st] = *(const bf16x8*)(B_n + (base + st*16 + r16)*DSTATE + k0);
#pragma unroll
        for (int mt = 0; mt < 2; ++mt)
#pragma unroll
            for (int st = 0; st < 8; ++st)
                if (st <= wave*2+mt)
                    acc[mt][st] = __builtin_amdgcn_mfma_f32_16x16x32_bf16(
                        af[mt], bfv[st], acc[mt][st], 0,0,0);
    }
    size_t cbb = (size_t)(b*NCHUNK+c)*CHUNK*CHUNK;
    int scol = lane & 15, rowq = (lane>>4)*4;
#pragma unroll
    for (int mt = 0; mt < 2; ++mt)
#pragma unroll
        for (int st = 0; st < 8; ++st)
            if (st <= wave*2+mt)
#pragma unroll
                for (int r = 0; r < 4; ++r)
                    CB16[cbb + (size_t)((wave*2+mt)*16 + rowq + r)*CHUNK + st*16 + scol] =
                        __float2bfloat16(acc[mt][st][r]);
}

// ======== states[p][n] = sum_l (x[l,p]*f[l]) * B[l,n], f = dt*dec ========
__global__ __launch_bounds__(256)
void states_mfma(const __hip_bfloat16* __restrict__ x_t, const __hip_bfloat16* __restrict__ B_t,
                 const float* __restrict__ dtb, const float* __restrict__ acum,
                 __hip_bfloat16* __restrict__ states)
{
    __shared__ float f[128];
    int c = blockIdx.x & 31;
    int h = (blockIdx.x>>5) % NHEADS;
    int b = blockIdx.x/(32*NHEADS);
    int tid = threadIdx.x, lane = tid & 63, wave = tid >> 6;
    int arow = ((b*NHEADS+h)*NCHUNK + c)*CHUNK;
    size_t rbase = (size_t)b*SEQ + c*CHUNK;
    if (tid < 128) {
        float alast = acum[arow + 127];
        f[tid] = dtb[(rbase + tid)*NHEADS + h] * expf(alast - acum[arow + tid]);
    }
    __syncthreads();
    int r16 = lane & 15, kq = (lane>>4)*8;
    size_t xtb = ((size_t)b*NHEADS + h)*HEADDIM;
    int cl = c*CHUNK;
    floatx4 acc[8] = {};
#pragma unroll
    for (int ks = 0; ks < 4; ++ks) {
        int k0 = ks*32 + kq;
        bf16x8 xa = *(const bf16x8*)(x_t + (xtb + wave*16 + r16)*SEQ + cl + k0);
        bf16x8 af;
#pragma unroll
        for (int j = 0; j < 8; ++j)
            af[j] = (__bf16)((float)xa[j] * f[k0 + j]);
        bf16x8 bfv[8];
#pragma unroll
        for (int nt = 0; nt < 8; ++nt)
            bfv[nt] = *(const bf16x8*)(B_t + ((size_t)b*DSTATE + nt*16 + r16)*SEQ + cl + k0);
#pragma unroll
        for (int nt = 0; nt < 8; ++nt)
            acc[nt] = __builtin_amdgcn_mfma_f32_16x16x32_bf16(af, bfv[nt], acc[nt], 0,0,0);
    }
    size_t sb = ((size_t)(b*NCHUNK+c)*NHEADS + h)*(HEADDIM*DSTATE);
    int ncol = lane & 15, rowq = (lane>>4)*4;
#pragma unroll
    for (int nt = 0; nt < 8; ++nt)
#pragma unroll
        for (int r = 0; r < 4; ++r)
            states[sb + (size_t)(wave*16 + rowq + r)*DSTATE + nt*16 + ncol] =
                __float2bfloat16(acc[nt][r]);
}

// ---- sequential inter-chunk recurrence, in place (bf16): states[c] := prev[c] ----
__global__ __launch_bounds__(256)
void recur_k(__hip_bfloat16* __restrict__ states, const float* __restrict__ acum)
{
    int pb = blockIdx.x & 3;
    int bh = blockIdx.x >> 2;
    int h = bh % NHEADS, b = bh / NHEADS;
    int voff = (pb*256 + threadIdx.x)*8;
    float S[8] = {};
    for (int c = 0; c < NCHUNK; ++c) {
        size_t addr = ((size_t)(b*NCHUNK+c)*NHEADS + h)*(HEADDIM*DSTATE) + voff;
        bf16x8 st = *(bf16x8*)(states + addr);
        float e = expf(acum[((b*NHEADS+h)*NCHUNK + c)*CHUNK + 127]);
        bf16x8 pv;
#pragma unroll
        for (int j = 0; j < 8; ++j) {
            pv[j] = (__bf16)S[j];
            S[j] = S[j]*e + (float)st[j];
        }
        *(bf16x8*)(states + addr) = pv;
    }
}

// ======== Y = tril(CB*exp(dAc)*dt) @ x  +  (C*exp(ac)) @ prev^T  +  D*x ========
__global__ __launch_bounds__(512)
void y_mfma(const __hip_bfloat16* __restrict__ x_t, const __hip_bfloat16* __restrict__ x_bf,
            const __hip_bfloat16* __restrict__ C_n, const __hip_bfloat16* __restrict__ CB16,
            const __hip_bfloat16* __restrict__ states, const float* __restrict__ dtb,
            const float* __restrict__ acum, const float* __restrict__ Dp,
            __hip_bfloat16* __restrict__ y16)
{
    __shared__ float ac[128], dts[128];
    int c = blockIdx.x & 31;
    int h = (blockIdx.x>>5) % NHEADS;
    int b = blockIdx.x/(32*NHEADS);
    int tid = threadIdx.x, lane = tid & 63, wave = tid >> 6;
    int arow = ((b*NHEADS+h)*NCHUNK + c)*CHUNK;
    size_t rbase = (size_t)b*SEQ + c*CHUNK;
    if (tid < 128) {
        ac[tid]  = acum[arow + tid];
        dts[tid] = dtb[(rbase + tid)*NHEADS + h];
    }
    __syncthreads();
    int r16 = lane & 15, kq = (lane>>4)*8;
    int l = wave*16 + r16;
    float acl = ac[l];
    size_t cbb = (size_t)(b*NCHUNK+c)*CHUNK*CHUNK;
    size_t xtb = ((size_t)b*NHEADS + h)*HEADDIM;
    int cl = c*CHUNK;
    floatx4 acc[4] = {};
    int nks = ((wave+1)*16 + 31) >> 5;
    for (int ks = 0; ks < nks; ++ks) {
        int k0 = ks*32 + kq;
        bf16x8 cbv = *(const bf16x8*)(CB16 + cbb + (size_t)l*CHUNK + k0);
        bf16x8 af;
#pragma unroll
        for (int j = 0; j < 8; ++j) {
            int s = k0 + j;
            float w = (s <= l) ? (float)cbv[j] * expf(acl - ac[s]) * dts[s] : 0.f;
            af[j] = (__bf16)w;
        }
        bf16x8 bfv[4];
#pragma unroll
        for (int pt = 0; pt < 4; ++pt)
            bfv[pt] = *(const bf16x8*)(x_t + (xtb + pt*16 + r16)*SEQ + cl + k0);
#pragma unroll
        for (int pt = 0; pt < 4; ++pt)
            acc[pt] = __builtin_amdgcn_mfma_f32_16x16x32_bf16(af, bfv[pt], acc[pt], 0,0,0);
    }
    float eal = expf(acl);
    size_t sb = ((size_t)(b*NCHUNK+c)*NHEADS + h)*(HEADDIM*DSTATE);
#pragma unroll
    for (int ks = 0; ks < 4; ++ks) {
        int k0 = ks*32 + kq;
        bf16x8 cv = *(const bf16x8*)(C_n + (rbase + l)*DSTATE + k0);
        bf16x8 af;
#pragma unroll
        for (int j = 0; j < 8; ++j)
            af[j] = (__bf16)((float)cv[j] * eal);
        bf16x8 bfv[4];
#pragma unroll
        for (int pt = 0; pt < 4; ++pt)
            bfv[pt] = *(const bf16x8*)(states + sb + (size_t)(pt*16 + r16)*DSTATE + k0);
#pragma unroll
        for (int pt = 0; pt < 4; ++pt)
            acc[pt] = __builtin_amdgcn_mfma_f32_16x16x32_bf16(af, bfv[pt], acc[pt], 0,0,0);
    }
    float Dh = Dp[h];
    int pcol = lane & 15, rowq = (lane>>4)*4;
#pragma unroll
    for (int pt = 0; pt < 4; ++pt)
#pragma unroll
        for (int r = 0; r < 4; ++r) {
            int ll = wave*16 + rowq + r;
            int p = pt*16 + pcol;
            size_t rr = rbase + ll;
            float x = __bfloat162float(x_bf[rr*DINNER + h*HEADDIM + p]);
            y16[rr*DINNER + h*HEADDIM + p] = __float2bfloat16(acc[pt][r] + Dh*x);
        }
}

// ------- y16 *= silu(z16); RMSNorm * norm_w (in place, bf16, vectorized) -------------
__global__ __launch_bounds__(256)
void norm_k(__hip_bfloat16* __restrict__ y16, const __hip_bfloat16* __restrict__ z16,
            const float* __restrict__ nw)
{
    int r = blockIdx.x, tid = threadIdx.x;
    float v[8]; float ss = 0.f;
    int c0 = tid*8;
    if (tid < 192) {
        bf16x8 zv = *(const bf16x8*)(z16 + (size_t)r*DINNER + c0);
        bf16x8 yv = *(const bf16x8*)(y16 + (size_t)r*DINNER + c0);
#pragma unroll
        for (int j = 0; j < 8; ++j) {
            float g = (float)yv[j] * siluf_((float)zv[j]);
            v[j] = g; ss += g*g;
        }
    }
    for (int off=32; off; off>>=1) ss += __shfl_down(ss, off);
    __shared__ float red[4];
    __shared__ float stot;
    int lane = tid & 63, wid = tid >> 6;
    if (lane==0) red[wid] = ss;
    __syncthreads();
    if (tid==0) stot = red[0]+red[1]+red[2]+red[3];
    __syncthreads();
    float scale = rsqrtf(stot * (1.f/DINNER) + 1e-5f);
    if (tid < 192) {
        bf16x8 ov;
#pragma unroll
        for (int j = 0; j < 8; ++j)
            ov[j] = (__bf16)(v[j]*scale*nw[c0+j]);
        *(bf16x8*)(y16 + (size_t)r*DINNER + c0) = ov;
    }
}

extern "C" void kernel_launch(void* const* d_in, const int* in_sizes, int n_in,
                              void* d_out, int out_size, void* d_ws, size_t ws_size,
                              hipStream_t stream)
{
    const float* feature = (const float*)d_in[0];
    const float* gate1   = (const float*)d_in[1];
    const float* in_w    = (const float*)d_in[2];
    const float* conv_w  = (const float*)d_in[3];
    const float* conv_b  = (const float*)d_in[4];
    const float* dt_bias = (const float*)d_in[5];
    const float* A_log   = (const float*)d_in[6];
    const float* Dp      = (const float*)d_in[7];
    const float* norm_w  = (const float*)d_in[8];
    const float* out_w   = (const float*)d_in[9];
    float* out = (float*)d_out;

    // workspace layout — ~186 MB (< 256 MiB)
    char* p = (char*)d_ws;
    __hip_bfloat16* z16   = (__hip_bfloat16*)p; p += (size_t)ROWS*DINNER*2;  // 25.2 MB
    __hip_bfloat16* xbc16 = (__hip_bfloat16*)p; p += (size_t)ROWS*DXBC*2;    // 29.4 MB
    __hip_bfloat16* x_bf  = (__hip_bfloat16*)p; p += (size_t)ROWS*DINNER*2;  // 25.2 MB
    __hip_bfloat16* x_t   = (__hip_bfloat16*)p; p += (size_t)ROWS*DINNER*2;  // 25.2 MB
    __hip_bfloat16* B_n   = (__hip_bfloat16*)p; p += (size_t)ROWS*DSTATE*2;  // 2.1 MB
    __hip_bfloat16* B_t   = (__hip_bfloat16*)p; p += (size_t)ROWS*DSTATE*2;  // 2.1 MB
    __hip_bfloat16* C_n   = (__hip_bfloat16*)p; p += (size_t)ROWS*DSTATE*2;  // 2.1 MB
    float* dtb    = (float*)p;            p += (size_t)ROWS*NHEADS*4;        // 0.8 MB
    float* acum   = (float*)p;            p += (size_t)B_SZ*NHEADS*NCHUNK*CHUNK*4; // 0.8 MB
    __hip_bfloat16* CB16 = (__hip_bfloat16*)p; p += (size_t)B_SZ*NCHUNK*CHUNK*CHUNK*2; // 2.1 MB
    __hip_bfloat16* states = (__hip_bfloat16*)p; p += (size_t)B_SZ*NCHUNK*NHEADS*HEADDIM*DSTATE*2; // 25.2 MB
    __hip_bfloat16* y16  = (__hip_bfloat16*)p; p += (size_t)ROWS*DINNER*2;   // 25.2 MB
    __hip_bfloat16* fbf  = (__hip_bfloat16*)p; p += (size_t)ROWS*DMODEL*2;   // 12.6 MB
    __hip_bfloat16* wbf  = (__hip_bfloat16*)p; p += (size_t)NPAD1*DMODEL*2;  //  5.3 MB
    __hip_bfloat16* owbf = (__hip_bfloat16*)p; p += (size_t)DMODEL*DINNER*2; //  2.4 MB

    cast_k<<<(ROWS*DMODEL+255)/256, 256, 0, stream>>>(feature, fbf, ROWS*DMODEL);
    cast_w1_k<<<(NPAD1*DMODEL+255)/256, 256, 0, stream>>>(in_w, wbf);
    cast_k<<<(DMODEL*DINNER+255)/256, 256, 0, stream>>>(out_w, owbf, DMODEL*DINNER);

    gemm1_mfma<<<27*64, 256, 0, stream>>>(fbf, wbf, z16, xbc16, dtb, dt_bias);
    conv_k<<<dim3(14, 32, B_SZ), 256, 0, stream>>>(xbc16, conv_w, conv_b,
                                                   x_bf, x_t, B_n, B_t, C_n);
    scan_k<<<B_SZ*NHEADS*NCHUNK, 128, 0, stream>>>(dtb, A_log, acum);
    cb_mfma<<<B_SZ*NCHUNK, 256, 0, stream>>>(B_n, C_n, CB16);
    states_mfma<<<B_SZ*NHEADS*NCHUNK, 256, 0, stream>>>(x_t, B_t, dtb, acum, states);
    recur_k<<<B_SZ*NHEADS*4, 256, 0, stream>>>(states, acum);
    y_mfma<<<B_SZ*NHEADS*NCHUNK, 512, 0, stream>>>(x_t, x_bf, C_n, CB16, states,
                                                   dtb, acum, Dp, y16);
    norm_k<<<ROWS, 256, 0, stream>>>(y16, z16, norm_w);
    gemm2_mfma<<<6*64, 256, 0, stream>>>(y16, owbf, out, gate1, feature);
}

// Round 9
// 347.726 us; speedup vs baseline: 5.1150x; 1.0799x over previous
//
#include <hip/hip_runtime.h>
#include <hip/hip_bf16.h>
#include <math.h>

#define B_SZ 2
#define SEQ 4096
#define DMODEL 768
#define DSTATE 128
#define HEADDIM 64
#define DINNER 1536
#define NHEADS 24
#define DXBC 1792
#define DPROJ 3352
#define NPAD1 3456
#define CHUNK 128
#define NCHUNK 32
#define ROWS (B_SZ*SEQ)
#define LDTC 136   // padded LDS stride for conv input tile
#define LDE 136    // padded LDS stride (bf16) for epilogue tiles
#define LDE2 132   // padded LDS stride (fp32) for gemm2 epilogue tile

typedef float floatx4 __attribute__((ext_vector_type(4)));
typedef __bf16 bf16x8 __attribute__((ext_vector_type(8)));

__device__ __forceinline__ float sigmoidf_(float x){ return 1.f/(1.f+expf(-x)); }
__device__ __forceinline__ float siluf_(float x){ return x/(1.f+expf(-x)); }
__device__ __forceinline__ float softplusf_(float x){ return (x>20.f)? x : log1pf(expf(x)); }

__device__ __forceinline__ void gload_lds16(const __hip_bfloat16* g, __hip_bfloat16* l){
    __builtin_amdgcn_global_load_lds(
        (const __attribute__((address_space(1))) void*)g,
        (__attribute__((address_space(3))) void*)l, 16, 0, 0);
}

// ======== GEMM1: 256x128 tile, 8 waves; epilogue -> z16 / xbc16 / dtb ========
// XCD band (4 M-tiles/XCD) for L2; XOR bank-swizzle in LDS staging.
__global__ __launch_bounds__(512)
void gemm1_mfma(const __hip_bfloat16* __restrict__ A,   // fbf [ROWS][768]
                const __hip_bfloat16* __restrict__ W,   // wbf [3456][768]
                __hip_bfloat16* __restrict__ z16, __hip_bfloat16* __restrict__ xbc16,
                float* __restrict__ dtb, const float* __restrict__ dt_bias)
{
    __shared__ __align__(16) char smem[49152];          // Asm 32K + Wsm 16K
    __hip_bfloat16* Asm = (__hip_bfloat16*)smem;        // [256][64]
    __hip_bfloat16* Wsm = Asm + 256*64;                 // [128][64]
    const int tid = threadIdx.x;
    const int lane = tid & 63, wave = tid >> 6;
    const int blk = blockIdx.x;
    const int m_tile = ((blk & 7) << 2) | ((blk >> 3) & 3);   // 32 M-tiles, XCD band
    const int bx = blk >> 5;                                   // N-tile 0..26
    const int bm = m_tile*256, bn = bx*128;
    const int wm = (wave & 3)*64, wn = (wave >> 2)*64;
    const int r16 = lane & 15, qbase = lane >> 4, sw = r16 & 7;
    floatx4 acc[4][4] = {};
    for (int k0 = 0; k0 < DMODEL; k0 += 64) {
#pragma unroll
        for (int j = 0; j < 4; ++j) {
            int cc = j*512 + tid;                // A: 2048 chunks
            int row = cc >> 3, jc = cc & 7;
            int sj = jc ^ (row & 7);
            gload_lds16(A + (size_t)(bm+row)*DMODEL + k0 + sj*8, Asm + cc*8);
        }
#pragma unroll
        for (int j = 0; j < 2; ++j) {
            int cc = j*512 + tid;                // W: 1024 chunks
            int row = cc >> 3, jc = cc & 7;
            int sj = jc ^ (row & 7);
            gload_lds16(W + (size_t)(bn+row)*DMODEL + k0 + sj*8, Wsm + cc*8);
        }
        __syncthreads();
#pragma unroll
        for (int ks = 0; ks < 2; ++ks) {
            const int kq = ((qbase + ks*4) ^ sw)*8;
            bf16x8 af[4], wf[4];
#pragma unroll
            for (int i = 0; i < 4; ++i) {
                af[i] = *(const bf16x8*)(Asm + (wm + i*16 + r16)*64 + kq);
                wf[i] = *(const bf16x8*)(Wsm + (wn + i*16 + r16)*64 + kq);
            }
#pragma unroll
            for (int mi = 0; mi < 4; ++mi)
#pragma unroll
                for (int ni = 0; ni < 4; ++ni)
                    acc[mi][ni] = __builtin_amdgcn_mfma_f32_16x16x32_bf16(
                        af[mi], wf[ni], acc[mi][ni], 0, 0, 0);
        }
        __syncthreads();
    }
    const int col = lane & 15, rowq = (lane >> 4)*4;
    if (bx == 26) {
        if (wn == 0) {           // waves 0..3 cover all 256 rows
#pragma unroll
            for (int mi = 0; mi < 4; ++mi)
#pragma unroll
                for (int ni = 0; ni < 2; ++ni) {
                    int h = ni*16 + col;
                    if (h < NHEADS)
#pragma unroll
                        for (int r = 0; r < 4; ++r) {
                            int m = bm + wm + mi*16 + rowq + r;
                            dtb[(size_t)m*NHEADS + h] =
                                softplusf_(acc[mi][ni][r] + dt_bias[h]);
                        }
                }
        }
        return;
    }
    __hip_bfloat16* Tsm = (__hip_bfloat16*)smem;   // [128][LDE]
    __hip_bfloat16* dst; int ldd;
    if (bx < 12) { dst = z16 + bn;            ldd = DINNER; }
    else         { dst = xbc16 + bn - DINNER; ldd = DXBC;  }
    for (int half = 0; half < 2; ++half) {
        if (((wave & 3) >> 1) == half) {
#pragma unroll
            for (int mi = 0; mi < 4; ++mi)
#pragma unroll
                for (int ni = 0; ni < 4; ++ni)
#pragma unroll
                    for (int r = 0; r < 4; ++r)
                        Tsm[(wm - half*128 + mi*16 + rowq + r)*LDE + wn + ni*16 + col] =
                            __float2bfloat16(acc[mi][ni][r]);
        }
        __syncthreads();
#pragma unroll
        for (int it = 0; it < 4; ++it) {
            int e = it*512 + tid;
            int row = e >> 4, c0 = (e & 15)*8;
            bf16x8 v = *(const bf16x8*)(Tsm + row*LDE + c0);
            *(bf16x8*)(dst + (size_t)(bm + half*128 + row)*ldd + c0) = v;
        }
        __syncthreads();
    }
}

// ======== GEMM2: out = sigmoid(gate)*(y16 @ out_w^T) + feature ========
__global__ __launch_bounds__(256)
void gemm2_mfma(const __hip_bfloat16* __restrict__ A,   // y16 [ROWS][1536]
                const __hip_bfloat16* __restrict__ W,   // owbf [768][1536]
                float* __restrict__ C,
                const float* __restrict__ gate, const float* __restrict__ resid)
{
    __shared__ __align__(16) char smem[128*LDE*2];
    __hip_bfloat16* Asm = (__hip_bfloat16*)smem;
    __hip_bfloat16* Wsm = Asm + 128*64;
    const int tid = threadIdx.x;
    const int lane = tid & 63, wave = tid >> 6;
    const int blk = blockIdx.x;
    const int m_tile = ((blk & 7) << 3) | ((blk >> 3) & 7);
    const int bm = m_tile*128, bn = (blk >> 6)*128;             // n-tile 0..5
    const int wm = (wave & 1)*64, wn = (wave >> 1)*64;
    const int r16 = lane & 15, qbase = lane >> 4, sw = r16 & 7;
    floatx4 acc[4][4] = {};
    for (int k0 = 0; k0 < DINNER; k0 += 64) {
#pragma unroll
        for (int j = 0; j < 4; ++j) {
            int cc = j*256 + tid;
            int row = cc >> 3, jc = cc & 7;
            int sj = jc ^ (row & 7);
            gload_lds16(A + (size_t)(bm+row)*DINNER + k0 + sj*8, Asm + cc*8);
            gload_lds16(W + (size_t)(bn+row)*DINNER + k0 + sj*8, Wsm + cc*8);
        }
        __syncthreads();
#pragma unroll
        for (int ks = 0; ks < 2; ++ks) {
            const int kq = ((qbase + ks*4) ^ sw)*8;
            bf16x8 af[4], wf[4];
#pragma unroll
            for (int i = 0; i < 4; ++i) {
                af[i] = *(const bf16x8*)(Asm + (wm + i*16 + r16)*64 + kq);
                wf[i] = *(const bf16x8*)(Wsm + (wn + i*16 + r16)*64 + kq);
            }
#pragma unroll
            for (int mi = 0; mi < 4; ++mi)
#pragma unroll
                for (int ni = 0; ni < 4; ++ni)
                    acc[mi][ni] = __builtin_amdgcn_mfma_f32_16x16x32_bf16(
                        af[mi], wf[ni], acc[mi][ni], 0, 0, 0);
        }
        __syncthreads();
    }
    float gs = sigmoidf_(gate[0]);
    const int col = lane & 15, rowq = (lane >> 4)*4;
    float* Tsm = (float*)smem;   // 64 x LDE2 fp32
    for (int half = 0; half < 2; ++half) {
        if ((wave & 1) == half) {
#pragma unroll
            for (int mi = 0; mi < 4; ++mi)
#pragma unroll
                for (int ni = 0; ni < 4; ++ni)
#pragma unroll
                    for (int r = 0; r < 4; ++r)
                        Tsm[(mi*16 + rowq + r)*LDE2 + wn + ni*16 + col] = acc[mi][ni][r];
        }
        __syncthreads();
#pragma unroll
        for (int it = 0; it < 8; ++it) {
            int e = it*256 + tid;
            int row = e >> 5, c0 = (e & 31)*4;
            float4 v = *(const float4*)(Tsm + row*LDE2 + c0);
            size_t off = (size_t)(bm + half*64 + row)*DMODEL + bn + c0;
            float4 rv = *(const float4*)(resid + off);
            v.x = gs*v.x + rv.x; v.y = gs*v.y + rv.y;
            v.z = gs*v.z + rv.z; v.w = gs*v.w + rv.w;
            *(float4*)(C + off) = v;
        }
        __syncthreads();
    }
}

// ---------------- fp32 -> bf16 casts ----------------
__global__ __launch_bounds__(256)
void cast_k(const float* __restrict__ src, __hip_bfloat16* __restrict__ dst, int n)
{
    int i = blockIdx.x*256 + threadIdx.x;
    if (i < n) dst[i] = __float2bfloat16(src[i]);
}
__global__ __launch_bounds__(256)
void cast_w1_k(const float* __restrict__ src, __hip_bfloat16* __restrict__ dst)
{
    int i = blockIdx.x*256 + threadIdx.x;
    if (i >= NPAD1*DMODEL) return;
    int n = i / DMODEL, k = i % DMODEL;
    dst[i] = __float2bfloat16(n < DPROJ ? src[(size_t)n*DMODEL + k] : 0.f);
}

// ======== conv4+SiLU, emits x_t/B_n/B_t/C_n in MFMA-ready layouts ========
__global__ __launch_bounds__(256)
void conv_k(const __hip_bfloat16* __restrict__ xbc16, const float* __restrict__ cw,
            const float* __restrict__ cbias,
            __hip_bfloat16* __restrict__ x_t,
            __hip_bfloat16* __restrict__ B_n, __hip_bfloat16* __restrict__ B_t,
            __hip_bfloat16* __restrict__ C_n)
{
    __shared__ __align__(16) __hip_bfloat16 in[131*LDTC];
    int ct = blockIdx.x, lt = blockIdx.y, b = blockIdx.z;
    int tid = threadIdx.x;
    int base = lt*128;
    for (int it = 0; it < 2096; it += 256) {
        int e = it + tid; if (e >= 2096) break;
        int row = e >> 4, c0 = (e & 15)*8;
        int l = base - 3 + row;
        bf16x8 v;
        if (l < 0) { for (int j = 0; j < 8; ++j) v[j] = (__bf16)0.f; }
        else v = *(const bf16x8*)(xbc16 + ((size_t)b*SEQ + l)*DXBC + ct*128 + c0);
        *(bf16x8*)(in + row*LDTC + c0) = v;
    }
    __syncthreads();
    int ch = tid & 127, lh = tid >> 7, l0 = lh*64;
    int g = ct*128 + ch;
    float w0 = cw[g*4+0], w1 = cw[g*4+1], w2 = cw[g*4+2], w3 = cw[g*4+3];
    float bias = cbias[g];
    float a0 = __bfloat162float(in[(l0+0)*LDTC + ch]);
    float a1 = __bfloat162float(in[(l0+1)*LDTC + ch]);
    float a2 = __bfloat162float(in[(l0+2)*LDTC + ch]);
    size_t trow = 0;
    if (ct < 12)      trow = ((size_t)b*NHEADS + (g>>6))*HEADDIM + (g & 63);
    else if (ct == 12) trow = (size_t)b*DSTATE + ch;
    bf16x8 obuf;
#pragma unroll
    for (int li = 0; li < 64; ++li) {
        float a3 = __bfloat162float(in[(l0+li+3)*LDTC + ch]);
        float o = siluf_(bias + w0*a0 + w1*a1 + w2*a2 + w3*a3);
        a0 = a1; a1 = a2; a2 = a3;
        __hip_bfloat16 ob = __float2bfloat16(o);
        size_t rr = (size_t)b*SEQ + base + l0 + li;
        if (ct == 12)      B_n[rr*DSTATE + ch] = ob;
        else if (ct == 13) C_n[rr*DSTATE + ch] = ob;
        obuf[li & 7] = *(const __bf16*)&ob;
        if ((li & 7) == 7 && ct <= 12) {
            __hip_bfloat16* dst = (ct < 12) ? x_t : B_t;
            *(bf16x8*)(dst + trow*SEQ + base + l0 + (li - 7)) = obuf;
        }
    }
}

// ---------------- intra-chunk inclusive cumsum of dt*A ----------------
__global__ __launch_bounds__(128)
void scan_k(const float* __restrict__ dtb, const float* __restrict__ A_log,
            float* __restrict__ acum)
{
    int c = blockIdx.x & 31;
    int h = (blockIdx.x >> 5) % NHEADS;
    int b = blockIdx.x / (32*NHEADS);
    int l = threadIdx.x;
    float A = -expf(A_log[h]);
    size_t row = (size_t)b*SEQ + c*CHUNK + l;
    float v = dtb[row*NHEADS + h] * A;
    __shared__ float sh[128];
    sh[l] = v; __syncthreads();
    for (int off=1; off<128; off<<=1){
        float t = (l>=off) ? sh[l-off] : 0.f;
        __syncthreads();
        sh[l] += t;
        __syncthreads();
    }
    acum[((b*NHEADS+h)*NCHUNK + c)*CHUNK + l] = sh[l];
}

// ======== CB[l][s] = sum_n C[l][n]*B[s][n], per (b,c), LDS-free, tril tiles only ========
__global__ __launch_bounds__(256)
void cb_mfma(const __hip_bfloat16* __restrict__ B_n, const __hip_bfloat16* __restrict__ C_n,
             __hip_bfloat16* __restrict__ CB16)
{
    int c = blockIdx.x & 31, b = blockIdx.x >> 5;
    size_t base = (size_t)b*SEQ + c*CHUNK;
    int tid = threadIdx.x, lane = tid & 63, wave = tid >> 6;
    int r16 = lane & 15, kq = (lane>>4)*8;
    floatx4 acc[2][8] = {};
#pragma unroll
    for (int ks = 0; ks < 4; ++ks) {
        int k0 = ks*32 + kq;
        bf16x8 af[2], bfv[8];
#pragma unroll
        for (int mt = 0; mt < 2; ++mt)
            af[mt] = *(const bf16x8*)(C_n + (base + (wave*2+mt)*16 + r16)*DSTATE + k0);
#pragma unroll
        for (int st = 0; st < 8; ++st)
            bfv[st] = *(const bf16x8*)(B_n + (base + st*16 + r16)*DSTATE + k0);
#pragma unroll
        for (int mt = 0; mt < 2; ++mt)
#pragma unroll
            for (int st = 0; st < 8; ++st)
                if (st <= wave*2+mt)
                    acc[mt][st] = __builtin_amdgcn_mfma_f32_16x16x32_bf16(
                        af[mt], bfv[st], acc[mt][st], 0,0,0);
    }
    size_t cbb = (size_t)(b*NCHUNK+c)*CHUNK*CHUNK;
    int scol = lane & 15, rowq = (lane>>4)*4;
#pragma unroll
    for (int mt = 0; mt < 2; ++mt)
#pragma unroll
        for (int st = 0; st < 8; ++st)
            if (st <= wave*2+mt)
#pragma unroll
                for (int r = 0; r < 4; ++r)
                    CB16[cbb + (size_t)((wave*2+mt)*16 + rowq + r)*CHUNK + st*16 + scol] =
                        __float2bfloat16(acc[mt][st][r]);
}

// ======== states[p][n] = sum_l (x[l,p]*f[l]) * B[l,n], f = dt*dec ========
__global__ __launch_bounds__(256)
void states_mfma(const __hip_bfloat16* __restrict__ x_t, const __hip_bfloat16* __restrict__ B_t,
                 const float* __restrict__ dtb, const float* __restrict__ acum,
                 __hip_bfloat16* __restrict__ states)
{
    __shared__ float f[128];
    int c = blockIdx.x & 31;
    int h = (blockIdx.x>>5) % NHEADS;
    int b = blockIdx.x/(32*NHEADS);
    int tid = threadIdx.x, lane = tid & 63, wave = tid >> 6;
    int arow = ((b*NHEADS+h)*NCHUNK + c)*CHUNK;
    size_t rbase = (size_t)b*SEQ + c*CHUNK;
    if (tid < 128) {
        float alast = acum[arow + 127];
        f[tid] = dtb[(rbase + tid)*NHEADS + h] * expf(alast - acum[arow + tid]);
    }
    __syncthreads();
    int r16 = lane & 15, kq = (lane>>4)*8;
    size_t xtb = ((size_t)b*NHEADS + h)*HEADDIM;
    int cl = c*CHUNK;
    floatx4 acc[8] = {};
#pragma unroll
    for (int ks = 0; ks < 4; ++ks) {
        int k0 = ks*32 + kq;
        bf16x8 xa = *(const bf16x8*)(x_t + (xtb + wave*16 + r16)*SEQ + cl + k0);
        bf16x8 af;
#pragma unroll
        for (int j = 0; j < 8; ++j)
            af[j] = (__bf16)((float)xa[j] * f[k0 + j]);
        bf16x8 bfv[8];
#pragma unroll
        for (int nt = 0; nt < 8; ++nt)
            bfv[nt] = *(const bf16x8*)(B_t + ((size_t)b*DSTATE + nt*16 + r16)*SEQ + cl + k0);
#pragma unroll
        for (int nt = 0; nt < 8; ++nt)
            acc[nt] = __builtin_amdgcn_mfma_f32_16x16x32_bf16(af, bfv[nt], acc[nt], 0,0,0);
    }
    size_t sb = ((size_t)(b*NCHUNK+c)*NHEADS + h)*(HEADDIM*DSTATE);
    int ncol = lane & 15, rowq = (lane>>4)*4;
#pragma unroll
    for (int nt = 0; nt < 8; ++nt)
#pragma unroll
        for (int r = 0; r < 4; ++r)
            states[sb + (size_t)(wave*16 + rowq + r)*DSTATE + nt*16 + ncol] =
                __float2bfloat16(acc[nt][r]);
}

// ---- sequential inter-chunk recurrence, in place (bf16): states[c] := prev[c] ----
__global__ __launch_bounds__(256)
void recur_k(__hip_bfloat16* __restrict__ states, const float* __restrict__ acum)
{
    int pb = blockIdx.x & 3;
    int bh = blockIdx.x >> 2;
    int h = bh % NHEADS, b = bh / NHEADS;
    int voff = (pb*256 + threadIdx.x)*8;
    float S[8] = {};
    for (int c = 0; c < NCHUNK; ++c) {
        size_t addr = ((size_t)(b*NCHUNK+c)*NHEADS + h)*(HEADDIM*DSTATE) + voff;
        bf16x8 st = *(bf16x8*)(states + addr);
        float e = expf(acum[((b*NHEADS+h)*NCHUNK + c)*CHUNK + 127]);
        bf16x8 pv;
#pragma unroll
        for (int j = 0; j < 8; ++j) {
            pv[j] = (__bf16)S[j];
            S[j] = S[j]*e + (float)st[j];
        }
        *(bf16x8*)(states + addr) = pv;
    }
}

// ======== Y = [tril(CB*exp(dAc)*dt) + D*I] @ x  +  (C*exp(ac)) @ prev^T ========
__global__ __launch_bounds__(512)
void y_mfma(const __hip_bfloat16* __restrict__ x_t,
            const __hip_bfloat16* __restrict__ C_n, const __hip_bfloat16* __restrict__ CB16,
            const __hip_bfloat16* __restrict__ states, const float* __restrict__ dtb,
            const float* __restrict__ acum, const float* __restrict__ Dp,
            __hip_bfloat16* __restrict__ y16)
{
    __shared__ float ac[128], dts[128];
    int c = blockIdx.x & 31;
    int h = (blockIdx.x>>5) % NHEADS;
    int b = blockIdx.x/(32*NHEADS);
    int tid = threadIdx.x, lane = tid & 63, wave = tid >> 6;
    int arow = ((b*NHEADS+h)*NCHUNK + c)*CHUNK;
    size_t rbase = (size_t)b*SEQ + c*CHUNK;
    if (tid < 128) {
        ac[tid]  = acum[arow + tid];
        dts[tid] = dtb[(rbase + tid)*NHEADS + h];
    }
    __syncthreads();
    int r16 = lane & 15, kq = (lane>>4)*8;
    int l = wave*16 + r16;
    float acl = ac[l];
    float Dh = Dp[h];
    size_t cbb = (size_t)(b*NCHUNK+c)*CHUNK*CHUNK;
    size_t xtb = ((size_t)b*NHEADS + h)*HEADDIM;
    int cl = c*CHUNK;
    floatx4 acc[4] = {};
    int nks = ((wave+1)*16 + 31) >> 5;
    for (int ks = 0; ks < nks; ++ks) {
        int k0 = ks*32 + kq;
        bf16x8 cbv = *(const bf16x8*)(CB16 + cbb + (size_t)l*CHUNK + k0);
        bf16x8 af;
#pragma unroll
        for (int j = 0; j < 8; ++j) {
            int s = k0 + j;
            float w = (s <= l) ? (float)cbv[j] * expf(acl - ac[s]) * dts[s] : 0.f;
            if (s == l) w += Dh;               // D*x folded into the diagonal
            af[j] = (__bf16)w;
        }
        bf16x8 bfv[4];
#pragma unroll
        for (int pt = 0; pt < 4; ++pt)
            bfv[pt] = *(const bf16x8*)(x_t + (xtb + pt*16 + r16)*SEQ + cl + k0);
#pragma unroll
        for (int pt = 0; pt < 4; ++pt)
            acc[pt] = __builtin_amdgcn_mfma_f32_16x16x32_bf16(af, bfv[pt], acc[pt], 0,0,0);
    }
    float eal = expf(acl);
    size_t sb = ((size_t)(b*NCHUNK+c)*NHEADS + h)*(HEADDIM*DSTATE);
#pragma unroll
    for (int ks = 0; ks < 4; ++ks) {
        int k0 = ks*32 + kq;
        bf16x8 cv = *(const bf16x8*)(C_n + (rbase + l)*DSTATE + k0);
        bf16x8 af;
#pragma unroll
        for (int j = 0; j < 8; ++j)
            af[j] = (__bf16)((float)cv[j] * eal);
        bf16x8 bfv[4];
#pragma unroll
        for (int pt = 0; pt < 4; ++pt)
            bfv[pt] = *(const bf16x8*)(states + sb + (size_t)(pt*16 + r16)*DSTATE + k0);
#pragma unroll
        for (int pt = 0; pt < 4; ++pt)
            acc[pt] = __builtin_amdgcn_mfma_f32_16x16x32_bf16(af, bfv[pt], acc[pt], 0,0,0);
    }
    int pcol = lane & 15, rowq = (lane>>4)*4;
#pragma unroll
    for (int pt = 0; pt < 4; ++pt)
#pragma unroll
        for (int r = 0; r < 4; ++r) {
            int ll = wave*16 + rowq + r;
            int p = pt*16 + pcol;
            size_t rr = rbase + ll;
            y16[rr*DINNER + h*HEADDIM + p] = __float2bfloat16(acc[pt][r]);
        }
}

// ------- y16 *= silu(z16); RMSNorm * norm_w (in place, bf16, 192 thr) -------------
__global__ __launch_bounds__(192)
void norm_k(__hip_bfloat16* __restrict__ y16, const __hip_bfloat16* __restrict__ z16,
            const float* __restrict__ nw)
{
    int r = blockIdx.x, tid = threadIdx.x;
    float v[8]; float ss = 0.f;
    int c0 = tid*8;
    bf16x8 zv = *(const bf16x8*)(z16 + (size_t)r*DINNER + c0);
    bf16x8 yv = *(const bf16x8*)(y16 + (size_t)r*DINNER + c0);
#pragma unroll
    for (int j = 0; j < 8; ++j) {
        float g = (float)yv[j] * siluf_((float)zv[j]);
        v[j] = g; ss += g*g;
    }
    for (int off=32; off; off>>=1) ss += __shfl_down(ss, off);
    __shared__ float red[3];
    __shared__ float stot;
    int lane = tid & 63, wid = tid >> 6;
    if (lane==0) red[wid] = ss;
    __syncthreads();
    if (tid==0) stot = red[0]+red[1]+red[2];
    __syncthreads();
    float scale = rsqrtf(stot * (1.f/DINNER) + 1e-5f);
    bf16x8 ov;
#pragma unroll
    for (int j = 0; j < 8; ++j)
        ov[j] = (__bf16)(v[j]*scale*nw[c0+j]);
    *(bf16x8*)(y16 + (size_t)r*DINNER + c0) = ov;
}

extern "C" void kernel_launch(void* const* d_in, const int* in_sizes, int n_in,
                              void* d_out, int out_size, void* d_ws, size_t ws_size,
                              hipStream_t stream)
{
    const float* feature = (const float*)d_in[0];
    const float* gate1   = (const float*)d_in[1];
    const float* in_w    = (const float*)d_in[2];
    const float* conv_w  = (const float*)d_in[3];
    const float* conv_b  = (const float*)d_in[4];
    const float* dt_bias = (const float*)d_in[5];
    const float* A_log   = (const float*)d_in[6];
    const float* Dp      = (const float*)d_in[7];
    const float* norm_w  = (const float*)d_in[8];
    const float* out_w   = (const float*)d_in[9];
    float* out = (float*)d_out;

    // workspace layout — ~161 MB (< 256 MiB)
    char* p = (char*)d_ws;
    __hip_bfloat16* z16   = (__hip_bfloat16*)p; p += (size_t)ROWS*DINNER*2;  // 25.2 MB
    __hip_bfloat16* xbc16 = (__hip_bfloat16*)p; p += (size_t)ROWS*DXBC*2;    // 29.4 MB
    __hip_bfloat16* x_t   = (__hip_bfloat16*)p; p += (size_t)ROWS*DINNER*2;  // 25.2 MB
    __hip_bfloat16* B_n   = (__hip_bfloat16*)p; p += (size_t)ROWS*DSTATE*2;  // 2.1 MB
    __hip_bfloat16* B_t   = (__hip_bfloat16*)p; p += (size_t)ROWS*DSTATE*2;  // 2.1 MB
    __hip_bfloat16* C_n   = (__hip_bfloat16*)p; p += (size_t)ROWS*DSTATE*2;  // 2.1 MB
    float* dtb    = (float*)p;            p += (size_t)ROWS*NHEADS*4;        // 0.8 MB
    float* acum   = (float*)p;            p += (size_t)B_SZ*NHEADS*NCHUNK*CHUNK*4; // 0.8 MB
    __hip_bfloat16* CB16 = (__hip_bfloat16*)p; p += (size_t)B_SZ*NCHUNK*CHUNK*CHUNK*2; // 2.1 MB
    __hip_bfloat16* states = (__hip_bfloat16*)p; p += (size_t)B_SZ*NCHUNK*NHEADS*HEADDIM*DSTATE*2; // 25.2 MB
    __hip_bfloat16* y16  = (__hip_bfloat16*)p; p += (size_t)ROWS*DINNER*2;   // 25.2 MB
    __hip_bfloat16* fbf  = (__hip_bfloat16*)p; p += (size_t)ROWS*DMODEL*2;   // 12.6 MB
    __hip_bfloat16* wbf  = (__hip_bfloat16*)p; p += (size_t)NPAD1*DMODEL*2;  //  5.3 MB
    __hip_bfloat16* owbf = (__hip_bfloat16*)p; p += (size_t)DMODEL*DINNER*2; //  2.4 MB

    cast_k<<<(ROWS*DMODEL+255)/256, 256, 0, stream>>>(feature, fbf, ROWS*DMODEL);
    cast_w1_k<<<(NPAD1*DMODEL+255)/256, 256, 0, stream>>>(in_w, wbf);
    cast_k<<<(DMODEL*DINNER+255)/256, 256, 0, stream>>>(out_w, owbf, DMODEL*DINNER);

    gemm1_mfma<<<27*32, 512, 0, stream>>>(fbf, wbf, z16, xbc16, dtb, dt_bias);
    conv_k<<<dim3(14, 32, B_SZ), 256, 0, stream>>>(xbc16, conv_w, conv_b,
                                                   x_t, B_n, B_t, C_n);
    scan_k<<<B_SZ*NHEADS*NCHUNK, 128, 0, stream>>>(dtb, A_log, acum);
    cb_mfma<<<B_SZ*NCHUNK, 256, 0, stream>>>(B_n, C_n, CB16);
    states_mfma<<<B_SZ*NHEADS*NCHUNK, 256, 0, stream>>>(x_t, B_t, dtb, acum, states);
    recur_k<<<B_SZ*NHEADS*4, 256, 0, stream>>>(states, acum);
    y_mfma<<<B_SZ*NHEADS*NCHUNK, 512, 0, stream>>>(x_t, C_n, CB16, states,
                                                   dtb, acum, Dp, y16);
    norm_k<<<ROWS, 192, 0, stream>>>(y16, z16, norm_w);
    gemm2_mfma<<<6*64, 256, 0, stream>>>(y16, owbf, out, gate1, feature);
}

// Round 10
// 339.207 us; speedup vs baseline: 5.2434x; 1.0251x over previous
//
#include <hip/hip_runtime.h>
#include <hip/hip_bf16.h>
#include <math.h>

#define B_SZ 2
#define SEQ 4096
#define DMODEL 768
#define DSTATE 128
#define HEADDIM 64
#define DINNER 1536
#define NHEADS 24
#define DXBC 1792
#define DPROJ 3352
#define NPAD1 3456
#define CHUNK 128
#define NCHUNK 32
#define ROWS (B_SZ*SEQ)
#define LDTC 136   // padded LDS stride for conv input tile
#define LDE 136    // padded LDS stride (bf16) for epilogue tiles
#define LDE2 132   // padded LDS stride (fp32) for gemm2 epilogue tile

typedef float floatx4 __attribute__((ext_vector_type(4)));
typedef __bf16 bf16x8 __attribute__((ext_vector_type(8)));

__device__ __forceinline__ float sigmoidf_(float x){ return 1.f/(1.f+expf(-x)); }
__device__ __forceinline__ float siluf_(float x){ return x/(1.f+expf(-x)); }
__device__ __forceinline__ float softplusf_(float x){ return (x>20.f)? x : log1pf(expf(x)); }

__device__ __forceinline__ void gload_lds16(const __hip_bfloat16* g, __hip_bfloat16* l){
    __builtin_amdgcn_global_load_lds(
        (const __attribute__((address_space(1))) void*)g,
        (__attribute__((address_space(3))) void*)l, 16, 0, 0);
}

// ======== GEMM1: 256x128 tile, 8 waves; epilogue -> z16 / xbc16 / dtb ========
__global__ __launch_bounds__(512)
void gemm1_mfma(const __hip_bfloat16* __restrict__ A,   // fbf [ROWS][768]
                const __hip_bfloat16* __restrict__ W,   // wbf [3456][768]
                __hip_bfloat16* __restrict__ z16, __hip_bfloat16* __restrict__ xbc16,
                float* __restrict__ dtb, const float* __restrict__ dt_bias)
{
    __shared__ __align__(16) char smem[49152];          // Asm 32K + Wsm 16K
    __hip_bfloat16* Asm = (__hip_bfloat16*)smem;        // [256][64]
    __hip_bfloat16* Wsm = Asm + 256*64;                 // [128][64]
    const int tid = threadIdx.x;
    const int lane = tid & 63, wave = tid >> 6;
    const int blk = blockIdx.x;
    const int m_tile = ((blk & 7) << 2) | ((blk >> 3) & 3);   // 32 M-tiles, XCD band
    const int bx = blk >> 5;                                   // N-tile 0..26
    const int bm = m_tile*256, bn = bx*128;
    const int wm = (wave & 3)*64, wn = (wave >> 2)*64;
    const int r16 = lane & 15, qbase = lane >> 4, sw = r16 & 7;
    floatx4 acc[4][4] = {};
    for (int k0 = 0; k0 < DMODEL; k0 += 64) {
#pragma unroll
        for (int j = 0; j < 4; ++j) {
            int cc = j*512 + tid;                // A: 2048 chunks
            int row = cc >> 3, jc = cc & 7;
            int sj = jc ^ (row & 7);
            gload_lds16(A + (size_t)(bm+row)*DMODEL + k0 + sj*8, Asm + cc*8);
        }
#pragma unroll
        for (int j = 0; j < 2; ++j) {
            int cc = j*512 + tid;                // W: 1024 chunks
            int row = cc >> 3, jc = cc & 7;
            int sj = jc ^ (row & 7);
            gload_lds16(W + (size_t)(bn+row)*DMODEL + k0 + sj*8, Wsm + cc*8);
        }
        __syncthreads();
#pragma unroll
        for (int ks = 0; ks < 2; ++ks) {
            const int kq = ((qbase + ks*4) ^ sw)*8;
            bf16x8 af[4], wf[4];
#pragma unroll
            for (int i = 0; i < 4; ++i) {
                af[i] = *(const bf16x8*)(Asm + (wm + i*16 + r16)*64 + kq);
                wf[i] = *(const bf16x8*)(Wsm + (wn + i*16 + r16)*64 + kq);
            }
#pragma unroll
            for (int mi = 0; mi < 4; ++mi)
#pragma unroll
                for (int ni = 0; ni < 4; ++ni)
                    acc[mi][ni] = __builtin_amdgcn_mfma_f32_16x16x32_bf16(
                        af[mi], wf[ni], acc[mi][ni], 0, 0, 0);
        }
        __syncthreads();
    }
    const int col = lane & 15, rowq = (lane >> 4)*4;
    if (bx == 26) {
        if (wn == 0) {
#pragma unroll
            for (int mi = 0; mi < 4; ++mi)
#pragma unroll
                for (int ni = 0; ni < 2; ++ni) {
                    int h = ni*16 + col;
                    if (h < NHEADS)
#pragma unroll
                        for (int r = 0; r < 4; ++r) {
                            int m = bm + wm + mi*16 + rowq + r;
                            dtb[(size_t)m*NHEADS + h] =
                                softplusf_(acc[mi][ni][r] + dt_bias[h]);
                        }
                }
        }
        return;
    }
    __hip_bfloat16* Tsm = (__hip_bfloat16*)smem;   // [128][LDE]
    __hip_bfloat16* dst; int ldd;
    if (bx < 12) { dst = z16 + bn;            ldd = DINNER; }
    else         { dst = xbc16 + bn - DINNER; ldd = DXBC;  }
    for (int half = 0; half < 2; ++half) {
        if (((wave & 3) >> 1) == half) {
#pragma unroll
            for (int mi = 0; mi < 4; ++mi)
#pragma unroll
                for (int ni = 0; ni < 4; ++ni)
#pragma unroll
                    for (int r = 0; r < 4; ++r)
                        Tsm[(wm - half*128 + mi*16 + rowq + r)*LDE + wn + ni*16 + col] =
                            __float2bfloat16(acc[mi][ni][r]);
        }
        __syncthreads();
#pragma unroll
        for (int it = 0; it < 4; ++it) {
            int e = it*512 + tid;
            int row = e >> 4, c0 = (e & 15)*8;
            bf16x8 v = *(const bf16x8*)(Tsm + row*LDE + c0);
            *(bf16x8*)(dst + (size_t)(bm + half*128 + row)*ldd + c0) = v;
        }
        __syncthreads();
    }
}

// ======== GEMM2: 256x128 tile; out = sig(gate)*rms_scale_r*(g @ Wn^T) + feature ====
// A = y16 holds g = y*silu(z); Wn = out_w * norm_w (folded at cast); rms scale from rowsq.
__global__ __launch_bounds__(512)
void gemm2_mfma(const __hip_bfloat16* __restrict__ A,   // y16 [ROWS][1536] (gated)
                const __hip_bfloat16* __restrict__ W,   // owbf [768][1536]
                float* __restrict__ C,
                const float* __restrict__ gate, const float* __restrict__ resid,
                const float* __restrict__ rowsq)
{
    __shared__ __align__(16) char smem[49152];
    __shared__ float scale_lds[256];
    __hip_bfloat16* Asm = (__hip_bfloat16*)smem;        // [256][64]
    __hip_bfloat16* Wsm = Asm + 256*64;                 // [128][64]
    const int tid = threadIdx.x;
    const int lane = tid & 63, wave = tid >> 6;
    const int blk = blockIdx.x;
    const int m_tile = ((blk & 7) << 2) | ((blk >> 3) & 3);
    const int bm = m_tile*256, bn = (blk >> 5)*128;     // n-tile 0..5
    const int wm = (wave & 3)*64, wn = (wave >> 2)*64;
    const int r16 = lane & 15, qbase = lane >> 4, sw = r16 & 7;
    floatx4 acc[4][4] = {};
    for (int k0 = 0; k0 < DINNER; k0 += 64) {
#pragma unroll
        for (int j = 0; j < 4; ++j) {
            int cc = j*512 + tid;
            int row = cc >> 3, jc = cc & 7;
            int sj = jc ^ (row & 7);
            gload_lds16(A + (size_t)(bm+row)*DINNER + k0 + sj*8, Asm + cc*8);
        }
#pragma unroll
        for (int j = 0; j < 2; ++j) {
            int cc = j*512 + tid;
            int row = cc >> 3, jc = cc & 7;
            int sj = jc ^ (row & 7);
            gload_lds16(W + (size_t)(bn+row)*DINNER + k0 + sj*8, Wsm + cc*8);
        }
        __syncthreads();
#pragma unroll
        for (int ks = 0; ks < 2; ++ks) {
            const int kq = ((qbase + ks*4) ^ sw)*8;
            bf16x8 af[4], wf[4];
#pragma unroll
            for (int i = 0; i < 4; ++i) {
                af[i] = *(const bf16x8*)(Asm + (wm + i*16 + r16)*64 + kq);
                wf[i] = *(const bf16x8*)(Wsm + (wn + i*16 + r16)*64 + kq);
            }
#pragma unroll
            for (int mi = 0; mi < 4; ++mi)
#pragma unroll
                for (int ni = 0; ni < 4; ++ni)
                    acc[mi][ni] = __builtin_amdgcn_mfma_f32_16x16x32_bf16(
                        af[mi], wf[ni], acc[mi][ni], 0, 0, 0);
        }
        __syncthreads();
    }
    if (tid < 256)
        scale_lds[tid] = rsqrtf(rowsq[bm + tid] * (1.f/DINNER) + 1e-5f);
    float gs = sigmoidf_(gate[0]);
    __syncthreads();
    const int col = lane & 15, rowq = (lane >> 4)*4;
    float* Tsm = (float*)smem;   // 64 x LDE2 fp32
    for (int qp = 0; qp < 4; ++qp) {
        if ((wave & 3) == qp) {
#pragma unroll
            for (int mi = 0; mi < 4; ++mi)
#pragma unroll
                for (int ni = 0; ni < 4; ++ni)
#pragma unroll
                    for (int r = 0; r < 4; ++r)
                        Tsm[(mi*16 + rowq + r)*LDE2 + wn + ni*16 + col] = acc[mi][ni][r];
        }
        __syncthreads();
#pragma unroll
        for (int it = 0; it < 4; ++it) {
            int e = it*512 + tid;
            int row = e >> 5, c0 = (e & 31)*4;
            float4 v = *(const float4*)(Tsm + row*LDE2 + c0);
            float sc = gs * scale_lds[qp*64 + row];
            size_t off = (size_t)(bm + qp*64 + row)*DMODEL + bn + c0;
            float4 rv = *(const float4*)(resid + off);
            v.x = sc*v.x + rv.x; v.y = sc*v.y + rv.y;
            v.z = sc*v.z + rv.z; v.w = sc*v.w + rv.w;
            *(float4*)(C + off) = v;
        }
        __syncthreads();
    }
}

// ---------------- fused fp32 -> bf16 casts (feature / in_w padded / out_w*norm_w) ----
#define NC1 (ROWS*DMODEL)
#define NC2 (NPAD1*DMODEL)
#define NC3 (DMODEL*DINNER)
__global__ __launch_bounds__(256)
void cast_all(const float* __restrict__ feature, const float* __restrict__ in_w,
              const float* __restrict__ out_w, const float* __restrict__ nw,
              __hip_bfloat16* __restrict__ fbf, __hip_bfloat16* __restrict__ wbf,
              __hip_bfloat16* __restrict__ owbf)
{
    int i = blockIdx.x*256 + threadIdx.x;
    if (i < NC1) {
        fbf[i] = __float2bfloat16(feature[i]);
    } else if (i < NC1 + NC2) {
        int j = i - NC1;
        int n = j / DMODEL, k = j % DMODEL;
        wbf[j] = __float2bfloat16(n < DPROJ ? in_w[(size_t)n*DMODEL + k] : 0.f);
    } else if (i < NC1 + NC2 + NC3) {
        int j = i - NC1 - NC2;
        int k = j % DINNER;
        owbf[j] = __float2bfloat16(out_w[j] * nw[k]);
    }
}

// ======== conv4+SiLU, emits x_t/B_n/B_t/C_n in MFMA-ready layouts ========
__global__ __launch_bounds__(256)
void conv_k(const __hip_bfloat16* __restrict__ xbc16, const float* __restrict__ cw,
            const float* __restrict__ cbias,
            __hip_bfloat16* __restrict__ x_t,
            __hip_bfloat16* __restrict__ B_n, __hip_bfloat16* __restrict__ B_t,
            __hip_bfloat16* __restrict__ C_n)
{
    __shared__ __align__(16) __hip_bfloat16 in[131*LDTC];
    int ct = blockIdx.x, lt = blockIdx.y, b = blockIdx.z;
    int tid = threadIdx.x;
    int base = lt*128;
    for (int it = 0; it < 2096; it += 256) {
        int e = it + tid; if (e >= 2096) break;
        int row = e >> 4, c0 = (e & 15)*8;
        int l = base - 3 + row;
        bf16x8 v;
        if (l < 0) { for (int j = 0; j < 8; ++j) v[j] = (__bf16)0.f; }
        else v = *(const bf16x8*)(xbc16 + ((size_t)b*SEQ + l)*DXBC + ct*128 + c0);
        *(bf16x8*)(in + row*LDTC + c0) = v;
    }
    __syncthreads();
    int ch = tid & 127, lh = tid >> 7, l0 = lh*64;
    int g = ct*128 + ch;
    float w0 = cw[g*4+0], w1 = cw[g*4+1], w2 = cw[g*4+2], w3 = cw[g*4+3];
    float bias = cbias[g];
    float a0 = __bfloat162float(in[(l0+0)*LDTC + ch]);
    float a1 = __bfloat162float(in[(l0+1)*LDTC + ch]);
    float a2 = __bfloat162float(in[(l0+2)*LDTC + ch]);
    size_t trow = 0;
    if (ct < 12)      trow = ((size_t)b*NHEADS + (g>>6))*HEADDIM + (g & 63);
    else if (ct == 12) trow = (size_t)b*DSTATE + ch;
    bf16x8 obuf;
#pragma unroll
    for (int li = 0; li < 64; ++li) {
        float a3 = __bfloat162float(in[(l0+li+3)*LDTC + ch]);
        float o = siluf_(bias + w0*a0 + w1*a1 + w2*a2 + w3*a3);
        a0 = a1; a1 = a2; a2 = a3;
        __hip_bfloat16 ob = __float2bfloat16(o);
        size_t rr = (size_t)b*SEQ + base + l0 + li;
        if (ct == 12)      B_n[rr*DSTATE + ch] = ob;
        else if (ct == 13) C_n[rr*DSTATE + ch] = ob;
        obuf[li & 7] = *(const __bf16*)&ob;
        if ((li & 7) == 7 && ct <= 12) {
            __hip_bfloat16* dst = (ct < 12) ? x_t : B_t;
            *(bf16x8*)(dst + trow*SEQ + base + l0 + (li - 7)) = obuf;
        }
    }
}

// ---------------- intra-chunk inclusive cumsum of dt*A ----------------
__global__ __launch_bounds__(128)
void scan_k(const float* __restrict__ dtb, const float* __restrict__ A_log,
            float* __restrict__ acum)
{
    int c = blockIdx.x & 31;
    int h = (blockIdx.x >> 5) % NHEADS;
    int b = blockIdx.x / (32*NHEADS);
    int l = threadIdx.x;
    float A = -expf(A_log[h]);
    size_t row = (size_t)b*SEQ + c*CHUNK + l;
    float v = dtb[row*NHEADS + h] * A;
    __shared__ float sh[128];
    sh[l] = v; __syncthreads();
    for (int off=1; off<128; off<<=1){
        float t = (l>=off) ? sh[l-off] : 0.f;
        __syncthreads();
        sh[l] += t;
        __syncthreads();
    }
    acum[((b*NHEADS+h)*NCHUNK + c)*CHUNK + l] = sh[l];
}

// ======== CB[l][s] = sum_n C[l][n]*B[s][n], per (b,c), LDS-free, tril tiles only ========
__global__ __launch_bounds__(256)
void cb_mfma(const __hip_bfloat16* __restrict__ B_n, const __hip_bfloat16* __restrict__ C_n,
             __hip_bfloat16* __restrict__ CB16)
{
    int c = blockIdx.x & 31, b = blockIdx.x >> 5;
    size_t base = (size_t)b*SEQ + c*CHUNK;
    int tid = threadIdx.x, lane = tid & 63, wave = tid >> 6;
    int r16 = lane & 15, kq = (lane>>4)*8;
    floatx4 acc[2][8] = {};
#pragma unroll
    for (int ks = 0; ks < 4; ++ks) {
        int k0 = ks*32 + kq;
        bf16x8 af[2], bfv[8];
#pragma unroll
        for (int mt = 0; mt < 2; ++mt)
            af[mt] = *(const bf16x8*)(C_n + (base + (wave*2+mt)*16 + r16)*DSTATE + k0);
#pragma unroll
        for (int st = 0; st < 8; ++st)
            bfv[st] = *(const bf16x8*)(B_n + (base + st*16 + r16)*DSTATE + k0);
#pragma unroll
        for (int mt = 0; mt < 2; ++mt)
#pragma unroll
            for (int st = 0; st < 8; ++st)
                if (st <= wave*2+mt)
                    acc[mt][st] = __builtin_amdgcn_mfma_f32_16x16x32_bf16(
                        af[mt], bfv[st], acc[mt][st], 0,0,0);
    }
    size_t cbb = (size_t)(b*NCHUNK+c)*CHUNK*CHUNK;
    int scol = lane & 15, rowq = (lane>>4)*4;
#pragma unroll
    for (int mt = 0; mt < 2; ++mt)
#pragma unroll
        for (int st = 0; st < 8; ++st)
            if (st <= wave*2+mt)
#pragma unroll
                for (int r = 0; r < 4; ++r)
                    CB16[cbb + (size_t)((wave*2+mt)*16 + rowq + r)*CHUNK + st*16 + scol] =
                        __float2bfloat16(acc[mt][st][r]);
}

// ======== states[p][n] = sum_l (x[l,p]*f[l]) * B[l,n], f = dt*dec ========
__global__ __launch_bounds__(256)
void states_mfma(const __hip_bfloat16* __restrict__ x_t, const __hip_bfloat16* __restrict__ B_t,
                 const float* __restrict__ dtb, const float* __restrict__ acum,
                 __hip_bfloat16* __restrict__ states)
{
    __shared__ float f[128];
    int c = blockIdx.x & 31;
    int h = (blockIdx.x>>5) % NHEADS;
    int b = blockIdx.x/(32*NHEADS);
    int tid = threadIdx.x, lane = tid & 63, wave = tid >> 6;
    int arow = ((b*NHEADS+h)*NCHUNK + c)*CHUNK;
    size_t rbase = (size_t)b*SEQ + c*CHUNK;
    if (tid < 128) {
        float alast = acum[arow + 127];
        f[tid] = dtb[(rbase + tid)*NHEADS + h] * expf(alast - acum[arow + tid]);
    }
    __syncthreads();
    int r16 = lane & 15, kq = (lane>>4)*8;
    size_t xtb = ((size_t)b*NHEADS + h)*HEADDIM;
    int cl = c*CHUNK;
    floatx4 acc[8] = {};
#pragma unroll
    for (int ks = 0; ks < 4; ++ks) {
        int k0 = ks*32 + kq;
        bf16x8 xa = *(const bf16x8*)(x_t + (xtb + wave*16 + r16)*SEQ + cl + k0);
        bf16x8 af;
#pragma unroll
        for (int j = 0; j < 8; ++j)
            af[j] = (__bf16)((float)xa[j] * f[k0 + j]);
        bf16x8 bfv[8];
#pragma unroll
        for (int nt = 0; nt < 8; ++nt)
            bfv[nt] = *(const bf16x8*)(B_t + ((size_t)b*DSTATE + nt*16 + r16)*SEQ + cl + k0);
#pragma unroll
        for (int nt = 0; nt < 8; ++nt)
            acc[nt] = __builtin_amdgcn_mfma_f32_16x16x32_bf16(af, bfv[nt], acc[nt], 0,0,0);
    }
    size_t sb = ((size_t)(b*NCHUNK+c)*NHEADS + h)*(HEADDIM*DSTATE);
    int ncol = lane & 15, rowq = (lane>>4)*4;
#pragma unroll
    for (int nt = 0; nt < 8; ++nt)
#pragma unroll
        for (int r = 0; r < 4; ++r)
            states[sb + (size_t)(wave*16 + rowq + r)*DSTATE + nt*16 + ncol] =
                __float2bfloat16(acc[nt][r]);
}

// ---- sequential inter-chunk recurrence, in place (bf16): states[c] := prev[c] ----
__global__ __launch_bounds__(256)
void recur_k(__hip_bfloat16* __restrict__ states, const float* __restrict__ acum)
{
    int pb = blockIdx.x & 3;
    int bh = blockIdx.x >> 2;
    int h = bh % NHEADS, b = bh / NHEADS;
    int voff = (pb*256 + threadIdx.x)*8;
    float S[8] = {};
    for (int c = 0; c < NCHUNK; ++c) {
        size_t addr = ((size_t)(b*NCHUNK+c)*NHEADS + h)*(HEADDIM*DSTATE) + voff;
        bf16x8 st = *(bf16x8*)(states + addr);
        float e = expf(acum[((b*NHEADS+h)*NCHUNK + c)*CHUNK + 127]);
        bf16x8 pv;
#pragma unroll
        for (int j = 0; j < 8; ++j) {
            pv[j] = (__bf16)S[j];
            S[j] = S[j]*e + (float)st[j];
        }
        *(bf16x8*)(states + addr) = pv;
    }
}

// ======== Y = [tril(CB*exp(dAc)*dt)+D*I] @ x + (C*exp(ac)) @ prev^T; then
//          g = Y*silu(z) -> y16; rowsq += per-row sum(g^2) (atomic) ========
__global__ __launch_bounds__(512)
void y_mfma(const __hip_bfloat16* __restrict__ x_t, const __hip_bfloat16* __restrict__ z16,
            const __hip_bfloat16* __restrict__ C_n, const __hip_bfloat16* __restrict__ CB16,
            const __hip_bfloat16* __restrict__ states, const float* __restrict__ dtb,
            const float* __restrict__ acum, const float* __restrict__ Dp,
            __hip_bfloat16* __restrict__ y16, float* __restrict__ rowsq)
{
    __shared__ float ac[128], dts[128];
    int c = blockIdx.x & 31;
    int h = (blockIdx.x>>5) % NHEADS;
    int b = blockIdx.x/(32*NHEADS);
    int tid = threadIdx.x, lane = tid & 63, wave = tid >> 6;
    int arow = ((b*NHEADS+h)*NCHUNK + c)*CHUNK;
    size_t rbase = (size_t)b*SEQ + c*CHUNK;
    if (tid < 128) {
        ac[tid]  = acum[arow + tid];
        dts[tid] = dtb[(rbase + tid)*NHEADS + h];
    }
    __syncthreads();
    int r16 = lane & 15, kq = (lane>>4)*8;
    int l = wave*16 + r16;
    float acl = ac[l];
    float Dh = Dp[h];
    size_t cbb = (size_t)(b*NCHUNK+c)*CHUNK*CHUNK;
    size_t xtb = ((size_t)b*NHEADS + h)*HEADDIM;
    int cl = c*CHUNK;
    floatx4 acc[4] = {};
    int nks = ((wave+1)*16 + 31) >> 5;
    for (int ks = 0; ks < nks; ++ks) {
        int k0 = ks*32 + kq;
        bf16x8 cbv = *(const bf16x8*)(CB16 + cbb + (size_t)l*CHUNK + k0);
        bf16x8 af;
#pragma unroll
        for (int j = 0; j < 8; ++j) {
            int s = k0 + j;
            float w = (s <= l) ? (float)cbv[j] * expf(acl - ac[s]) * dts[s] : 0.f;
            if (s == l) w += Dh;               // D*x folded into the diagonal
            af[j] = (__bf16)w;
        }
        bf16x8 bfv[4];
#pragma unroll
        for (int pt = 0; pt < 4; ++pt)
            bfv[pt] = *(const bf16x8*)(x_t + (xtb + pt*16 + r16)*SEQ + cl + k0);
#pragma unroll
        for (int pt = 0; pt < 4; ++pt)
            acc[pt] = __builtin_amdgcn_mfma_f32_16x16x32_bf16(af, bfv[pt], acc[pt], 0,0,0);
    }
    float eal = expf(acl);
    size_t sb = ((size_t)(b*NCHUNK+c)*NHEADS + h)*(HEADDIM*DSTATE);
#pragma unroll
    for (int ks = 0; ks < 4; ++ks) {
        int k0 = ks*32 + kq;
        bf16x8 cv = *(const bf16x8*)(C_n + (rbase + l)*DSTATE + k0);
        bf16x8 af;
#pragma unroll
        for (int j = 0; j < 8; ++j)
            af[j] = (__bf16)((float)cv[j] * eal);
        bf16x8 bfv[4];
#pragma unroll
        for (int pt = 0; pt < 4; ++pt)
            bfv[pt] = *(const bf16x8*)(states + sb + (size_t)(pt*16 + r16)*DSTATE + k0);
#pragma unroll
        for (int pt = 0; pt < 4; ++pt)
            acc[pt] = __builtin_amdgcn_mfma_f32_16x16x32_bf16(af, bfv[pt], acc[pt], 0,0,0);
    }
    // epilogue: g = acc * silu(z); store; per-row sumsq via shuffle + atomic
    int pcol = lane & 15, rowq = (lane>>4)*4;
    float sr[4] = {0.f, 0.f, 0.f, 0.f};
#pragma unroll
    for (int pt = 0; pt < 4; ++pt)
#pragma unroll
        for (int r = 0; r < 4; ++r) {
            int ll = wave*16 + rowq + r;
            int p = pt*16 + pcol;
            size_t rr = rbase + ll;
            float zv = __bfloat162float(z16[rr*DINNER + h*HEADDIM + p]);
            float g = acc[pt][r] * siluf_(zv);
            y16[rr*DINNER + h*HEADDIM + p] = __float2bfloat16(g);
            sr[r] += g*g;
        }
#pragma unroll
    for (int r = 0; r < 4; ++r) {
        float s = sr[r];
        s += __shfl_xor(s, 1); s += __shfl_xor(s, 2);
        s += __shfl_xor(s, 4); s += __shfl_xor(s, 8);
        if (pcol == 0)
            atomicAdd(rowsq + rbase + wave*16 + rowq + r, s);
    }
}

extern "C" void kernel_launch(void* const* d_in, const int* in_sizes, int n_in,
                              void* d_out, int out_size, void* d_ws, size_t ws_size,
                              hipStream_t stream)
{
    const float* feature = (const float*)d_in[0];
    const float* gate1   = (const float*)d_in[1];
    const float* in_w    = (const float*)d_in[2];
    const float* conv_w  = (const float*)d_in[3];
    const float* conv_b  = (const float*)d_in[4];
    const float* dt_bias = (const float*)d_in[5];
    const float* A_log   = (const float*)d_in[6];
    const float* Dp      = (const float*)d_in[7];
    const float* norm_w  = (const float*)d_in[8];
    const float* out_w   = (const float*)d_in[9];
    float* out = (float*)d_out;

    // workspace layout — ~161 MB (< 256 MiB)
    char* p = (char*)d_ws;
    __hip_bfloat16* z16   = (__hip_bfloat16*)p; p += (size_t)ROWS*DINNER*2;  // 25.2 MB
    __hip_bfloat16* xbc16 = (__hip_bfloat16*)p; p += (size_t)ROWS*DXBC*2;    // 29.4 MB
    __hip_bfloat16* x_t   = (__hip_bfloat16*)p; p += (size_t)ROWS*DINNER*2;  // 25.2 MB
    __hip_bfloat16* B_n   = (__hip_bfloat16*)p; p += (size_t)ROWS*DSTATE*2;  // 2.1 MB
    __hip_bfloat16* B_t   = (__hip_bfloat16*)p; p += (size_t)ROWS*DSTATE*2;  // 2.1 MB
    __hip_bfloat16* C_n   = (__hip_bfloat16*)p; p += (size_t)ROWS*DSTATE*2;  // 2.1 MB
    float* dtb    = (float*)p;            p += (size_t)ROWS*NHEADS*4;        // 0.8 MB
    float* acum   = (float*)p;            p += (size_t)B_SZ*NHEADS*NCHUNK*CHUNK*4; // 0.8 MB
    float* rowsq  = (float*)p;            p += (size_t)ROWS*4;               // 32 KB
    __hip_bfloat16* CB16 = (__hip_bfloat16*)p; p += (size_t)B_SZ*NCHUNK*CHUNK*CHUNK*2; // 2.1 MB
    __hip_bfloat16* states = (__hip_bfloat16*)p; p += (size_t)B_SZ*NCHUNK*NHEADS*HEADDIM*DSTATE*2; // 25.2 MB
    __hip_bfloat16* y16  = (__hip_bfloat16*)p; p += (size_t)ROWS*DINNER*2;   // 25.2 MB
    __hip_bfloat16* fbf  = (__hip_bfloat16*)p; p += (size_t)ROWS*DMODEL*2;   // 12.6 MB
    __hip_bfloat16* wbf  = (__hip_bfloat16*)p; p += (size_t)NPAD1*DMODEL*2;  //  5.3 MB
    __hip_bfloat16* owbf = (__hip_bfloat16*)p; p += (size_t)DMODEL*DINNER*2; //  2.4 MB

    cast_all<<<(NC1+NC2+NC3+255)/256, 256, 0, stream>>>(feature, in_w, out_w, norm_w,
                                                        fbf, wbf, owbf);
    hipMemsetAsync(rowsq, 0, (size_t)ROWS*4, stream);

    gemm1_mfma<<<27*32, 512, 0, stream>>>(fbf, wbf, z16, xbc16, dtb, dt_bias);
    conv_k<<<dim3(14, 32, B_SZ), 256, 0, stream>>>(xbc16, conv_w, conv_b,
                                                   x_t, B_n, B_t, C_n);
    scan_k<<<B_SZ*NHEADS*NCHUNK, 128, 0, stream>>>(dtb, A_log, acum);
    cb_mfma<<<B_SZ*NCHUNK, 256, 0, stream>>>(B_n, C_n, CB16);
    states_mfma<<<B_SZ*NHEADS*NCHUNK, 256, 0, stream>>>(x_t, B_t, dtb, acum, states);
    recur_k<<<B_SZ*NHEADS*4, 256, 0, stream>>>(states, acum);
    y_mfma<<<B_SZ*NHEADS*NCHUNK, 512, 0, stream>>>(x_t, z16, C_n, CB16, states,
                                                   dtb, acum, Dp, y16, rowsq);
    gemm2_mfma<<<6*32, 512, 0, stream>>>(y16, owbf, out, gate1, feature, rowsq);
}